// Round 3
// baseline (5553.282 us; speedup 1.0000x reference)
//
#include <hip/hip_runtime.h>

#define DEVFN __device__ __forceinline__

constexpr int SEQ = 262144;
constexpr int REV_N = 65536;
constexpr int TAPS = 1023;
constexpr int NOISE_LEN = REV_N + TAPS - 1;   // 66558

constexpr int NS_T = 32, L_T = 512, C_T = 512;
constexpr int NS_M = 4,  L_M = 256, C_M = 1024;

// output layout: panned = B*2*NT*SEQ = 16,777,216 floats, then master = B*2*SEQ
constexpr int OUT_MASTER_OFF = 16777216;

#define C_DB  0.16609640474436813f   /* log2(10)/20 */
#define C_LOG 6.0205999132796239f    /* 20*log10(2) */
#define PI_D  3.14159265358979323846

struct SigP {
  float g_in;
  float cb0[6], cb1[6], cb2[6], ca1[6], ca2[6];
  float alpha, oma;
  float th, invr, knee, makeup;
  float g_out;
  float gl, gr, send;
};
struct MatP { double m00, m01, m10, m11; };

// ---------------- workspace layout (bytes) ----------------
constexpr size_t OFF_X   = 0;                       // 33,554,432
constexpr size_t OFF_Y   = 33554432;                // 33,554,432
constexpr size_t OFF_FX  = 67108864;                // 4 MB  (B,2,S)
constexpr size_t OFF_M0  = 71303168;                // 4 MB
constexpr size_t OFF_E2  = 75497472;                // float2[16384]
constexpr size_t OFF_I2  = OFF_E2 + 131072;
constexpr size_t OFF_E1  = OFF_I2 + 131072;         // float[16384]
constexpr size_t OFF_I1  = OFF_E1 + 65536;
constexpr size_t OFF_PT  = OFF_I1 + 65536;
constexpr size_t OFF_PM  = OFF_PT + 32*sizeof(SigP);
constexpr size_t OFF_MT  = (OFF_PM + 4*sizeof(SigP) + 7) & ~(size_t)7;
constexpr size_t OFF_MM  = OFF_MT + 32*6*sizeof(MatP);
constexpr size_t OFF_ALT = OFF_MM + 4*6*sizeof(MatP);
constexpr size_t OFF_ALM = OFF_ALT + 32*sizeof(double);
// overlays (X,Y dead after pan):
constexpr size_t OFF_FILT = OFF_X;                       // 48*65536*4 = 12,582,912
constexpr size_t OFF_IR   = OFF_X + 12582912;            // 1 MB
constexpr size_t OFF_XM   = OFF_X + 16777216;            // 4 MB master ping A
constexpr size_t OFF_YM   = OFF_X + 20971520;            // 4 MB master ping B
constexpr size_t OFF_M1   = OFF_Y;                       // 4 MB master input

// ---------------- params kernel ----------------
DEVFN double dn(float p, double lo, double hi){ return (double)p*(hi-lo)+lo; }

__device__ void mk_sig(const float* p, int L, int nsq, bool is_master,
                       SigP* sp, MatP* mats, double* aL)
{
  const double flo[6] = {20.,80.,2000.,8000.,12000.,6000.};
  const double fhi[6] = {2000.,2000.,8000.,12000.,21050.,21050.};
  double gdb = dn(p[0], -48., 48.);
  sp->g_in = (float)exp2(gdb * 0.16609640474436813);
  for (int k=0;k<6;k++){
    double g  = dn(p[1+3*k], -12., 12.);
    double fc = dn(p[2+3*k], flo[k], fhi[k]);
    double q  = dn(p[3+3*k], 0.1, 5.0);
    double A  = pow(10.0, g/40.0);
    double w0 = 2.0*PI_D*(fc/44100.0);
    double al = sin(w0)/(2.0*q), co = cos(w0), sA = sqrt(A);
    double b0,b1,b2,a0,a1,a2;
    if (k==0){                       // low shelf
      b0 = A*((A+1.0) - (A-1.0)*co + 2.0*sA*al);
      b1 = 2.0*A*((A-1.0) - (A+1.0)*co);
      b2 = A*((A+1.0) - (A-1.0)*co - 2.0*sA*al);
      a0 = (A+1.0) + (A-1.0)*co + 2.0*sA*al;
      a1 = -2.0*((A-1.0) + (A+1.0)*co);
      a2 = (A+1.0) + (A-1.0)*co - 2.0*sA*al;
    } else if (k==5){                // high shelf
      b0 = A*((A+1.0) + (A-1.0)*co + 2.0*sA*al);
      b1 = -2.0*A*((A-1.0) + (A+1.0)*co);
      b2 = A*((A+1.0) + (A-1.0)*co - 2.0*sA*al);
      a0 = (A+1.0) - (A-1.0)*co + 2.0*sA*al;
      a1 = 2.0*((A-1.0) - (A+1.0)*co);
      a2 = (A+1.0) - (A-1.0)*co - 2.0*sA*al;
    } else {                         // peaking
      b0 = 1.0 + al*A; b1 = -2.0*co; b2 = 1.0 - al*A;
      a0 = 1.0 + al/A; a1 = -2.0*co; a2 = 1.0 - al/A;
    }
    double ia0 = 1.0/a0;
    double na1 = a1*ia0, na2 = a2*ia0;
    sp->cb0[k]=(float)(b0*ia0); sp->cb1[k]=(float)(b1*ia0); sp->cb2[k]=(float)(b2*ia0);
    sp->ca1[k]=(float)na1;      sp->ca2[k]=(float)na2;
    double m00=-na1, m01=-na2, m10=1.0, m11=0.0;
    for (int j=0;j<nsq;j++){
      double t00=m00*m00+m01*m10, t01=m00*m01+m01*m11;
      double t10=m10*m00+m11*m10, t11=m10*m01+m11*m11;
      m00=t00;m01=t01;m10=t10;m11=t11;
    }
    mats[k].m00=m00; mats[k].m01=m01; mats[k].m10=m10; mats[k].m11=m11;
  }
  double th    = dn(p[19], -60., 0.);
  double ratio = dn(p[20], 1., 10.);
  double at    = dn(p[21], 5., 250.);
  double knee  = dn(p[23], 3., 12.);
  double mkup  = dn(p[24], 0., 6.);
  double alpha = exp(-log(9.0)/(44100.0*at*0.001));
  sp->alpha=(float)alpha; sp->oma=(float)(1.0-alpha);
  sp->th=(float)th; sp->invr=(float)(1.0/ratio); sp->knee=(float)knee; sp->makeup=(float)mkup;
  *aL = pow(alpha, (double)L);
  if (is_master){
    sp->g_out = (float)exp2(dn(p[25],-48.,48.)*0.16609640474436813);
    sp->gl=0.f; sp->gr=0.f; sp->send=0.f;
  } else {
    sp->g_out = 1.f;
    sp->send = (float)exp2(dn(p[25],-80.,12.)*0.16609640474436813);
    double th2 = dn(p[26],0.,1.)*(PI_D/2.0);
    sp->gl = (float)sqrt((PI_D/2.0-th2)*(2.0/PI_D)*cos(th2));
    sp->gr = (float)sqrt(th2*(2.0/PI_D)*sin(th2));
  }
}

__global__ __launch_bounds__(64) void k_params(const float* __restrict__ tp, const float* __restrict__ mp,
    SigP* Pt, SigP* Pm, MatP* Mt, MatP* Mm, double* aLt, double* aLm)
{
  int i = threadIdx.x;
  if (i < 32)       mk_sig(tp + i*27, L_T, 9, false, &Pt[i], &Mt[i*6], &aLt[i]);
  else if (i < 36){ int j=i-32; mk_sig(mp + (j>>1)*26, L_M, 8, true, &Pm[j], &Mm[j*6], &aLm[j]); }
}

// ---------------- compressor gain computer ----------------
DEVFN float comp_gc(float y, float th, float invr, float kn){
  float av  = fmaxf(fabsf(y), 1e-8f);
  float xdb = C_LOG * __builtin_log2f(av);
  float d   = xdb - th;
  float w = (2.f*d < -kn) ? 0.f
          : ((2.f*fabsf(d) <= kn) ? (d+0.5f*kn)*(d+0.5f*kn)/(2.f*kn) : d);
  return (invr-1.f)*w;
}

// ---------------- section-0 zero-state end (A-pass) ----------------
__global__ __launch_bounds__(256) void k_eqA0(const float* __restrict__ in, const SigP* __restrict__ P,
    float2* __restrict__ endst, int nsig, int C, int L)
{
  int tid = blockIdx.x*256 + threadIdx.x;
  if (tid >= nsig*C) return;
  int sig = tid / C, c = tid - sig*C;
  const SigP* sp = P + sig;
  float g  = sp->g_in;
  float b0 = sp->cb0[0]*g, b1 = sp->cb1[0]*g, b2 = sp->cb2[0]*g;
  float a1 = sp->ca1[0], a2 = sp->ca2[0];
  const float* xp = in + (size_t)sig*SEQ + (size_t)c*L;
  float xm1=0.f, xm2=0.f;
  if (c){ xm1 = xp[-1]; xm2 = xp[-2]; }
  float ym1=0.f, ym2=0.f;
  for (int i=0;i<L;i+=4){
    float4 v = *(const float4*)(xp+i);
    float t0, y;
    t0 = fmaf(b0,v.x, fmaf(b1,xm1, fmaf(b2,xm2, -a2*ym2))); y = fmaf(-a1,ym1,t0); xm2=xm1;xm1=v.x;ym2=ym1;ym1=y;
    t0 = fmaf(b0,v.y, fmaf(b1,xm1, fmaf(b2,xm2, -a2*ym2))); y = fmaf(-a1,ym1,t0); xm2=xm1;xm1=v.y;ym2=ym1;ym1=y;
    t0 = fmaf(b0,v.z, fmaf(b1,xm1, fmaf(b2,xm2, -a2*ym2))); y = fmaf(-a1,ym1,t0); xm2=xm1;xm1=v.z;ym2=ym1;ym1=y;
    t0 = fmaf(b0,v.w, fmaf(b1,xm1, fmaf(b2,xm2, -a2*ym2))); y = fmaf(-a1,ym1,t0); xm2=xm1;xm1=v.w;ym2=ym1;ym1=y;
  }
  endst[tid] = make_float2(ym1, ym2);
}

// ---------------- 2-state chunk scan (double) ----------------
__global__ __launch_bounds__(256) void k_scan2(const float2* __restrict__ endst, float2* __restrict__ inits,
    const MatP* __restrict__ M, int sec, int nsig, int C, int G)
{
  __shared__ float2 sb[4096];
  int s0 = blockIdx.x*G;
  int total = G*C;
  for (int i=threadIdx.x; i<total; i+=256){
    int gi = s0*C + i;
    sb[i] = (gi < nsig*C) ? endst[gi] : make_float2(0.f,0.f);
  }
  __syncthreads();
  int g = threadIdx.x;
  if (g < G && (s0+g) < nsig){
    MatP m = M[(s0+g)*6 + sec];
    double sx=0.0, sy=0.0;
    float2* op = inits + (size_t)(s0+g)*C;
    const float2* dp = sb + g*C;
    for (int c=0;c<C;c++){
      op[c] = make_float2((float)sx,(float)sy);
      float2 d = dp[c];
      double tx = m.m00*sx + m.m01*sy + (double)d.x;
      double ty = m.m10*sx + m.m11*sy + (double)d.y;
      sx=tx; sy=ty;
    }
  }
}

// ---------------- 1-state chunk scan (smoother) ----------------
__global__ __launch_bounds__(256) void k_scan1(const float* __restrict__ endst, float* __restrict__ inits,
    const double* __restrict__ aL, int nsig, int C, int G)
{
  __shared__ float sb[8192];
  int s0 = blockIdx.x*G;
  int total = G*C;
  for (int i=threadIdx.x; i<total; i+=256){
    int gi = s0*C + i;
    sb[i] = (gi < nsig*C) ? endst[gi] : 0.f;
  }
  __syncthreads();
  int g = threadIdx.x;
  if (g < G && (s0+g) < nsig){
    double a = aL[s0+g];
    double s = 0.0;
    float* op = inits + (size_t)(s0+g)*C;
    const float* dp = sb + g*C;
    for (int c=0;c<C;c++){
      op[c] = (float)s;
      s = a*s + (double)dp[c];
    }
  }
}

// ---------------- biquad re-run (C-pass), fused next-section d ----------------
template<bool LAST>
__global__ __launch_bounds__(256) void k_eqC(const float* __restrict__ in, float* __restrict__ out,
    const SigP* __restrict__ P, int sec, const float2* __restrict__ inits,
    float2* __restrict__ endn2, float* __restrict__ endn1, int nsig, int C, int L)
{
  int tid = blockIdx.x*256 + threadIdx.x;
  if (tid >= nsig*C) return;
  int sig = tid / C, c = tid - sig*C;
  const SigP* sp = P + sig;
  float g  = (sec==0) ? sp->g_in : 1.f;
  float b0 = sp->cb0[sec]*g, b1 = sp->cb1[sec]*g, b2 = sp->cb2[sec]*g;
  float a1 = sp->ca1[sec], a2 = sp->ca2[sec];
  size_t base = (size_t)sig*SEQ + (size_t)c*L;
  const float* xp = in + base;
  float* op = out + base;
  float xm1=0.f, xm2=0.f;
  if (c){ xm1 = xp[-1]; xm2 = xp[-2]; }
  float2 s0 = inits[tid];
  float ym1 = s0.x, ym2 = s0.y;
  float nb0=0,nb1=0,nb2=0,na1=0,na2=0,pxm1=0,pxm2=0,pym1=0,pym2=0;
  float al=0,oma=0,th=0,invr=0,kn=0,gacc=0;
  if (!LAST){
    nb0=sp->cb0[sec+1]; nb1=sp->cb1[sec+1]; nb2=sp->cb2[sec+1];
    na1=sp->ca1[sec+1]; na2=sp->ca2[sec+1];
    pxm1=s0.x; pxm2=s0.y;
  } else {
    al=sp->alpha; oma=sp->oma; th=sp->th; invr=sp->invr; kn=sp->knee;
  }
  for (int i=0;i<L;i+=4){
    float4 v = *(const float4*)(xp+i);
    float4 o;
    #pragma unroll
    for (int u=0;u<4;u++){
      float x = (u==0)?v.x:(u==1)?v.y:(u==2)?v.z:v.w;
      float t0 = fmaf(b0,x, fmaf(b1,xm1, fmaf(b2,xm2, -a2*ym2)));
      float y  = fmaf(-a1,ym1,t0);
      xm2=xm1; xm1=x; ym2=ym1; ym1=y;
      if (u==0) o.x=y; else if (u==1) o.y=y; else if (u==2) o.z=y; else o.w=y;
      if (!LAST){
        float t1 = fmaf(nb0,y, fmaf(nb1,pxm1, fmaf(nb2,pxm2, -na2*pym2)));
        float z  = fmaf(-na1,pym1,t1);
        pxm2=pxm1; pxm1=y; pym2=pym1; pym1=z;
      } else {
        gacc = fmaf(al, gacc, oma*comp_gc(y,th,invr,kn));
      }
    }
    *(float4*)(op+i) = o;
  }
  if (!LAST) endn2[tid] = make_float2(pym1,pym2);
  else       endn1[tid] = gacc;
}

// ---------------- smoother re-run: y5 -> g_s ----------------
__global__ __launch_bounds__(256) void k_smooth(const float* __restrict__ yin, float* __restrict__ gout,
    const SigP* __restrict__ P, const float* __restrict__ inits1, int nsig, int C, int L)
{
  int tid = blockIdx.x*256 + threadIdx.x;
  if (tid >= nsig*C) return;
  int sig = tid / C, c = tid - sig*C;
  const SigP* sp = P + sig;
  float al=sp->alpha, oma=sp->oma, th=sp->th, invr=sp->invr, kn=sp->knee;
  size_t base = (size_t)sig*SEQ + (size_t)c*L;
  const float* xp = yin + base;
  float* op = gout + base;
  float gsv = inits1[tid];
  for (int i=0;i<L;i+=4){
    float4 v = *(const float4*)(xp+i);
    float4 o;
    gsv = fmaf(al, gsv, oma*comp_gc(v.x,th,invr,kn)); o.x=gsv;
    gsv = fmaf(al, gsv, oma*comp_gc(v.y,th,invr,kn)); o.y=gsv;
    gsv = fmaf(al, gsv, oma*comp_gc(v.z,th,invr,kn)); o.z=gsv;
    gsv = fmaf(al, gsv, oma*comp_gc(v.w,th,invr,kn)); o.w=gsv;
    *(float4*)(op+i) = o;
  }
}

// ---------------- apply compressor gain (+lookahead, +out gain) ----------------
__global__ __launch_bounds__(256) void k_comp(const float* __restrict__ y, const float* __restrict__ gs,
    const SigP* __restrict__ P, float* __restrict__ outp, int la)
{
  int q = blockIdx.x*256 + threadIdx.x;
  int sig = q / (SEQ/4);
  int n   = (q - sig*(SEQ/4))*4;
  const SigP* sp = P + sig;
  float mk = sp->makeup, go = sp->g_out;
  size_t base = (size_t)sig*SEQ;
  float4 v = *(const float4*)(y+base+n);
  float4 gv;
  int nl = n + la;
  if (nl+3 <= SEQ-1) gv = *(const float4*)(gs+base+nl);
  else {
    int i0=nl,i1=nl+1,i2=nl+2,i3=nl+3;
    if(i0>SEQ-1)i0=SEQ-1; if(i1>SEQ-1)i1=SEQ-1; if(i2>SEQ-1)i2=SEQ-1; if(i3>SEQ-1)i3=SEQ-1;
    gv.x=gs[base+i0]; gv.y=gs[base+i1]; gv.z=gs[base+i2]; gv.w=gs[base+i3];
  }
  float4 o;
  o.x = v.x * __builtin_exp2f((gv.x+mk)*C_DB) * go;
  o.y = v.y * __builtin_exp2f((gv.y+mk)*C_DB) * go;
  o.z = v.z * __builtin_exp2f((gv.z+mk)*C_DB) * go;
  o.w = v.w * __builtin_exp2f((gv.w+mk)*C_DB) * go;
  *(float4*)(outp+base+n) = o;
}

// ---------------- pan + master/fx sums ----------------
__global__ __launch_bounds__(256) void k_pan(const float* __restrict__ y, const SigP* __restrict__ P,
    float* __restrict__ panned, float* __restrict__ m0, float* __restrict__ fx)
{
  int q = blockIdx.x*256 + threadIdx.x;   // BS*SEQ/4 threads
  int b = q / (SEQ/4);
  int n = (q - b*(SEQ/4))*4;
  float4 aL={0,0,0,0}, aR={0,0,0,0}, fL={0,0,0,0}, fR={0,0,0,0};
  for (int t=0;t<16;t++){
    const SigP* sp = P + b*16 + t;
    float gl=sp->gl, gr=sp->gr, sd=sp->send;
    float4 v = *(const float4*)(y + (size_t)(b*16+t)*SEQ + n);
    float4 pl = { v.x*gl, v.y*gl, v.z*gl, v.w*gl };
    float4 pr = { v.x*gr, v.y*gr, v.z*gr, v.w*gr };
    *(float4*)(panned + (size_t)(b*32+t)*SEQ + n)    = pl;
    *(float4*)(panned + (size_t)(b*32+16+t)*SEQ + n) = pr;
    aL.x+=pl.x; aL.y+=pl.y; aL.z+=pl.z; aL.w+=pl.w;
    aR.x+=pr.x; aR.y+=pr.y; aR.z+=pr.z; aR.w+=pr.w;
    fL.x=fmaf(pl.x,sd,fL.x); fL.y=fmaf(pl.y,sd,fL.y); fL.z=fmaf(pl.z,sd,fL.z); fL.w=fmaf(pl.w,sd,fL.w);
    fR.x=fmaf(pr.x,sd,fR.x); fR.y=fmaf(pr.y,sd,fR.y); fR.z=fmaf(pr.z,sd,fR.z); fR.w=fmaf(pr.w,sd,fR.w);
  }
  *(float4*)(m0 + (size_t)(b*2+0)*SEQ + n) = aL;
  *(float4*)(m0 + (size_t)(b*2+1)*SEQ + n) = aR;
  *(float4*)(fx + (size_t)(b*2+0)*SEQ + n) = fL;
  *(float4*)(fx + (size_t)(b*2+1)*SEQ + n) = fR;
}

// ---------------- reverb band FIR: filt = valid(conv(noise, fb)) ----------------
__global__ __launch_bounds__(256) void k_fir(const float* __restrict__ noise, const float* __restrict__ fb,
    float* __restrict__ filt)
{
  __shared__ alignas(16) float sx[3072];
  __shared__ alignas(16) float sf[1024];
  int sig = blockIdx.x >> 5;            // 48 sigs, 32 blocks each
  int n0  = (blockIdx.x & 31) * 2048;
  int band = sig % 12;
  const float* np_ = noise + (size_t)sig*NOISE_LEN + n0;
  for (int i=threadIdx.x; i<3072; i+=256) sx[i] = (i<3070) ? np_[i] : 0.f;
  for (int i=threadIdx.x; i<1024; i+=256) sf[i] = (i<1023) ? fb[band*TAPS + 1022 - i] : 0.f;
  __syncthreads();
  int t = threadIdx.x;
  float acc[8];
  #pragma unroll
  for (int j=0;j<8;j++) acc[j]=0.f;
  float w[16];
  int wb = 8*t;
  #pragma unroll
  for (int m=0;m<16;m+=4){
    float4 qq = *(const float4*)(sx+wb+m);
    w[m]=qq.x; w[m+1]=qq.y; w[m+2]=qq.z; w[m+3]=qq.w;
  }
  for (int ut=0; ut<128; ut++){
    float4 f0 = *(const float4*)(sf + 8*ut);
    float4 f1 = *(const float4*)(sf + 8*ut + 4);
    float f[8] = {f0.x,f0.y,f0.z,f0.w,f1.x,f1.y,f1.z,f1.w};
    #pragma unroll
    for (int d=0;d<8;d++)
      #pragma unroll
      for (int j=0;j<8;j++)
        acc[j] = fmaf(f[d], w[j+d], acc[j]);
    if (ut<127){
      #pragma unroll
      for (int m=0;m<8;m++) w[m]=w[m+8];
      float4 q0 = *(const float4*)(sx + wb + 8*ut + 16);
      float4 q1 = *(const float4*)(sx + wb + 8*ut + 20);
      w[8]=q0.x; w[9]=q0.y; w[10]=q0.z; w[11]=q0.w;
      w[12]=q1.x; w[13]=q1.y; w[14]=q1.z; w[15]=q1.w;
    }
  }
  float* op = filt + (size_t)sig*REV_N + n0 + 8*t;
  float4 o0={acc[0],acc[1],acc[2],acc[3]}, o1={acc[4],acc[5],acc[6],acc[7]};
  *(float4*)(op)   = o0;
  *(float4*)(op+4) = o1;
}

// ---------------- ir = mean over bands of filt*env*gain ----------------
__global__ __launch_bounds__(256) void k_ir(const float* __restrict__ filt, const float* __restrict__ fxp,
    float* __restrict__ ir)
{
  int q = blockIdx.x*256 + threadIdx.x;   // 4*REV_N/4 threads
  int sig = q / (REV_N/4);
  int i   = (q - sig*(REV_N/4))*4;
  int b = sig >> 1;
  float4 acc={0,0,0,0};
  const float ts = 1.0f/65535.0f;
  for (int band=0; band<12; band++){
    float gn  = fxp[b*25 + band];
    float dec = fxp[b*25 + 12 + band]*10.f + 1.f;
    float4 f = *(const float4*)(filt + ((size_t)(sig*12+band))*REV_N + i);
    float s = -dec*ts;
    float e0=expf(s*(float)i), e1=expf(s*(float)(i+1)), e2=expf(s*(float)(i+2)), e3=expf(s*(float)(i+3));
    acc.x = fmaf(gn*e0, f.x, acc.x);
    acc.y = fmaf(gn*e1, f.y, acc.y);
    acc.z = fmaf(gn*e2, f.z, acc.z);
    acc.w = fmaf(gn*e3, f.w, acc.w);
  }
  const float inv12 = 1.f/12.f;
  acc.x*=inv12; acc.y*=inv12; acc.z*=inv12; acc.w*=inv12;
  *(float4*)(ir + (size_t)sig*REV_N + i) = acc;
}

// ---------------- wet conv (65536 taps) + mix + add to master ----------------
__global__ __launch_bounds__(256) void k_wet(const float* __restrict__ fx, const float* __restrict__ ir,
    const float* __restrict__ m0, const float* __restrict__ fxp, float* __restrict__ m1)
{
  __shared__ alignas(16) float sx[3072];
  __shared__ alignas(16) float si[1024];
  int sig = blockIdx.x >> 7;            // 4 sigs * 128 blocks
  int n0  = (blockIdx.x & 127) * 2048;
  int b = sig >> 1;
  float mix = fxp[b*25+24];
  const float* xs  = fx + (size_t)sig*SEQ;
  const float* irs = ir + (size_t)sig*REV_N;
  int t = threadIdx.x;
  float acc[8];
  #pragma unroll
  for (int j=0;j<8;j++) acc[j]=0.f;
  for (int kt=0; kt<64; kt++){
    int k0 = kt*1024;
    __syncthreads();
    int gbase = n0 - k0 - 1024;
    for (int i=t*4; i<3072; i+=1024){
      int gi = gbase + i;
      float4 v;
      if (gi >= 0) v = *(const float4*)(xs + gi);
      else         v = make_float4(0.f,0.f,0.f,0.f);
      *(float4*)(sx+i) = v;
    }
    *(float4*)(si + t*4) = *(const float4*)(irs + k0 + t*4);
    __syncthreads();
    float w[16];
    int wb = 8*t + 1016;
    #pragma unroll
    for (int m=0;m<16;m+=4){
      float4 qq = *(const float4*)(sx+wb+m);
      w[m]=qq.x; w[m+1]=qq.y; w[m+2]=qq.z; w[m+3]=qq.w;
    }
    for (int st=0; st<128; st++){
      float4 f0 = *(const float4*)(si + 8*st);
      float4 f1 = *(const float4*)(si + 8*st + 4);
      float f[8] = {f0.x,f0.y,f0.z,f0.w,f1.x,f1.y,f1.z,f1.w};
      #pragma unroll
      for (int d=0;d<8;d++)
        #pragma unroll
        for (int j=0;j<8;j++)
          acc[j] = fmaf(f[d], w[8+j-d], acc[j]);
      if (st<127){
        #pragma unroll
        for (int m=15;m>=8;m--) w[m]=w[m-8];
        int nb = wb - 8*(st+1);
        float4 q0 = *(const float4*)(sx+nb);
        float4 q1 = *(const float4*)(sx+nb+4);
        w[0]=q0.x; w[1]=q0.y; w[2]=q0.z; w[3]=q0.w;
        w[4]=q1.x; w[5]=q1.y; w[6]=q1.z; w[7]=q1.w;
      }
    }
  }
  int n = n0 + 8*t;
  size_t ob = (size_t)sig*SEQ + n;
  float4 w0 = *(const float4*)(m0+ob), w1 = *(const float4*)(m0+ob+4);
  float4 x0 = *(const float4*)(xs+n),  x1 = *(const float4*)(xs+n+4);
  float om = 1.f - mix;
  float4 o0, o1;
  o0.x = w0.x + om*x0.x + mix*acc[0];
  o0.y = w0.y + om*x0.y + mix*acc[1];
  o0.z = w0.z + om*x0.z + mix*acc[2];
  o0.w = w0.w + om*x0.w + mix*acc[3];
  o1.x = w1.x + om*x1.x + mix*acc[4];
  o1.y = w1.y + om*x1.y + mix*acc[5];
  o1.z = w1.z + om*x1.z + mix*acc[6];
  o1.w = w1.w + om*x1.w + mix*acc[7];
  *(float4*)(m1+ob)   = o0;
  *(float4*)(m1+ob+4) = o1;
}

// ---------------- launch ----------------
extern "C" void kernel_launch(void* const* d_in, const int* in_sizes, int n_in,
                              void* d_out, int out_size, void* d_ws, size_t ws_size,
                              hipStream_t stream)
{
  const float* tracks = (const float*)d_in[0];
  const float* tp     = (const float*)d_in[1];
  const float* fxp    = (const float*)d_in[2];
  const float* mp     = (const float*)d_in[3];
  const float* noise  = (const float*)d_in[4];
  const float* fbp    = (const float*)d_in[5];
  float* out = (float*)d_out;
  char* w = (char*)d_ws;

  float*  X   = (float*)(w + OFF_X);
  float*  Y   = (float*)(w + OFF_Y);
  float*  FXb = (float*)(w + OFF_FX);
  float*  M0  = (float*)(w + OFF_M0);
  float2* E2  = (float2*)(w + OFF_E2);
  float2* I2  = (float2*)(w + OFF_I2);
  float*  E1  = (float*)(w + OFF_E1);
  float*  I1  = (float*)(w + OFF_I1);
  SigP*   Pt  = (SigP*)(w + OFF_PT);
  SigP*   Pm  = (SigP*)(w + OFF_PM);
  MatP*   Mt  = (MatP*)(w + OFF_MT);
  MatP*   Mm  = (MatP*)(w + OFF_MM);
  double* aLt = (double*)(w + OFF_ALT);
  double* aLm = (double*)(w + OFF_ALM);
  float*  FILT= (float*)(w + OFF_FILT);
  float*  IR  = (float*)(w + OFF_IR);
  float*  XM  = (float*)(w + OFF_XM);
  float*  YM  = (float*)(w + OFF_YM);
  float*  M1  = (float*)(w + OFF_M1);

  k_params<<<1,64,0,stream>>>(tp, mp, Pt, Pm, Mt, Mm, aLt, aLm);

  // ---- track chain: nsig=32, L=512, C=512 ----
  const int GT = NS_T*C_T/256;   // 64 blocks
  k_eqA0<<<GT,256,0,stream>>>(tracks, Pt, E2, NS_T, C_T, L_T);
  k_scan2<<<4,256,0,stream>>>(E2, I2, Mt, 0, NS_T, C_T, 8);
  k_eqC<false><<<GT,256,0,stream>>>(tracks, X, Pt, 0, I2, E2, nullptr, NS_T, C_T, L_T);
  k_scan2<<<4,256,0,stream>>>(E2, I2, Mt, 1, NS_T, C_T, 8);
  k_eqC<false><<<GT,256,0,stream>>>(X, Y, Pt, 1, I2, E2, nullptr, NS_T, C_T, L_T);
  k_scan2<<<4,256,0,stream>>>(E2, I2, Mt, 2, NS_T, C_T, 8);
  k_eqC<false><<<GT,256,0,stream>>>(Y, X, Pt, 2, I2, E2, nullptr, NS_T, C_T, L_T);
  k_scan2<<<4,256,0,stream>>>(E2, I2, Mt, 3, NS_T, C_T, 8);
  k_eqC<false><<<GT,256,0,stream>>>(X, Y, Pt, 3, I2, E2, nullptr, NS_T, C_T, L_T);
  k_scan2<<<4,256,0,stream>>>(E2, I2, Mt, 4, NS_T, C_T, 8);
  k_eqC<false><<<GT,256,0,stream>>>(Y, X, Pt, 4, I2, E2, nullptr, NS_T, C_T, L_T);
  k_scan2<<<4,256,0,stream>>>(E2, I2, Mt, 5, NS_T, C_T, 8);
  k_eqC<true><<<GT,256,0,stream>>>(X, Y, Pt, 5, I2, nullptr, E1, NS_T, C_T, L_T);
  k_scan1<<<2,256,0,stream>>>(E1, I1, aLt, NS_T, C_T, 16);
  k_smooth<<<GT,256,0,stream>>>(Y, X, Pt, I1, NS_T, C_T, L_T);
  k_comp<<<NS_T*(SEQ/4)/256,256,0,stream>>>(Y, X, Pt, Y, 2048);
  k_pan<<<2*(SEQ/4)/256,256,0,stream>>>(Y, Pt, out, M0, FXb);

  // ---- reverb ----
  k_fir<<<48*32,256,0,stream>>>(noise, fbp, FILT);
  k_ir<<<4*(REV_N/4)/256,256,0,stream>>>(FILT, fxp, IR);
  k_wet<<<4*128,256,0,stream>>>(FXb, IR, M0, fxp, M1);

  // ---- master chain: nsig=4, L=256, C=1024 ----
  const int GM = NS_M*C_M/256;   // 16 blocks
  k_eqA0<<<GM,256,0,stream>>>(M1, Pm, E2, NS_M, C_M, L_M);
  k_scan2<<<1,256,0,stream>>>(E2, I2, Mm, 0, NS_M, C_M, 4);
  k_eqC<false><<<GM,256,0,stream>>>(M1, XM, Pm, 0, I2, E2, nullptr, NS_M, C_M, L_M);
  k_scan2<<<1,256,0,stream>>>(E2, I2, Mm, 1, NS_M, C_M, 4);
  k_eqC<false><<<GM,256,0,stream>>>(XM, YM, Pm, 1, I2, E2, nullptr, NS_M, C_M, L_M);
  k_scan2<<<1,256,0,stream>>>(E2, I2, Mm, 2, NS_M, C_M, 4);
  k_eqC<false><<<GM,256,0,stream>>>(YM, XM, Pm, 2, I2, E2, nullptr, NS_M, C_M, L_M);
  k_scan2<<<1,256,0,stream>>>(E2, I2, Mm, 3, NS_M, C_M, 4);
  k_eqC<false><<<GM,256,0,stream>>>(XM, YM, Pm, 3, I2, E2, nullptr, NS_M, C_M, L_M);
  k_scan2<<<1,256,0,stream>>>(E2, I2, Mm, 4, NS_M, C_M, 4);
  k_eqC<false><<<GM,256,0,stream>>>(YM, XM, Pm, 4, I2, E2, nullptr, NS_M, C_M, L_M);
  k_scan2<<<1,256,0,stream>>>(E2, I2, Mm, 5, NS_M, C_M, 4);
  k_eqC<true><<<GM,256,0,stream>>>(XM, YM, Pm, 5, I2, nullptr, E1, NS_M, C_M, L_M);
  k_scan1<<<1,256,0,stream>>>(E1, I1, aLm, NS_M, C_M, 4);
  k_smooth<<<GM,256,0,stream>>>(YM, XM, Pm, I1, NS_M, C_M, L_M);
  k_comp<<<NS_M*(SEQ/4)/256,256,0,stream>>>(YM, XM, Pm, out + OUT_MASTER_OFF, 1024);
}

// Round 4
// 3104.877 us; speedup vs baseline: 1.7886x; 1.7886x over previous
//
#include <hip/hip_runtime.h>

#define DEVFN __device__ __forceinline__

constexpr int SEQ = 262144;
constexpr int REV_N = 65536;
constexpr int TAPS = 1023;
constexpr int NOISE_LEN = REV_N + TAPS - 1;   // 66558

constexpr int NS_T = 32, L_T = 512, C_T = 512;
constexpr int NS_M = 4,  L_M = 256, C_M = 1024;

// output layout: panned = B*2*NT*SEQ = 16,777,216 floats, then master = B*2*SEQ
constexpr int OUT_MASTER_OFF = 16777216;

constexpr int WET_BN = 4096;   // outputs per block
constexpr int WET_KT = 16;     // 1024-tap tiles per k-partition (4 partitions)

#define C_DB  0.16609640474436813f   /* log2(10)/20 */
#define C_LOG 6.0205999132796239f    /* 20*log10(2) */
#define PI_D  3.14159265358979323846

struct SigP {
  float g_in;
  float cb0[6], cb1[6], cb2[6], ca1[6], ca2[6];
  float alpha, oma;
  float th, invr, knee, makeup;
  float g_out;
  float gl, gr, send;
};
struct MatP { double m00, m01, m10, m11; };

// ---------------- workspace layout (bytes) ----------------
constexpr size_t OFF_X   = 0;                       // 33,554,432
constexpr size_t OFF_Y   = 33554432;                // 33,554,432
constexpr size_t OFF_FX  = 67108864;                // 4 MB  (B,2,S)
constexpr size_t OFF_M0  = 71303168;                // 4 MB
constexpr size_t OFF_E2  = 75497472;                // float2[16384]
constexpr size_t OFF_I2  = OFF_E2 + 131072;
constexpr size_t OFF_E1  = OFF_I2 + 131072;         // float[16384]
constexpr size_t OFF_I1  = OFF_E1 + 65536;
constexpr size_t OFF_PT  = OFF_I1 + 65536;
constexpr size_t OFF_PM  = OFF_PT + 32*sizeof(SigP);
constexpr size_t OFF_MT  = (OFF_PM + 4*sizeof(SigP) + 7) & ~(size_t)7;
constexpr size_t OFF_MM  = OFF_MT + 32*6*sizeof(MatP);
constexpr size_t OFF_ALT = OFF_MM + 4*6*sizeof(MatP);
constexpr size_t OFF_ALM = OFF_ALT + 32*sizeof(double);
// overlays (X,Y dead after pan):
constexpr size_t OFF_FILT = OFF_X;                       // 48*65536*4 = 12,582,912
constexpr size_t OFF_IR   = OFF_X + 12582912;            // 1 MB
constexpr size_t OFF_XM   = OFF_X + 16777216;            // 4 MB master ping A
constexpr size_t OFF_YM   = OFF_X + 20971520;            // 4 MB master ping B
constexpr size_t OFF_M1   = OFF_Y;                       // 4 MB master input
constexpr size_t OFF_WP   = OFF_Y + 4194304;             // 16 MB wet partials (4 kp x 4 sig x SEQ)

// padded LDS index: one float4 pad per 8 float4s -> strided b128 reads conflict-free
DEVFN int pq(int i){ return i + ((i >> 5) << 2); }

// ---------------- params kernel ----------------
DEVFN double dn(float p, double lo, double hi){ return (double)p*(hi-lo)+lo; }

__device__ void mk_sig(const float* p, int L, int nsq, bool is_master,
                       SigP* sp, MatP* mats, double* aL)
{
  const double flo[6] = {20.,80.,2000.,8000.,12000.,6000.};
  const double fhi[6] = {2000.,2000.,8000.,12000.,21050.,21050.};
  double gdb = dn(p[0], -48., 48.);
  sp->g_in = (float)exp2(gdb * 0.16609640474436813);
  for (int k=0;k<6;k++){
    double g  = dn(p[1+3*k], -12., 12.);
    double fc = dn(p[2+3*k], flo[k], fhi[k]);
    double q  = dn(p[3+3*k], 0.1, 5.0);
    double A  = pow(10.0, g/40.0);
    double w0 = 2.0*PI_D*(fc/44100.0);
    double al = sin(w0)/(2.0*q), co = cos(w0), sA = sqrt(A);
    double b0,b1,b2,a0,a1,a2;
    if (k==0){                       // low shelf
      b0 = A*((A+1.0) - (A-1.0)*co + 2.0*sA*al);
      b1 = 2.0*A*((A-1.0) - (A+1.0)*co);
      b2 = A*((A+1.0) - (A-1.0)*co - 2.0*sA*al);
      a0 = (A+1.0) + (A-1.0)*co + 2.0*sA*al;
      a1 = -2.0*((A-1.0) + (A+1.0)*co);
      a2 = (A+1.0) + (A-1.0)*co - 2.0*sA*al;
    } else if (k==5){                // high shelf
      b0 = A*((A+1.0) + (A-1.0)*co + 2.0*sA*al);
      b1 = -2.0*A*((A-1.0) + (A+1.0)*co);
      b2 = A*((A+1.0) + (A-1.0)*co - 2.0*sA*al);
      a0 = (A+1.0) - (A-1.0)*co + 2.0*sA*al;
      a1 = 2.0*((A-1.0) - (A+1.0)*co);
      a2 = (A+1.0) - (A-1.0)*co - 2.0*sA*al;
    } else {                         // peaking
      b0 = 1.0 + al*A; b1 = -2.0*co; b2 = 1.0 - al*A;
      a0 = 1.0 + al/A; a1 = -2.0*co; a2 = 1.0 - al/A;
    }
    double ia0 = 1.0/a0;
    double na1 = a1*ia0, na2 = a2*ia0;
    sp->cb0[k]=(float)(b0*ia0); sp->cb1[k]=(float)(b1*ia0); sp->cb2[k]=(float)(b2*ia0);
    sp->ca1[k]=(float)na1;      sp->ca2[k]=(float)na2;
    double m00=-na1, m01=-na2, m10=1.0, m11=0.0;
    for (int j=0;j<nsq;j++){
      double t00=m00*m00+m01*m10, t01=m00*m01+m01*m11;
      double t10=m10*m00+m11*m10, t11=m10*m01+m11*m11;
      m00=t00;m01=t01;m10=t10;m11=t11;
    }
    mats[k].m00=m00; mats[k].m01=m01; mats[k].m10=m10; mats[k].m11=m11;
  }
  double th    = dn(p[19], -60., 0.);
  double ratio = dn(p[20], 1., 10.);
  double at    = dn(p[21], 5., 250.);
  double knee  = dn(p[23], 3., 12.);
  double mkup  = dn(p[24], 0., 6.);
  double alpha = exp(-log(9.0)/(44100.0*at*0.001));
  sp->alpha=(float)alpha; sp->oma=(float)(1.0-alpha);
  sp->th=(float)th; sp->invr=(float)(1.0/ratio); sp->knee=(float)knee; sp->makeup=(float)mkup;
  *aL = pow(alpha, (double)L);
  if (is_master){
    sp->g_out = (float)exp2(dn(p[25],-48.,48.)*0.16609640474436813);
    sp->gl=0.f; sp->gr=0.f; sp->send=0.f;
  } else {
    sp->g_out = 1.f;
    sp->send = (float)exp2(dn(p[25],-80.,12.)*0.16609640474436813);
    double th2 = dn(p[26],0.,1.)*(PI_D/2.0);
    sp->gl = (float)sqrt((PI_D/2.0-th2)*(2.0/PI_D)*cos(th2));
    sp->gr = (float)sqrt(th2*(2.0/PI_D)*sin(th2));
  }
}

__global__ __launch_bounds__(64) void k_params(const float* __restrict__ tp, const float* __restrict__ mp,
    SigP* Pt, SigP* Pm, MatP* Mt, MatP* Mm, double* aLt, double* aLm)
{
  int i = threadIdx.x;
  if (i < 32)       mk_sig(tp + i*27, L_T, 9, false, &Pt[i], &Mt[i*6], &aLt[i]);
  else if (i < 36){ int j=i-32; mk_sig(mp + (j>>1)*26, L_M, 8, true, &Pm[j], &Mm[j*6], &aLm[j]); }
}

// ---------------- compressor gain computer ----------------
DEVFN float comp_gc(float y, float th, float invr, float kn){
  float av  = fmaxf(fabsf(y), 1e-8f);
  float xdb = C_LOG * __builtin_log2f(av);
  float d   = xdb - th;
  float w = (2.f*d < -kn) ? 0.f
          : ((2.f*fabsf(d) <= kn) ? (d+0.5f*kn)*(d+0.5f*kn)/(2.f*kn) : d);
  return (invr-1.f)*w;
}

// ---------------- section-0 zero-state end (A-pass) ----------------
__global__ __launch_bounds__(256) void k_eqA0(const float* __restrict__ in, const SigP* __restrict__ P,
    float2* __restrict__ endst, int nsig, int C, int L)
{
  int tid = blockIdx.x*256 + threadIdx.x;
  if (tid >= nsig*C) return;
  int sig = tid / C, c = tid - sig*C;
  const SigP* sp = P + sig;
  float g  = sp->g_in;
  float b0 = sp->cb0[0]*g, b1 = sp->cb1[0]*g, b2 = sp->cb2[0]*g;
  float a1 = sp->ca1[0], a2 = sp->ca2[0];
  const float* xp = in + (size_t)sig*SEQ + (size_t)c*L;
  float xm1=0.f, xm2=0.f;
  if (c){ xm1 = xp[-1]; xm2 = xp[-2]; }
  float ym1=0.f, ym2=0.f;
  for (int i=0;i<L;i+=4){
    float4 v = *(const float4*)(xp+i);
    float t0, y;
    t0 = fmaf(b0,v.x, fmaf(b1,xm1, fmaf(b2,xm2, -a2*ym2))); y = fmaf(-a1,ym1,t0); xm2=xm1;xm1=v.x;ym2=ym1;ym1=y;
    t0 = fmaf(b0,v.y, fmaf(b1,xm1, fmaf(b2,xm2, -a2*ym2))); y = fmaf(-a1,ym1,t0); xm2=xm1;xm1=v.y;ym2=ym1;ym1=y;
    t0 = fmaf(b0,v.z, fmaf(b1,xm1, fmaf(b2,xm2, -a2*ym2))); y = fmaf(-a1,ym1,t0); xm2=xm1;xm1=v.z;ym2=ym1;ym1=y;
    t0 = fmaf(b0,v.w, fmaf(b1,xm1, fmaf(b2,xm2, -a2*ym2))); y = fmaf(-a1,ym1,t0); xm2=xm1;xm1=v.w;ym2=ym1;ym1=y;
  }
  endst[tid] = make_float2(ym1, ym2);
}

// ---------------- 2-state chunk scan (double) ----------------
__global__ __launch_bounds__(256) void k_scan2(const float2* __restrict__ endst, float2* __restrict__ inits,
    const MatP* __restrict__ M, int sec, int nsig, int C, int G)
{
  __shared__ float2 sb[4096];
  int s0 = blockIdx.x*G;
  int total = G*C;
  for (int i=threadIdx.x; i<total; i+=256){
    int gi = s0*C + i;
    sb[i] = (gi < nsig*C) ? endst[gi] : make_float2(0.f,0.f);
  }
  __syncthreads();
  int g = threadIdx.x;
  if (g < G && (s0+g) < nsig){
    MatP m = M[(s0+g)*6 + sec];
    double sx=0.0, sy=0.0;
    float2* op = inits + (size_t)(s0+g)*C;
    const float2* dp = sb + g*C;
    for (int c=0;c<C;c++){
      op[c] = make_float2((float)sx,(float)sy);
      float2 d = dp[c];
      double tx = m.m00*sx + m.m01*sy + (double)d.x;
      double ty = m.m10*sx + m.m11*sy + (double)d.y;
      sx=tx; sy=ty;
    }
  }
}

// ---------------- 1-state chunk scan (smoother) ----------------
__global__ __launch_bounds__(256) void k_scan1(const float* __restrict__ endst, float* __restrict__ inits,
    const double* __restrict__ aL, int nsig, int C, int G)
{
  __shared__ float sb[8192];
  int s0 = blockIdx.x*G;
  int total = G*C;
  for (int i=threadIdx.x; i<total; i+=256){
    int gi = s0*C + i;
    sb[i] = (gi < nsig*C) ? endst[gi] : 0.f;
  }
  __syncthreads();
  int g = threadIdx.x;
  if (g < G && (s0+g) < nsig){
    double a = aL[s0+g];
    double s = 0.0;
    float* op = inits + (size_t)(s0+g)*C;
    const float* dp = sb + g*C;
    for (int c=0;c<C;c++){
      op[c] = (float)s;
      s = a*s + (double)dp[c];
    }
  }
}

// ---------------- biquad re-run (C-pass), fused next-section d ----------------
template<bool LAST>
__global__ __launch_bounds__(256) void k_eqC(const float* __restrict__ in, float* __restrict__ out,
    const SigP* __restrict__ P, int sec, const float2* __restrict__ inits,
    float2* __restrict__ endn2, float* __restrict__ endn1, int nsig, int C, int L)
{
  int tid = blockIdx.x*256 + threadIdx.x;
  if (tid >= nsig*C) return;
  int sig = tid / C, c = tid - sig*C;
  const SigP* sp = P + sig;
  float g  = (sec==0) ? sp->g_in : 1.f;
  float b0 = sp->cb0[sec]*g, b1 = sp->cb1[sec]*g, b2 = sp->cb2[sec]*g;
  float a1 = sp->ca1[sec], a2 = sp->ca2[sec];
  size_t base = (size_t)sig*SEQ + (size_t)c*L;
  const float* xp = in + base;
  float* op = out + base;
  float xm1=0.f, xm2=0.f;
  if (c){ xm1 = xp[-1]; xm2 = xp[-2]; }
  float2 s0 = inits[tid];
  float ym1 = s0.x, ym2 = s0.y;
  float nb0=0,nb1=0,nb2=0,na1=0,na2=0,pxm1=0,pxm2=0,pym1=0,pym2=0;
  float al=0,oma=0,th=0,invr=0,kn=0,gacc=0;
  if (!LAST){
    nb0=sp->cb0[sec+1]; nb1=sp->cb1[sec+1]; nb2=sp->cb2[sec+1];
    na1=sp->ca1[sec+1]; na2=sp->ca2[sec+1];
    pxm1=s0.x; pxm2=s0.y;
  } else {
    al=sp->alpha; oma=sp->oma; th=sp->th; invr=sp->invr; kn=sp->knee;
  }
  for (int i=0;i<L;i+=4){
    float4 v = *(const float4*)(xp+i);
    float4 o;
    #pragma unroll
    for (int u=0;u<4;u++){
      float x = (u==0)?v.x:(u==1)?v.y:(u==2)?v.z:v.w;
      float t0 = fmaf(b0,x, fmaf(b1,xm1, fmaf(b2,xm2, -a2*ym2)));
      float y  = fmaf(-a1,ym1,t0);
      xm2=xm1; xm1=x; ym2=ym1; ym1=y;
      if (u==0) o.x=y; else if (u==1) o.y=y; else if (u==2) o.z=y; else o.w=y;
      if (!LAST){
        float t1 = fmaf(nb0,y, fmaf(nb1,pxm1, fmaf(nb2,pxm2, -na2*pym2)));
        float z  = fmaf(-na1,pym1,t1);
        pxm2=pxm1; pxm1=y; pym2=pym1; pym1=z;
      } else {
        gacc = fmaf(al, gacc, oma*comp_gc(y,th,invr,kn));
      }
    }
    *(float4*)(op+i) = o;
  }
  if (!LAST) endn2[tid] = make_float2(pym1,pym2);
  else       endn1[tid] = gacc;
}

// ---------------- smoother re-run: y5 -> g_s ----------------
__global__ __launch_bounds__(256) void k_smooth(const float* __restrict__ yin, float* __restrict__ gout,
    const SigP* __restrict__ P, const float* __restrict__ inits1, int nsig, int C, int L)
{
  int tid = blockIdx.x*256 + threadIdx.x;
  if (tid >= nsig*C) return;
  int sig = tid / C, c = tid - sig*C;
  const SigP* sp = P + sig;
  float al=sp->alpha, oma=sp->oma, th=sp->th, invr=sp->invr, kn=sp->knee;
  size_t base = (size_t)sig*SEQ + (size_t)c*L;
  const float* xp = yin + base;
  float* op = gout + base;
  float gsv = inits1[tid];
  for (int i=0;i<L;i+=4){
    float4 v = *(const float4*)(xp+i);
    float4 o;
    gsv = fmaf(al, gsv, oma*comp_gc(v.x,th,invr,kn)); o.x=gsv;
    gsv = fmaf(al, gsv, oma*comp_gc(v.y,th,invr,kn)); o.y=gsv;
    gsv = fmaf(al, gsv, oma*comp_gc(v.z,th,invr,kn)); o.z=gsv;
    gsv = fmaf(al, gsv, oma*comp_gc(v.w,th,invr,kn)); o.w=gsv;
    *(float4*)(op+i) = o;
  }
}

// ---------------- apply compressor gain (+lookahead, +out gain) ----------------
__global__ __launch_bounds__(256) void k_comp(const float* __restrict__ y, const float* __restrict__ gs,
    const SigP* __restrict__ P, float* __restrict__ outp, int la)
{
  int q = blockIdx.x*256 + threadIdx.x;
  int sig = q / (SEQ/4);
  int n   = (q - sig*(SEQ/4))*4;
  const SigP* sp = P + sig;
  float mk = sp->makeup, go = sp->g_out;
  size_t base = (size_t)sig*SEQ;
  float4 v = *(const float4*)(y+base+n);
  float4 gv;
  int nl = n + la;
  if (nl+3 <= SEQ-1) gv = *(const float4*)(gs+base+nl);
  else {
    int i0=nl,i1=nl+1,i2=nl+2,i3=nl+3;
    if(i0>SEQ-1)i0=SEQ-1; if(i1>SEQ-1)i1=SEQ-1; if(i2>SEQ-1)i2=SEQ-1; if(i3>SEQ-1)i3=SEQ-1;
    gv.x=gs[base+i0]; gv.y=gs[base+i1]; gv.z=gs[base+i2]; gv.w=gs[base+i3];
  }
  float4 o;
  o.x = v.x * __builtin_exp2f((gv.x+mk)*C_DB) * go;
  o.y = v.y * __builtin_exp2f((gv.y+mk)*C_DB) * go;
  o.z = v.z * __builtin_exp2f((gv.z+mk)*C_DB) * go;
  o.w = v.w * __builtin_exp2f((gv.w+mk)*C_DB) * go;
  *(float4*)(outp+base+n) = o;
}

// ---------------- pan + master/fx sums ----------------
__global__ __launch_bounds__(256) void k_pan(const float* __restrict__ y, const SigP* __restrict__ P,
    float* __restrict__ panned, float* __restrict__ m0, float* __restrict__ fx)
{
  int q = blockIdx.x*256 + threadIdx.x;   // BS*SEQ/4 threads
  int b = q / (SEQ/4);
  int n = (q - b*(SEQ/4))*4;
  float4 aL={0,0,0,0}, aR={0,0,0,0}, fL={0,0,0,0}, fR={0,0,0,0};
  for (int t=0;t<16;t++){
    const SigP* sp = P + b*16 + t;
    float gl=sp->gl, gr=sp->gr, sd=sp->send;
    float4 v = *(const float4*)(y + (size_t)(b*16+t)*SEQ + n);
    float4 pl = { v.x*gl, v.y*gl, v.z*gl, v.w*gl };
    float4 pr = { v.x*gr, v.y*gr, v.z*gr, v.w*gr };
    *(float4*)(panned + (size_t)(b*32+t)*SEQ + n)    = pl;
    *(float4*)(panned + (size_t)(b*32+16+t)*SEQ + n) = pr;
    aL.x+=pl.x; aL.y+=pl.y; aL.z+=pl.z; aL.w+=pl.w;
    aR.x+=pr.x; aR.y+=pr.y; aR.z+=pr.z; aR.w+=pr.w;
    fL.x=fmaf(pl.x,sd,fL.x); fL.y=fmaf(pl.y,sd,fL.y); fL.z=fmaf(pl.z,sd,fL.z); fL.w=fmaf(pl.w,sd,fL.w);
    fR.x=fmaf(pr.x,sd,fR.x); fR.y=fmaf(pr.y,sd,fR.y); fR.z=fmaf(pr.z,sd,fR.z); fR.w=fmaf(pr.w,sd,fR.w);
  }
  *(float4*)(m0 + (size_t)(b*2+0)*SEQ + n) = aL;
  *(float4*)(m0 + (size_t)(b*2+1)*SEQ + n) = aR;
  *(float4*)(fx + (size_t)(b*2+0)*SEQ + n) = fL;
  *(float4*)(fx + (size_t)(b*2+1)*SEQ + n) = fR;
}

// ---------------- reverb band FIR: filt = valid(conv(noise, fb)) ----------------
__global__ __launch_bounds__(256) void k_fir(const float* __restrict__ noise, const float* __restrict__ fb,
    float* __restrict__ filt)
{
  __shared__ alignas(16) float sx[3456];
  __shared__ alignas(16) float sf[1152];
  int sig = blockIdx.x >> 5;            // 48 sigs, 32 blocks each
  int n0  = (blockIdx.x & 31) * 2048;
  int band = sig % 12;
  const float* np_ = noise + (size_t)sig*NOISE_LEN + n0;
  for (int i=threadIdx.x; i<3072; i+=256) sx[pq(i)] = (i<3070) ? np_[i] : 0.f;
  for (int i=threadIdx.x; i<1024; i+=256) sf[pq(i)] = (i<1023) ? fb[band*TAPS + 1022 - i] : 0.f;
  __syncthreads();
  int t = threadIdx.x;
  float acc[8];
  #pragma unroll
  for (int j=0;j<8;j++) acc[j]=0.f;
  float w[16];
  int wb = 8*t;
  #pragma unroll
  for (int m=0;m<16;m+=4){
    float4 qq = *(const float4*)(sx+pq(wb+m));
    w[m]=qq.x; w[m+1]=qq.y; w[m+2]=qq.z; w[m+3]=qq.w;
  }
  for (int ut=0; ut<128; ut++){
    float4 f0 = *(const float4*)(sf + pq(8*ut));
    float4 f1 = *(const float4*)(sf + pq(8*ut + 4));
    float f[8] = {f0.x,f0.y,f0.z,f0.w,f1.x,f1.y,f1.z,f1.w};
    #pragma unroll
    for (int d=0;d<8;d++)
      #pragma unroll
      for (int j=0;j<8;j++)
        acc[j] = fmaf(f[d], w[j+d], acc[j]);
    if (ut<127){
      #pragma unroll
      for (int m=0;m<8;m++) w[m]=w[m+8];
      float4 q0 = *(const float4*)(sx + pq(wb + 8*ut + 16));
      float4 q1 = *(const float4*)(sx + pq(wb + 8*ut + 20));
      w[8]=q0.x; w[9]=q0.y; w[10]=q0.z; w[11]=q0.w;
      w[12]=q1.x; w[13]=q1.y; w[14]=q1.z; w[15]=q1.w;
    }
  }
  float* op = filt + (size_t)sig*REV_N + n0 + 8*t;
  float4 o0={acc[0],acc[1],acc[2],acc[3]}, o1={acc[4],acc[5],acc[6],acc[7]};
  *(float4*)(op)   = o0;
  *(float4*)(op+4) = o1;
}

// ---------------- ir = mean over bands of filt*env*gain ----------------
__global__ __launch_bounds__(256) void k_ir(const float* __restrict__ filt, const float* __restrict__ fxp,
    float* __restrict__ ir)
{
  int q = blockIdx.x*256 + threadIdx.x;   // 4*REV_N/4 threads
  int sig = q / (REV_N/4);
  int i   = (q - sig*(REV_N/4))*4;
  int b = sig >> 1;
  float4 acc={0,0,0,0};
  const float ts = 1.0f/65535.0f;
  for (int band=0; band<12; band++){
    float gn  = fxp[b*25 + band];
    float dec = fxp[b*25 + 12 + band]*10.f + 1.f;
    float4 f = *(const float4*)(filt + ((size_t)(sig*12+band))*REV_N + i);
    float s = -dec*ts;
    float e0=expf(s*(float)i), e1=expf(s*(float)(i+1)), e2=expf(s*(float)(i+2)), e3=expf(s*(float)(i+3));
    acc.x = fmaf(gn*e0, f.x, acc.x);
    acc.y = fmaf(gn*e1, f.y, acc.y);
    acc.z = fmaf(gn*e2, f.z, acc.z);
    acc.w = fmaf(gn*e3, f.w, acc.w);
  }
  const float inv12 = 1.f/12.f;
  acc.x*=inv12; acc.y*=inv12; acc.z*=inv12; acc.w*=inv12;
  *(float4*)(ir + (size_t)sig*REV_N + i) = acc;
}

// ---------------- wet conv partial (16384 taps per block), padded LDS ----------------
__global__ __launch_bounds__(256) void k_wet(const float* __restrict__ fx, const float* __restrict__ ir,
    float* __restrict__ wp)
{
  __shared__ alignas(16) float sx[5760];
  __shared__ alignas(16) float si[1152];
  int bid = blockIdx.x;                  // ((sig*4 + kp)*64 + nb), 1024 blocks
  int nb  = bid & 63;
  int kp  = (bid >> 6) & 3;
  int sig = bid >> 8;
  int n0  = nb * WET_BN;
  int t = threadIdx.x;
  float* op = wp + ((size_t)(kp*4+sig)*SEQ + n0 + 16*t);
  if (n0 + WET_BN - 1 < kp*WET_KT*1024){   // entire block has n < k: zero partial
    float4 z = make_float4(0.f,0.f,0.f,0.f);
    *(float4*)(op) = z; *(float4*)(op+4) = z; *(float4*)(op+8) = z; *(float4*)(op+12) = z;
    return;
  }
  const float* xs  = fx + (size_t)sig*SEQ;
  const float* irs = ir + (size_t)sig*REV_N;
  float acc[16];
  #pragma unroll
  for (int j=0;j<16;j++) acc[j]=0.f;
  for (int kt = kp*WET_KT; kt < kp*WET_KT + WET_KT; kt++){
    int k0 = kt*1024;
    __syncthreads();
    int gbase = n0 - k0 - 1024;
    for (int i=t*4; i<5120; i+=1024){
      int gi = gbase + i;
      float4 v;
      if (gi >= 0) v = *(const float4*)(xs + gi);
      else         v = make_float4(0.f,0.f,0.f,0.f);
      *(float4*)(sx + pq(i)) = v;
    }
    *(float4*)(si + pq(t*4)) = *(const float4*)(irs + k0 + t*4);
    __syncthreads();
    float w[24];
    int wb = 16*t + 1016;
    #pragma unroll
    for (int m=0;m<24;m+=4){
      float4 qq = *(const float4*)(sx + pq(wb+m));
      w[m]=qq.x; w[m+1]=qq.y; w[m+2]=qq.z; w[m+3]=qq.w;
    }
    for (int st=0; st<128; st++){
      float4 f0 = *(const float4*)(si + pq(8*st));
      float4 f1 = *(const float4*)(si + pq(8*st + 4));
      float f[8] = {f0.x,f0.y,f0.z,f0.w,f1.x,f1.y,f1.z,f1.w};
      #pragma unroll
      for (int d=0;d<8;d++)
        #pragma unroll
        for (int j=0;j<16;j++)
          acc[j] = fmaf(f[d], w[8+j-d], acc[j]);
      if (st<127){
        #pragma unroll
        for (int m=23;m>=8;m--) w[m]=w[m-8];
        int nq = wb - 8*(st+1);
        float4 q0 = *(const float4*)(sx + pq(nq));
        float4 q1 = *(const float4*)(sx + pq(nq+4));
        w[0]=q0.x; w[1]=q0.y; w[2]=q0.z; w[3]=q0.w;
        w[4]=q1.x; w[5]=q1.y; w[6]=q1.z; w[7]=q1.w;
      }
    }
  }
  float4 o0={acc[0],acc[1],acc[2],acc[3]},   o1={acc[4],acc[5],acc[6],acc[7]};
  float4 o2={acc[8],acc[9],acc[10],acc[11]}, o3={acc[12],acc[13],acc[14],acc[15]};
  *(float4*)(op)=o0; *(float4*)(op+4)=o1; *(float4*)(op+8)=o2; *(float4*)(op+12)=o3;
}

// ---------------- reduce partials + mix + add to master ----------------
__global__ __launch_bounds__(256) void k_wetred(const float* __restrict__ wp, const float* __restrict__ fx,
    const float* __restrict__ m0, const float* __restrict__ fxp, float* __restrict__ m1)
{
  int q = blockIdx.x*256 + threadIdx.x;   // 4*SEQ/4 threads
  int sig = q / (SEQ/4);
  int n = (q - sig*(SEQ/4))*4;
  float mix = fxp[(sig>>1)*25+24];
  size_t ob = (size_t)sig*SEQ + n;
  float4 p0 = *(const float4*)(wp + ob);
  float4 p1 = *(const float4*)(wp + (size_t)4*SEQ + ob);
  float4 p2 = *(const float4*)(wp + (size_t)8*SEQ + ob);
  float4 p3 = *(const float4*)(wp + (size_t)12*SEQ + ob);
  float4 w0 = *(const float4*)(m0+ob);
  float4 x0 = *(const float4*)(fx+ob);
  float om = 1.f - mix;
  float4 o;
  o.x = w0.x + om*x0.x + mix*(p0.x+p1.x+p2.x+p3.x);
  o.y = w0.y + om*x0.y + mix*(p0.y+p1.y+p2.y+p3.y);
  o.z = w0.z + om*x0.z + mix*(p0.z+p1.z+p2.z+p3.z);
  o.w = w0.w + om*x0.w + mix*(p0.w+p1.w+p2.w+p3.w);
  *(float4*)(m1+ob) = o;
}

// ---------------- launch ----------------
extern "C" void kernel_launch(void* const* d_in, const int* in_sizes, int n_in,
                              void* d_out, int out_size, void* d_ws, size_t ws_size,
                              hipStream_t stream)
{
  const float* tracks = (const float*)d_in[0];
  const float* tp     = (const float*)d_in[1];
  const float* fxp    = (const float*)d_in[2];
  const float* mp     = (const float*)d_in[3];
  const float* noise  = (const float*)d_in[4];
  const float* fbp    = (const float*)d_in[5];
  float* out = (float*)d_out;
  char* w = (char*)d_ws;

  float*  X   = (float*)(w + OFF_X);
  float*  Y   = (float*)(w + OFF_Y);
  float*  FXb = (float*)(w + OFF_FX);
  float*  M0  = (float*)(w + OFF_M0);
  float2* E2  = (float2*)(w + OFF_E2);
  float2* I2  = (float2*)(w + OFF_I2);
  float*  E1  = (float*)(w + OFF_E1);
  float*  I1  = (float*)(w + OFF_I1);
  SigP*   Pt  = (SigP*)(w + OFF_PT);
  SigP*   Pm  = (SigP*)(w + OFF_PM);
  MatP*   Mt  = (MatP*)(w + OFF_MT);
  MatP*   Mm  = (MatP*)(w + OFF_MM);
  double* aLt = (double*)(w + OFF_ALT);
  double* aLm = (double*)(w + OFF_ALM);
  float*  FILT= (float*)(w + OFF_FILT);
  float*  IR  = (float*)(w + OFF_IR);
  float*  XM  = (float*)(w + OFF_XM);
  float*  YM  = (float*)(w + OFF_YM);
  float*  M1  = (float*)(w + OFF_M1);
  float*  WP  = (float*)(w + OFF_WP);

  k_params<<<1,64,0,stream>>>(tp, mp, Pt, Pm, Mt, Mm, aLt, aLm);

  // ---- track chain: nsig=32, L=512, C=512 ----
  const int GT = NS_T*C_T/256;   // 64 blocks
  k_eqA0<<<GT,256,0,stream>>>(tracks, Pt, E2, NS_T, C_T, L_T);
  k_scan2<<<4,256,0,stream>>>(E2, I2, Mt, 0, NS_T, C_T, 8);
  k_eqC<false><<<GT,256,0,stream>>>(tracks, X, Pt, 0, I2, E2, nullptr, NS_T, C_T, L_T);
  k_scan2<<<4,256,0,stream>>>(E2, I2, Mt, 1, NS_T, C_T, 8);
  k_eqC<false><<<GT,256,0,stream>>>(X, Y, Pt, 1, I2, E2, nullptr, NS_T, C_T, L_T);
  k_scan2<<<4,256,0,stream>>>(E2, I2, Mt, 2, NS_T, C_T, 8);
  k_eqC<false><<<GT,256,0,stream>>>(Y, X, Pt, 2, I2, E2, nullptr, NS_T, C_T, L_T);
  k_scan2<<<4,256,0,stream>>>(E2, I2, Mt, 3, NS_T, C_T, 8);
  k_eqC<false><<<GT,256,0,stream>>>(X, Y, Pt, 3, I2, E2, nullptr, NS_T, C_T, L_T);
  k_scan2<<<4,256,0,stream>>>(E2, I2, Mt, 4, NS_T, C_T, 8);
  k_eqC<false><<<GT,256,0,stream>>>(Y, X, Pt, 4, I2, E2, nullptr, NS_T, C_T, L_T);
  k_scan2<<<4,256,0,stream>>>(E2, I2, Mt, 5, NS_T, C_T, 8);
  k_eqC<true><<<GT,256,0,stream>>>(X, Y, Pt, 5, I2, nullptr, E1, NS_T, C_T, L_T);
  k_scan1<<<2,256,0,stream>>>(E1, I1, aLt, NS_T, C_T, 16);
  k_smooth<<<GT,256,0,stream>>>(Y, X, Pt, I1, NS_T, C_T, L_T);
  k_comp<<<NS_T*(SEQ/4)/256,256,0,stream>>>(Y, X, Pt, Y, 2048);
  k_pan<<<2*(SEQ/4)/256,256,0,stream>>>(Y, Pt, out, M0, FXb);

  // ---- reverb ----
  k_fir<<<48*32,256,0,stream>>>(noise, fbp, FILT);
  k_ir<<<4*(REV_N/4)/256,256,0,stream>>>(FILT, fxp, IR);
  k_wet<<<1024,256,0,stream>>>(FXb, IR, WP);
  k_wetred<<<4*(SEQ/4)/256,256,0,stream>>>(WP, FXb, M0, fxp, M1);

  // ---- master chain: nsig=4, L=256, C=1024 ----
  const int GM = NS_M*C_M/256;   // 16 blocks
  k_eqA0<<<GM,256,0,stream>>>(M1, Pm, E2, NS_M, C_M, L_M);
  k_scan2<<<1,256,0,stream>>>(E2, I2, Mm, 0, NS_M, C_M, 4);
  k_eqC<false><<<GM,256,0,stream>>>(M1, XM, Pm, 0, I2, E2, nullptr, NS_M, C_M, L_M);
  k_scan2<<<1,256,0,stream>>>(E2, I2, Mm, 1, NS_M, C_M, 4);
  k_eqC<false><<<GM,256,0,stream>>>(XM, YM, Pm, 1, I2, E2, nullptr, NS_M, C_M, L_M);
  k_scan2<<<1,256,0,stream>>>(E2, I2, Mm, 2, NS_M, C_M, 4);
  k_eqC<false><<<GM,256,0,stream>>>(YM, XM, Pm, 2, I2, E2, nullptr, NS_M, C_M, L_M);
  k_scan2<<<1,256,0,stream>>>(E2, I2, Mm, 3, NS_M, C_M, 4);
  k_eqC<false><<<GM,256,0,stream>>>(XM, YM, Pm, 3, I2, E2, nullptr, NS_M, C_M, L_M);
  k_scan2<<<1,256,0,stream>>>(E2, I2, Mm, 4, NS_M, C_M, 4);
  k_eqC<false><<<GM,256,0,stream>>>(YM, XM, Pm, 4, I2, E2, nullptr, NS_M, C_M, L_M);
  k_scan2<<<1,256,0,stream>>>(E2, I2, Mm, 5, NS_M, C_M, 4);
  k_eqC<true><<<GM,256,0,stream>>>(XM, YM, Pm, 5, I2, nullptr, E1, NS_M, C_M, L_M);
  k_scan1<<<1,256,0,stream>>>(E1, I1, aLm, NS_M, C_M, 4);
  k_smooth<<<GM,256,0,stream>>>(YM, XM, Pm, I1, NS_M, C_M, L_M);
  k_comp<<<NS_M*(SEQ/4)/256,256,0,stream>>>(YM, XM, Pm, out + OUT_MASTER_OFF, 1024);
}

// Round 5
// 1438.627 us; speedup vs baseline: 3.8601x; 2.1582x over previous
//
#include <hip/hip_runtime.h>

#define DEVFN __device__ __forceinline__

constexpr int SEQ = 262144;
constexpr int REV_N = 65536;
constexpr int TAPS = 1023;
constexpr int NOISE_LEN = REV_N + TAPS - 1;   // 66558

constexpr int NS_T = 32, L_T = 512, C_T = 512;
constexpr int NS_M = 4,  L_M = 256, C_M = 1024;

// output layout: panned = B*2*NT*SEQ = 16,777,216 floats, then master = B*2*SEQ
constexpr int OUT_MASTER_OFF = 16777216;

// bf16 wet-conv buffers
constexpr int PADX = 65552;                 // front zero pad (>= 65536), even
constexpr int XBL  = 327744;                // per-sig padded x length (shorts), mult of 64
constexpr int IRL  = 67584;                 // per-sig reversed-padded ir length (shorts)

#define C_DB  0.16609640474436813f   /* log2(10)/20 */
#define C_LOG 6.0205999132796239f    /* 20*log10(2) */
#define PI_D  3.14159265358979323846

typedef __attribute__((ext_vector_type(8)))  short short8v;
typedef __attribute__((ext_vector_type(16))) float f32x16;

struct SigP {
  float g_in;
  float cb0[6], cb1[6], cb2[6], ca1[6], ca2[6];
  float alpha, oma;
  float th, invr, knee, makeup;
  float g_out;
  float gl, gr, send;
};
struct MatP { double m00, m01, m10, m11; };

// ---------------- workspace layout (bytes) ----------------
constexpr size_t OFF_X   = 0;                       // 33,554,432
constexpr size_t OFF_Y   = 33554432;                // 33,554,432
constexpr size_t OFF_FX  = 67108864;                // 4 MB  (B,2,S)
constexpr size_t OFF_M0  = 71303168;                // 4 MB
constexpr size_t OFF_E2  = 75497472;                // float2[16384]
constexpr size_t OFF_I2  = OFF_E2 + 131072;
constexpr size_t OFF_E1  = OFF_I2 + 131072;         // float[16384]
constexpr size_t OFF_I1  = OFF_E1 + 65536;
constexpr size_t OFF_PT  = OFF_I1 + 65536;
constexpr size_t OFF_PM  = OFF_PT + 32*sizeof(SigP);
constexpr size_t OFF_MT  = (OFF_PM + 4*sizeof(SigP) + 7) & ~(size_t)7;
constexpr size_t OFF_MM  = OFF_MT + 32*6*sizeof(MatP);
constexpr size_t OFF_ALT = OFF_MM + 4*6*sizeof(MatP);
constexpr size_t OFF_ALM = OFF_ALT + 32*sizeof(double);
// overlays (X,Y dead after pan):
constexpr size_t OFF_FILT = OFF_X;                       // 48*65536*4 = 12,582,912
constexpr size_t OFF_IR   = OFF_X + 12582912;            // 1 MB
constexpr size_t OFF_XM   = OFF_X + 16777216;            // 4 MB master ping A
constexpr size_t OFF_YM   = OFF_X + 20971520;            // 4 MB master ping B
constexpr size_t OFF_M1   = OFF_Y;                       // 4 MB master input
constexpr size_t OFF_WP   = OFF_Y + 4194304;             // 16 MB wet partials (8 kp x 4 sig x SEQ bf16)
constexpr size_t OFF_XB   = OFF_WP + 16777216;           // 2.62 MB padded bf16 x
constexpr size_t OFF_IR2  = OFF_XB + (size_t)4*XBL*2;    // 540 KB reversed bf16 ir

// padded LDS index: one float4 pad per 8 float4s -> strided b128 reads conflict-free
DEVFN int pq(int i){ return i + ((i >> 5) << 2); }

DEVFN unsigned short f2bf(float f){
  unsigned int u = __float_as_uint(f);
  unsigned int r = (u + 0x7fffu + ((u >> 16) & 1u)) >> 16;
  return (unsigned short)r;
}
DEVFN float bf2f(unsigned short h){ return __uint_as_float(((unsigned int)h) << 16); }

// ---------------- params kernel ----------------
DEVFN double dn(float p, double lo, double hi){ return (double)p*(hi-lo)+lo; }

__device__ void mk_sig(const float* p, int L, int nsq, bool is_master,
                       SigP* sp, MatP* mats, double* aL)
{
  const double flo[6] = {20.,80.,2000.,8000.,12000.,6000.};
  const double fhi[6] = {2000.,2000.,8000.,12000.,21050.,21050.};
  double gdb = dn(p[0], -48., 48.);
  sp->g_in = (float)exp2(gdb * 0.16609640474436813);
  for (int k=0;k<6;k++){
    double g  = dn(p[1+3*k], -12., 12.);
    double fc = dn(p[2+3*k], flo[k], fhi[k]);
    double q  = dn(p[3+3*k], 0.1, 5.0);
    double A  = pow(10.0, g/40.0);
    double w0 = 2.0*PI_D*(fc/44100.0);
    double al = sin(w0)/(2.0*q), co = cos(w0), sA = sqrt(A);
    double b0,b1,b2,a0,a1,a2;
    if (k==0){                       // low shelf
      b0 = A*((A+1.0) - (A-1.0)*co + 2.0*sA*al);
      b1 = 2.0*A*((A-1.0) - (A+1.0)*co);
      b2 = A*((A+1.0) - (A-1.0)*co - 2.0*sA*al);
      a0 = (A+1.0) + (A-1.0)*co + 2.0*sA*al;
      a1 = -2.0*((A-1.0) + (A+1.0)*co);
      a2 = (A+1.0) + (A-1.0)*co - 2.0*sA*al;
    } else if (k==5){                // high shelf
      b0 = A*((A+1.0) + (A-1.0)*co + 2.0*sA*al);
      b1 = -2.0*A*((A-1.0) + (A+1.0)*co);
      b2 = A*((A+1.0) + (A-1.0)*co - 2.0*sA*al);
      a0 = (A+1.0) - (A-1.0)*co + 2.0*sA*al;
      a1 = 2.0*((A-1.0) - (A+1.0)*co);
      a2 = (A+1.0) - (A-1.0)*co - 2.0*sA*al;
    } else {                         // peaking
      b0 = 1.0 + al*A; b1 = -2.0*co; b2 = 1.0 - al*A;
      a0 = 1.0 + al/A; a1 = -2.0*co; a2 = 1.0 - al/A;
    }
    double ia0 = 1.0/a0;
    double na1 = a1*ia0, na2 = a2*ia0;
    sp->cb0[k]=(float)(b0*ia0); sp->cb1[k]=(float)(b1*ia0); sp->cb2[k]=(float)(b2*ia0);
    sp->ca1[k]=(float)na1;      sp->ca2[k]=(float)na2;
    double m00=-na1, m01=-na2, m10=1.0, m11=0.0;
    for (int j=0;j<nsq;j++){
      double t00=m00*m00+m01*m10, t01=m00*m01+m01*m11;
      double t10=m10*m00+m11*m10, t11=m10*m01+m11*m11;
      m00=t00;m01=t01;m10=t10;m11=t11;
    }
    mats[k].m00=m00; mats[k].m01=m01; mats[k].m10=m10; mats[k].m11=m11;
  }
  double th    = dn(p[19], -60., 0.);
  double ratio = dn(p[20], 1., 10.);
  double at    = dn(p[21], 5., 250.);
  double knee  = dn(p[23], 3., 12.);
  double mkup  = dn(p[24], 0., 6.);
  double alpha = exp(-log(9.0)/(44100.0*at*0.001));
  sp->alpha=(float)alpha; sp->oma=(float)(1.0-alpha);
  sp->th=(float)th; sp->invr=(float)(1.0/ratio); sp->knee=(float)knee; sp->makeup=(float)mkup;
  *aL = pow(alpha, (double)L);
  if (is_master){
    sp->g_out = (float)exp2(dn(p[25],-48.,48.)*0.16609640474436813);
    sp->gl=0.f; sp->gr=0.f; sp->send=0.f;
  } else {
    sp->g_out = 1.f;
    sp->send = (float)exp2(dn(p[25],-80.,12.)*0.16609640474436813);
    double th2 = dn(p[26],0.,1.)*(PI_D/2.0);
    sp->gl = (float)sqrt((PI_D/2.0-th2)*(2.0/PI_D)*cos(th2));
    sp->gr = (float)sqrt(th2*(2.0/PI_D)*sin(th2));
  }
}

__global__ __launch_bounds__(64) void k_params(const float* __restrict__ tp, const float* __restrict__ mp,
    SigP* Pt, SigP* Pm, MatP* Mt, MatP* Mm, double* aLt, double* aLm)
{
  int i = threadIdx.x;
  if (i < 32)       mk_sig(tp + i*27, L_T, 9, false, &Pt[i], &Mt[i*6], &aLt[i]);
  else if (i < 36){ int j=i-32; mk_sig(mp + (j>>1)*26, L_M, 8, true, &Pm[j], &Mm[j*6], &aLm[j]); }
}

// ---------------- compressor gain computer ----------------
DEVFN float comp_gc(float y, float th, float invr, float kn){
  float av  = fmaxf(fabsf(y), 1e-8f);
  float xdb = C_LOG * __builtin_log2f(av);
  float d   = xdb - th;
  float w = (2.f*d < -kn) ? 0.f
          : ((2.f*fabsf(d) <= kn) ? (d+0.5f*kn)*(d+0.5f*kn)/(2.f*kn) : d);
  return (invr-1.f)*w;
}

// ---------------- section-0 zero-state end (A-pass) ----------------
__global__ __launch_bounds__(256) void k_eqA0(const float* __restrict__ in, const SigP* __restrict__ P,
    float2* __restrict__ endst, int nsig, int C, int L)
{
  int tid = blockIdx.x*256 + threadIdx.x;
  if (tid >= nsig*C) return;
  int sig = tid / C, c = tid - sig*C;
  const SigP* sp = P + sig;
  float g  = sp->g_in;
  float b0 = sp->cb0[0]*g, b1 = sp->cb1[0]*g, b2 = sp->cb2[0]*g;
  float a1 = sp->ca1[0], a2 = sp->ca2[0];
  const float* xp = in + (size_t)sig*SEQ + (size_t)c*L;
  float xm1=0.f, xm2=0.f;
  if (c){ xm1 = xp[-1]; xm2 = xp[-2]; }
  float ym1=0.f, ym2=0.f;
  for (int i=0;i<L;i+=4){
    float4 v = *(const float4*)(xp+i);
    float t0, y;
    t0 = fmaf(b0,v.x, fmaf(b1,xm1, fmaf(b2,xm2, -a2*ym2))); y = fmaf(-a1,ym1,t0); xm2=xm1;xm1=v.x;ym2=ym1;ym1=y;
    t0 = fmaf(b0,v.y, fmaf(b1,xm1, fmaf(b2,xm2, -a2*ym2))); y = fmaf(-a1,ym1,t0); xm2=xm1;xm1=v.y;ym2=ym1;ym1=y;
    t0 = fmaf(b0,v.z, fmaf(b1,xm1, fmaf(b2,xm2, -a2*ym2))); y = fmaf(-a1,ym1,t0); xm2=xm1;xm1=v.z;ym2=ym1;ym1=y;
    t0 = fmaf(b0,v.w, fmaf(b1,xm1, fmaf(b2,xm2, -a2*ym2))); y = fmaf(-a1,ym1,t0); xm2=xm1;xm1=v.w;ym2=ym1;ym1=y;
  }
  endst[tid] = make_float2(ym1, ym2);
}

// ---------------- 2-state chunk scan (double) ----------------
__global__ __launch_bounds__(256) void k_scan2(const float2* __restrict__ endst, float2* __restrict__ inits,
    const MatP* __restrict__ M, int sec, int nsig, int C, int G)
{
  __shared__ float2 sb[4096];
  int s0 = blockIdx.x*G;
  int total = G*C;
  for (int i=threadIdx.x; i<total; i+=256){
    int gi = s0*C + i;
    sb[i] = (gi < nsig*C) ? endst[gi] : make_float2(0.f,0.f);
  }
  __syncthreads();
  int g = threadIdx.x;
  if (g < G && (s0+g) < nsig){
    MatP m = M[(s0+g)*6 + sec];
    double sx=0.0, sy=0.0;
    float2* op = inits + (size_t)(s0+g)*C;
    const float2* dp = sb + g*C;
    for (int c=0;c<C;c++){
      op[c] = make_float2((float)sx,(float)sy);
      float2 d = dp[c];
      double tx = m.m00*sx + m.m01*sy + (double)d.x;
      double ty = m.m10*sx + m.m11*sy + (double)d.y;
      sx=tx; sy=ty;
    }
  }
}

// ---------------- 1-state chunk scan (smoother) ----------------
__global__ __launch_bounds__(256) void k_scan1(const float* __restrict__ endst, float* __restrict__ inits,
    const double* __restrict__ aL, int nsig, int C, int G)
{
  __shared__ float sb[8192];
  int s0 = blockIdx.x*G;
  int total = G*C;
  for (int i=threadIdx.x; i<total; i+=256){
    int gi = s0*C + i;
    sb[i] = (gi < nsig*C) ? endst[gi] : 0.f;
  }
  __syncthreads();
  int g = threadIdx.x;
  if (g < G && (s0+g) < nsig){
    double a = aL[s0+g];
    double s = 0.0;
    float* op = inits + (size_t)(s0+g)*C;
    const float* dp = sb + g*C;
    for (int c=0;c<C;c++){
      op[c] = (float)s;
      s = a*s + (double)dp[c];
    }
  }
}

// ---------------- biquad re-run (C-pass), fused next-section d ----------------
template<bool LAST>
__global__ __launch_bounds__(256) void k_eqC(const float* __restrict__ in, float* __restrict__ out,
    const SigP* __restrict__ P, int sec, const float2* __restrict__ inits,
    float2* __restrict__ endn2, float* __restrict__ endn1, int nsig, int C, int L)
{
  int tid = blockIdx.x*256 + threadIdx.x;
  if (tid >= nsig*C) return;
  int sig = tid / C, c = tid - sig*C;
  const SigP* sp = P + sig;
  float g  = (sec==0) ? sp->g_in : 1.f;
  float b0 = sp->cb0[sec]*g, b1 = sp->cb1[sec]*g, b2 = sp->cb2[sec]*g;
  float a1 = sp->ca1[sec], a2 = sp->ca2[sec];
  size_t base = (size_t)sig*SEQ + (size_t)c*L;
  const float* xp = in + base;
  float* op = out + base;
  float xm1=0.f, xm2=0.f;
  if (c){ xm1 = xp[-1]; xm2 = xp[-2]; }
  float2 s0 = inits[tid];
  float ym1 = s0.x, ym2 = s0.y;
  float nb0=0,nb1=0,nb2=0,na1=0,na2=0,pxm1=0,pxm2=0,pym1=0,pym2=0;
  float al=0,oma=0,th=0,invr=0,kn=0,gacc=0;
  if (!LAST){
    nb0=sp->cb0[sec+1]; nb1=sp->cb1[sec+1]; nb2=sp->cb2[sec+1];
    na1=sp->ca1[sec+1]; na2=sp->ca2[sec+1];
    pxm1=s0.x; pxm2=s0.y;
  } else {
    al=sp->alpha; oma=sp->oma; th=sp->th; invr=sp->invr; kn=sp->knee;
  }
  for (int i=0;i<L;i+=4){
    float4 v = *(const float4*)(xp+i);
    float4 o;
    #pragma unroll
    for (int u=0;u<4;u++){
      float x = (u==0)?v.x:(u==1)?v.y:(u==2)?v.z:v.w;
      float t0 = fmaf(b0,x, fmaf(b1,xm1, fmaf(b2,xm2, -a2*ym2)));
      float y  = fmaf(-a1,ym1,t0);
      xm2=xm1; xm1=x; ym2=ym1; ym1=y;
      if (u==0) o.x=y; else if (u==1) o.y=y; else if (u==2) o.z=y; else o.w=y;
      if (!LAST){
        float t1 = fmaf(nb0,y, fmaf(nb1,pxm1, fmaf(nb2,pxm2, -na2*pym2)));
        float z  = fmaf(-na1,pym1,t1);
        pxm2=pxm1; pxm1=y; pym2=pym1; pym1=z;
      } else {
        gacc = fmaf(al, gacc, oma*comp_gc(y,th,invr,kn));
      }
    }
    *(float4*)(op+i) = o;
  }
  if (!LAST) endn2[tid] = make_float2(pym1,pym2);
  else       endn1[tid] = gacc;
}

// ---------------- smoother re-run: y5 -> g_s ----------------
__global__ __launch_bounds__(256) void k_smooth(const float* __restrict__ yin, float* __restrict__ gout,
    const SigP* __restrict__ P, const float* __restrict__ inits1, int nsig, int C, int L)
{
  int tid = blockIdx.x*256 + threadIdx.x;
  if (tid >= nsig*C) return;
  int sig = tid / C, c = tid - sig*C;
  const SigP* sp = P + sig;
  float al=sp->alpha, oma=sp->oma, th=sp->th, invr=sp->invr, kn=sp->knee;
  size_t base = (size_t)sig*SEQ + (size_t)c*L;
  const float* xp = yin + base;
  float* op = gout + base;
  float gsv = inits1[tid];
  for (int i=0;i<L;i+=4){
    float4 v = *(const float4*)(xp+i);
    float4 o;
    gsv = fmaf(al, gsv, oma*comp_gc(v.x,th,invr,kn)); o.x=gsv;
    gsv = fmaf(al, gsv, oma*comp_gc(v.y,th,invr,kn)); o.y=gsv;
    gsv = fmaf(al, gsv, oma*comp_gc(v.z,th,invr,kn)); o.z=gsv;
    gsv = fmaf(al, gsv, oma*comp_gc(v.w,th,invr,kn)); o.w=gsv;
    *(float4*)(op+i) = o;
  }
}

// ---------------- apply compressor gain (+lookahead, +out gain) ----------------
__global__ __launch_bounds__(256) void k_comp(const float* __restrict__ y, const float* __restrict__ gs,
    const SigP* __restrict__ P, float* __restrict__ outp, int la)
{
  int q = blockIdx.x*256 + threadIdx.x;
  int sig = q / (SEQ/4);
  int n   = (q - sig*(SEQ/4))*4;
  const SigP* sp = P + sig;
  float mk = sp->makeup, go = sp->g_out;
  size_t base = (size_t)sig*SEQ;
  float4 v = *(const float4*)(y+base+n);
  float4 gv;
  int nl = n + la;
  if (nl+3 <= SEQ-1) gv = *(const float4*)(gs+base+nl);
  else {
    int i0=nl,i1=nl+1,i2=nl+2,i3=nl+3;
    if(i0>SEQ-1)i0=SEQ-1; if(i1>SEQ-1)i1=SEQ-1; if(i2>SEQ-1)i2=SEQ-1; if(i3>SEQ-1)i3=SEQ-1;
    gv.x=gs[base+i0]; gv.y=gs[base+i1]; gv.z=gs[base+i2]; gv.w=gs[base+i3];
  }
  float4 o;
  o.x = v.x * __builtin_exp2f((gv.x+mk)*C_DB) * go;
  o.y = v.y * __builtin_exp2f((gv.y+mk)*C_DB) * go;
  o.z = v.z * __builtin_exp2f((gv.z+mk)*C_DB) * go;
  o.w = v.w * __builtin_exp2f((gv.w+mk)*C_DB) * go;
  *(float4*)(outp+base+n) = o;
}

// ---------------- pan + master/fx sums ----------------
__global__ __launch_bounds__(256) void k_pan(const float* __restrict__ y, const SigP* __restrict__ P,
    float* __restrict__ panned, float* __restrict__ m0, float* __restrict__ fx)
{
  int q = blockIdx.x*256 + threadIdx.x;   // BS*SEQ/4 threads
  int b = q / (SEQ/4);
  int n = (q - b*(SEQ/4))*4;
  float4 aL={0,0,0,0}, aR={0,0,0,0}, fL={0,0,0,0}, fR={0,0,0,0};
  for (int t=0;t<16;t++){
    const SigP* sp = P + b*16 + t;
    float gl=sp->gl, gr=sp->gr, sd=sp->send;
    float4 v = *(const float4*)(y + (size_t)(b*16+t)*SEQ + n);
    float4 pl = { v.x*gl, v.y*gl, v.z*gl, v.w*gl };
    float4 pr = { v.x*gr, v.y*gr, v.z*gr, v.w*gr };
    *(float4*)(panned + (size_t)(b*32+t)*SEQ + n)    = pl;
    *(float4*)(panned + (size_t)(b*32+16+t)*SEQ + n) = pr;
    aL.x+=pl.x; aL.y+=pl.y; aL.z+=pl.z; aL.w+=pl.w;
    aR.x+=pr.x; aR.y+=pr.y; aR.z+=pr.z; aR.w+=pr.w;
    fL.x=fmaf(pl.x,sd,fL.x); fL.y=fmaf(pl.y,sd,fL.y); fL.z=fmaf(pl.z,sd,fL.z); fL.w=fmaf(pl.w,sd,fL.w);
    fR.x=fmaf(pr.x,sd,fR.x); fR.y=fmaf(pr.y,sd,fR.y); fR.z=fmaf(pr.z,sd,fR.z); fR.w=fmaf(pr.w,sd,fR.w);
  }
  *(float4*)(m0 + (size_t)(b*2+0)*SEQ + n) = aL;
  *(float4*)(m0 + (size_t)(b*2+1)*SEQ + n) = aR;
  *(float4*)(fx + (size_t)(b*2+0)*SEQ + n) = fL;
  *(float4*)(fx + (size_t)(b*2+1)*SEQ + n) = fR;
}

// ---------------- reverb band FIR: filt = valid(conv(noise, fb)) ----------------
__global__ __launch_bounds__(256) void k_fir(const float* __restrict__ noise, const float* __restrict__ fb,
    float* __restrict__ filt)
{
  __shared__ alignas(16) float sx[3456];
  __shared__ alignas(16) float sf[1152];
  int sig = blockIdx.x >> 5;            // 48 sigs, 32 blocks each
  int n0  = (blockIdx.x & 31) * 2048;
  int band = sig % 12;
  const float* np_ = noise + (size_t)sig*NOISE_LEN + n0;
  for (int i=threadIdx.x; i<3072; i+=256) sx[pq(i)] = (i<3070) ? np_[i] : 0.f;
  for (int i=threadIdx.x; i<1024; i+=256) sf[pq(i)] = (i<1023) ? fb[band*TAPS + 1022 - i] : 0.f;
  __syncthreads();
  int t = threadIdx.x;
  float acc[8];
  #pragma unroll
  for (int j=0;j<8;j++) acc[j]=0.f;
  float w[16];
  int wb = 8*t;
  #pragma unroll
  for (int m=0;m<16;m+=4){
    float4 qq = *(const float4*)(sx+pq(wb+m));
    w[m]=qq.x; w[m+1]=qq.y; w[m+2]=qq.z; w[m+3]=qq.w;
  }
  for (int ut=0; ut<128; ut++){
    float4 f0 = *(const float4*)(sf + pq(8*ut));
    float4 f1 = *(const float4*)(sf + pq(8*ut + 4));
    float f[8] = {f0.x,f0.y,f0.z,f0.w,f1.x,f1.y,f1.z,f1.w};
    #pragma unroll
    for (int d=0;d<8;d++)
      #pragma unroll
      for (int j=0;j<8;j++)
        acc[j] = fmaf(f[d], w[j+d], acc[j]);
    if (ut<127){
      #pragma unroll
      for (int m=0;m<8;m++) w[m]=w[m+8];
      float4 q0 = *(const float4*)(sx + pq(wb + 8*ut + 16));
      float4 q1 = *(const float4*)(sx + pq(wb + 8*ut + 20));
      w[8]=q0.x; w[9]=q0.y; w[10]=q0.z; w[11]=q0.w;
      w[12]=q1.x; w[13]=q1.y; w[14]=q1.z; w[15]=q1.w;
    }
  }
  float* op = filt + (size_t)sig*REV_N + n0 + 8*t;
  float4 o0={acc[0],acc[1],acc[2],acc[3]}, o1={acc[4],acc[5],acc[6],acc[7]};
  *(float4*)(op)   = o0;
  *(float4*)(op+4) = o1;
}

// ---------------- ir = mean over bands of filt*env*gain ----------------
__global__ __launch_bounds__(256) void k_ir(const float* __restrict__ filt, const float* __restrict__ fxp,
    float* __restrict__ ir)
{
  int q = blockIdx.x*256 + threadIdx.x;   // 4*REV_N/4 threads
  int sig = q / (REV_N/4);
  int i   = (q - sig*(REV_N/4))*4;
  int b = sig >> 1;
  float4 acc={0,0,0,0};
  const float ts = 1.0f/65535.0f;
  for (int band=0; band<12; band++){
    float gn  = fxp[b*25 + band];
    float dec = fxp[b*25 + 12 + band]*10.f + 1.f;
    float4 f = *(const float4*)(filt + ((size_t)(sig*12+band))*REV_N + i);
    float s = -dec*ts;
    float e0=expf(s*(float)i), e1=expf(s*(float)(i+1)), e2=expf(s*(float)(i+2)), e3=expf(s*(float)(i+3));
    acc.x = fmaf(gn*e0, f.x, acc.x);
    acc.y = fmaf(gn*e1, f.y, acc.y);
    acc.z = fmaf(gn*e2, f.z, acc.z);
    acc.w = fmaf(gn*e3, f.w, acc.w);
  }
  const float inv12 = 1.f/12.f;
  acc.x*=inv12; acc.y*=inv12; acc.z*=inv12; acc.w*=inv12;
  *(float4*)(ir + (size_t)sig*REV_N + i) = acc;
}

// ---------------- bf16 prep: padded x, reversed-padded ir ----------------
__global__ __launch_bounds__(256) void k_prepx(const float* __restrict__ fx, unsigned short* __restrict__ XB)
{
  int q = blockIdx.x*256 + threadIdx.x;           // 4*XBL
  int sig = q / XBL;
  int m   = q - sig*XBL;
  int a = m - PADX;
  float v = (a >= 0 && a < SEQ) ? fx[(size_t)sig*SEQ + a] : 0.f;
  XB[(size_t)sig*XBL + m] = f2bf(v);
}
__global__ __launch_bounds__(256) void k_prepir(const float* __restrict__ ir, unsigned short* __restrict__ IRV)
{
  int q = blockIdx.x*256 + threadIdx.x;           // 4*IRL
  int sig = q / IRL;
  int m   = q - sig*IRL;
  int a = m - 1024;
  float v = (a >= 0 && a < REV_N) ? ir[(size_t)sig*REV_N + (REV_N-1 - a)] : 0.f;
  IRV[(size_t)sig*IRL + m] = f2bf(v);
}

// ---------------- wet conv via MFMA (bf16 inputs, fp32 accum) ----------------
// out[n] = sum_k ir[k] x[n-k].  C[i,j] = out[n0+i+32j], A[i,k]=x[c0+i+k] (c0=n0-T0),
// B[k,j]=ir[T0+32j-k], T0=16s, s in [-62,4096]. 8 k-partitions -> bf16 partials.
__global__ __launch_bounds__(256,3) void k_wetm(const unsigned short* __restrict__ XB,
    const unsigned short* __restrict__ IRV, unsigned short* __restrict__ WP)
{
  __shared__ alignas(16) unsigned int xs0[4640];
  __shared__ alignas(16) unsigned int xs1[4640];
  __shared__ alignas(16) unsigned short sir[3456];
  int b = blockIdx.x;                 // 1024 = 32 ngrp * 4 sig * 8 kp
  int ng  = b & 31;
  int sig = (b >> 5) & 3;
  int kp  = b >> 7;
  int nblk = ng << 13;                // *8192 outputs per block
  int sbeg = -62 + 520*kp;
  int send = sbeg + 520; if (send > 4097) send = 4097;

  int tid = threadIdx.x;
  int l  = tid & 63, wv = tid >> 6;
  int lj = l & 31, lg = l >> 5, ph = l & 1;
  int hl = (lj + 8*lg - ph) >> 1;
  int offB = 32*lj - 8*lg;
  const unsigned int* xbu = (const unsigned int*)(XB + (size_t)sig*XBL);
  const unsigned short* irg = IRV + (size_t)sig*IRL;
  const unsigned int* xsel = ph ? (const unsigned int*)xs1 : (const unsigned int*)xs0;

  f32x16 acc0 = {};
  f32x16 acc1 = {};
  int n0_0 = nblk + (wv*2+0)*1024;
  int n0_1 = nblk + (wv*2+1)*1024;

  for (int sa = sbeg; sa < send; sa += 128){
    int ns = send - sa; if (ns > 128) ns = 128;
    __syncthreads();
    // ---- stage x (two dword-phase arrays) ----
    int clo = nblk - 16*(sa + ns - 1);                 // even
    int ub  = (PADX + clo) >> 1;
    int nd  = ((nblk + 7168 + 46 - 16*sa) - clo)/2 + 2;
    for (int d = tid; d < nd; d += 256){
      unsigned int u0 = xbu[ub + d], u1 = xbu[ub + d + 1];
      xs0[d] = u0;
      xs1[d] = (u0 >> 16) | (u1 << 16);
    }
    // ---- stage reversed ir with +8/64 pad ----
    int amin = 65535 - 16*(sa + ns - 1) - 992;
    int irlo = ((amin - 7) & ~7) + 7;                  // <= amin, ==7 mod 8
    int irspan = (65535 - 16*sa + 15) - irlo + 1;
    for (int r = tid; r < irspan; r += 256){
      sir[r + ((r>>6)<<3)] = irg[1024 + irlo + r];
    }
    __syncthreads();
    // ---- compute ----
    int db0 = ((n0_0 - clo) >> 1) - 8*sa + hl;
    int db1 = ((n0_1 - clo) >> 1) - 8*sa + hl;
    int Dh0 = 65535 - 16*sa - irlo;
    for (int ss = 0; ss < ns; ss++){
      int rB = (Dh0 - 16*ss) - offB;
      short8v bfrag = *(const short8v*)(sir + rB + ((rB>>6)<<3));
      union { unsigned int u[4]; short8v v; } a0, a1;
      int d0 = db0 - 8*ss, d1 = db1 - 8*ss;
      a0.u[0]=xsel[d0];   a0.u[1]=xsel[d0+1]; a0.u[2]=xsel[d0+2]; a0.u[3]=xsel[d0+3];
      a1.u[0]=xsel[d1];   a1.u[1]=xsel[d1+1]; a1.u[2]=xsel[d1+2]; a1.u[3]=xsel[d1+3];
      acc0 = __builtin_amdgcn_mfma_f32_32x32x16_bf16(a0.v, bfrag, acc0, 0, 0, 0);
      acc1 = __builtin_amdgcn_mfma_f32_32x32x16_bf16(a1.v, bfrag, acc1, 0, 0, 0);
    }
  }
  // ---- writeout bf16 partials ----
  unsigned short* wp = WP + ((size_t)(kp*4+sig))*SEQ;
  #pragma unroll
  for (int reg = 0; reg < 16; reg++){
    int i = (reg & 3) + 8*(reg >> 2) + 4*lg;
    wp[n0_0 + i + 32*lj] = f2bf(acc0[reg]);
    wp[n0_1 + i + 32*lj] = f2bf(acc1[reg]);
  }
}

// ---------------- reduce partials + mix + add to master ----------------
__global__ __launch_bounds__(256) void k_wetred(const unsigned short* __restrict__ wp, const float* __restrict__ fx,
    const float* __restrict__ m0, const float* __restrict__ fxp, float* __restrict__ m1)
{
  int q = blockIdx.x*256 + threadIdx.x;   // 4*SEQ/4 threads
  int sig = q / (SEQ/4);
  int n = (q - sig*(SEQ/4))*4;
  float mix = fxp[(sig>>1)*25+24];
  size_t ob = (size_t)sig*SEQ + n;
  float s0=0.f, s1=0.f, s2=0.f, s3=0.f;
  #pragma unroll
  for (int kp=0; kp<8; kp++){
    const unsigned short* p = wp + ((size_t)(kp*4+sig))*SEQ + n;
    s0 += bf2f(p[0]); s1 += bf2f(p[1]); s2 += bf2f(p[2]); s3 += bf2f(p[3]);
  }
  float4 w0 = *(const float4*)(m0+ob);
  float4 x0 = *(const float4*)(fx+ob);
  float om = 1.f - mix;
  float4 o;
  o.x = w0.x + om*x0.x + mix*s0;
  o.y = w0.y + om*x0.y + mix*s1;
  o.z = w0.z + om*x0.z + mix*s2;
  o.w = w0.w + om*x0.w + mix*s3;
  *(float4*)(m1+ob) = o;
}

// ---------------- launch ----------------
extern "C" void kernel_launch(void* const* d_in, const int* in_sizes, int n_in,
                              void* d_out, int out_size, void* d_ws, size_t ws_size,
                              hipStream_t stream)
{
  const float* tracks = (const float*)d_in[0];
  const float* tp     = (const float*)d_in[1];
  const float* fxp    = (const float*)d_in[2];
  const float* mp     = (const float*)d_in[3];
  const float* noise  = (const float*)d_in[4];
  const float* fbp    = (const float*)d_in[5];
  float* out = (float*)d_out;
  char* w = (char*)d_ws;

  float*  X   = (float*)(w + OFF_X);
  float*  Y   = (float*)(w + OFF_Y);
  float*  FXb = (float*)(w + OFF_FX);
  float*  M0  = (float*)(w + OFF_M0);
  float2* E2  = (float2*)(w + OFF_E2);
  float2* I2  = (float2*)(w + OFF_I2);
  float*  E1  = (float*)(w + OFF_E1);
  float*  I1  = (float*)(w + OFF_I1);
  SigP*   Pt  = (SigP*)(w + OFF_PT);
  SigP*   Pm  = (SigP*)(w + OFF_PM);
  MatP*   Mt  = (MatP*)(w + OFF_MT);
  MatP*   Mm  = (MatP*)(w + OFF_MM);
  double* aLt = (double*)(w + OFF_ALT);
  double* aLm = (double*)(w + OFF_ALM);
  float*  FILT= (float*)(w + OFF_FILT);
  float*  IR  = (float*)(w + OFF_IR);
  float*  XM  = (float*)(w + OFF_XM);
  float*  YM  = (float*)(w + OFF_YM);
  float*  M1  = (float*)(w + OFF_M1);
  unsigned short* WPu = (unsigned short*)(w + OFF_WP);
  unsigned short* XB  = (unsigned short*)(w + OFF_XB);
  unsigned short* IRV = (unsigned short*)(w + OFF_IR2);

  k_params<<<1,64,0,stream>>>(tp, mp, Pt, Pm, Mt, Mm, aLt, aLm);

  // ---- track chain: nsig=32, L=512, C=512 ----
  const int GT = NS_T*C_T/256;   // 64 blocks
  k_eqA0<<<GT,256,0,stream>>>(tracks, Pt, E2, NS_T, C_T, L_T);
  k_scan2<<<4,256,0,stream>>>(E2, I2, Mt, 0, NS_T, C_T, 8);
  k_eqC<false><<<GT,256,0,stream>>>(tracks, X, Pt, 0, I2, E2, nullptr, NS_T, C_T, L_T);
  k_scan2<<<4,256,0,stream>>>(E2, I2, Mt, 1, NS_T, C_T, 8);
  k_eqC<false><<<GT,256,0,stream>>>(X, Y, Pt, 1, I2, E2, nullptr, NS_T, C_T, L_T);
  k_scan2<<<4,256,0,stream>>>(E2, I2, Mt, 2, NS_T, C_T, 8);
  k_eqC<false><<<GT,256,0,stream>>>(Y, X, Pt, 2, I2, E2, nullptr, NS_T, C_T, L_T);
  k_scan2<<<4,256,0,stream>>>(E2, I2, Mt, 3, NS_T, C_T, 8);
  k_eqC<false><<<GT,256,0,stream>>>(X, Y, Pt, 3, I2, E2, nullptr, NS_T, C_T, L_T);
  k_scan2<<<4,256,0,stream>>>(E2, I2, Mt, 4, NS_T, C_T, 8);
  k_eqC<false><<<GT,256,0,stream>>>(Y, X, Pt, 4, I2, E2, nullptr, NS_T, C_T, L_T);
  k_scan2<<<4,256,0,stream>>>(E2, I2, Mt, 5, NS_T, C_T, 8);
  k_eqC<true><<<GT,256,0,stream>>>(X, Y, Pt, 5, I2, nullptr, E1, NS_T, C_T, L_T);
  k_scan1<<<2,256,0,stream>>>(E1, I1, aLt, NS_T, C_T, 16);
  k_smooth<<<GT,256,0,stream>>>(Y, X, Pt, I1, NS_T, C_T, L_T);
  k_comp<<<NS_T*(SEQ/4)/256,256,0,stream>>>(Y, X, Pt, Y, 2048);
  k_pan<<<2*(SEQ/4)/256,256,0,stream>>>(Y, Pt, out, M0, FXb);

  // ---- reverb ----
  k_fir<<<48*32,256,0,stream>>>(noise, fbp, FILT);
  k_ir<<<4*(REV_N/4)/256,256,0,stream>>>(FILT, fxp, IR);
  k_prepx<<<(4*XBL)/256,256,0,stream>>>(FXb, XB);
  k_prepir<<<(4*IRL)/256,256,0,stream>>>(IR, IRV);
  k_wetm<<<1024,256,0,stream>>>(XB, IRV, WPu);
  k_wetred<<<4*(SEQ/4)/256,256,0,stream>>>(WPu, FXb, M0, fxp, M1);

  // ---- master chain: nsig=4, L=256, C=1024 ----
  const int GM = NS_M*C_M/256;   // 16 blocks
  k_eqA0<<<GM,256,0,stream>>>(M1, Pm, E2, NS_M, C_M, L_M);
  k_scan2<<<1,256,0,stream>>>(E2, I2, Mm, 0, NS_M, C_M, 4);
  k_eqC<false><<<GM,256,0,stream>>>(M1, XM, Pm, 0, I2, E2, nullptr, NS_M, C_M, L_M);
  k_scan2<<<1,256,0,stream>>>(E2, I2, Mm, 1, NS_M, C_M, 4);
  k_eqC<false><<<GM,256,0,stream>>>(XM, YM, Pm, 1, I2, E2, nullptr, NS_M, C_M, L_M);
  k_scan2<<<1,256,0,stream>>>(E2, I2, Mm, 2, NS_M, C_M, 4);
  k_eqC<false><<<GM,256,0,stream>>>(YM, XM, Pm, 2, I2, E2, nullptr, NS_M, C_M, L_M);
  k_scan2<<<1,256,0,stream>>>(E2, I2, Mm, 3, NS_M, C_M, 4);
  k_eqC<false><<<GM,256,0,stream>>>(XM, YM, Pm, 3, I2, E2, nullptr, NS_M, C_M, L_M);
  k_scan2<<<1,256,0,stream>>>(E2, I2, Mm, 4, NS_M, C_M, 4);
  k_eqC<false><<<GM,256,0,stream>>>(YM, XM, Pm, 4, I2, E2, nullptr, NS_M, C_M, L_M);
  k_scan2<<<1,256,0,stream>>>(E2, I2, Mm, 5, NS_M, C_M, 4);
  k_eqC<true><<<GM,256,0,stream>>>(XM, YM, Pm, 5, I2, nullptr, E1, NS_M, C_M, L_M);
  k_scan1<<<1,256,0,stream>>>(E1, I1, aLm, NS_M, C_M, 4);
  k_smooth<<<GM,256,0,stream>>>(YM, XM, Pm, I1, NS_M, C_M, L_M);
  k_comp<<<NS_M*(SEQ/4)/256,256,0,stream>>>(YM, XM, Pm, out + OUT_MASTER_OFF, 1024);
}

// Round 8
// 860.599 us; speedup vs baseline: 6.4528x; 1.6717x over previous
//
#include <hip/hip_runtime.h>

#define DEVFN __device__ __forceinline__

constexpr int SEQ = 262144;
constexpr int REV_N = 65536;
constexpr int TAPS = 1023;
constexpr int NOISE_LEN = REV_N + TAPS - 1;   // 66558

constexpr int NS_T = 32, L_T = 128, C_T = 2048;   // track: 2048 chunks of 128
constexpr int NS_M = 4,  L_M = 64,  C_M = 4096;   // master: 4096 chunks of 64
constexpr int LA_T = 2048, LA_M = 1024;           // lookahead (16 chunks both)

// output layout: panned = B*2*NT*SEQ = 16,777,216 floats, then master = B*2*SEQ
constexpr int OUT_MASTER_OFF = 16777216;

// bf16 wet-conv buffers
constexpr int PADX = 65552;                 // front zero pad (>= 65536), even
constexpr int XBL  = 327744;                // per-sig padded x length (shorts), mult of 64
constexpr int IRL  = 67584;                 // per-sig reversed-padded ir length (shorts)

#define C_DB  0.16609640474436813f   /* log2(10)/20 */
#define C_LOG 6.0205999132796239f    /* 20*log10(2) */
#define PI_D  3.14159265358979323846

typedef __attribute__((ext_vector_type(8)))  short short8v;
typedef __attribute__((ext_vector_type(16))) float f32x16;

struct SigP {
  float g_in;
  float cb0[6], cb1[6], cb2[6], ca1[6], ca2[6];
  float alpha, oma;
  float th, invr, knee, makeup;
  float g_out;
  float gl, gr, send;
};
struct MatP { double m00, m01, m10, m11; };

// ---------------- workspace layout (bytes) ----------------
// Live-range map:
//   track chain : tracks(in), X[0,32M), Y[32M,64M... exactly 33554432..67108864), E@FX region, params
//   k_pan       : X -> out, M0, FXb   (E dead)
//   reverb      : FILT/IR/XB/IRV/WP overlays (X dead), FXb, M0, M1(=Y head)
//   master chain: M1, XM/YM (X region), E@FX region (FXb dead after wetred), params
constexpr size_t OFF_X   = 0;                       // 33,554,432
constexpr size_t OFF_Y   = 33554432;                // 33,554,432
constexpr size_t OFF_FX  = 67108864;                // 4 MB  (B,2,S)
constexpr size_t OFF_M0  = 71303168;                // 4 MB
// overlays (X dead after pan):
constexpr size_t OFF_FILT = OFF_X;                       // 48*65536*4 = 12,582,912
constexpr size_t OFF_IR   = OFF_X + 12582912;            // 1 MB
constexpr size_t OFF_XM   = OFF_X + 16777216;            // 4 MB master ping A
constexpr size_t OFF_YM   = OFF_X + 20971520;            // 4 MB master ping B
constexpr size_t OFF_M1   = OFF_Y;                       // 4 MB master input
constexpr size_t OFF_WP   = OFF_Y + 4194304;             // 16 MB wet partials [37.7M,54.5M)
constexpr size_t OFF_XB   = OFF_WP + 16777216;           // 2.62 MB padded bf16 x
constexpr size_t OFF_IR2  = OFF_XB + (size_t)4*XBL*2;    // 540 KB reversed bf16 ir (ends ~57.7M, inside Y: reverb-phase only, Y-as-tracks dead)
// E buffers overlay the FXb region (free during both scan phases):
constexpr size_t OFF_E2  = OFF_FX;                       // 32*2048*8 = 524,288
constexpr size_t OFF_I2  = OFF_FX + 524288;              // 524,288
constexpr size_t OFF_E1  = OFF_FX + 1048576;             // 262,144
constexpr size_t OFF_I1  = OFF_FX + 1310720;             // 262,144  (ends 68,681,728 < 71,303,168)
// persistent small region past M0 (proven writable in round 3 up to ~75.9M):
constexpr size_t OFF_GL  = 75497472;                     // gs_last: 32 track + 4 master
constexpr size_t OFF_PT  = OFF_GL + 1024;
constexpr size_t OFF_PM  = OFF_PT + 32*sizeof(SigP);
constexpr size_t OFF_MT  = (OFF_PM + 4*sizeof(SigP) + 7) & ~(size_t)7;
constexpr size_t OFF_MM  = OFF_MT + 32*6*sizeof(MatP);
constexpr size_t OFF_ALT = OFF_MM + 4*6*sizeof(MatP);
constexpr size_t OFF_ALM = OFF_ALT + 32*sizeof(double);

// padded LDS index: one float4 pad per 8 float4s -> strided b128 reads conflict-free
DEVFN int pq(int i){ return i + ((i >> 5) << 2); }

DEVFN unsigned short f2bf(float f){
  unsigned int u = __float_as_uint(f);
  unsigned int r = (u + 0x7fffu + ((u >> 16) & 1u)) >> 16;
  return (unsigned short)r;
}
DEVFN float bf2f(unsigned short h){ return __uint_as_float(((unsigned int)h) << 16); }

// ---------------- params kernel ----------------
DEVFN double dn(float p, double lo, double hi){ return (double)p*(hi-lo)+lo; }

__device__ void mk_sig(const float* p, int L, int nsq, bool is_master,
                       SigP* sp, MatP* mats, double* aL)
{
  const double flo[6] = {20.,80.,2000.,8000.,12000.,6000.};
  const double fhi[6] = {2000.,2000.,8000.,12000.,21050.,21050.};
  double gdb = dn(p[0], -48., 48.);
  sp->g_in = (float)exp2(gdb * 0.16609640474436813);
  for (int k=0;k<6;k++){
    double g  = dn(p[1+3*k], -12., 12.);
    double fc = dn(p[2+3*k], flo[k], fhi[k]);
    double q  = dn(p[3+3*k], 0.1, 5.0);
    double A  = pow(10.0, g/40.0);
    double w0 = 2.0*PI_D*(fc/44100.0);
    double al = sin(w0)/(2.0*q), co = cos(w0), sA = sqrt(A);
    double b0,b1,b2,a0,a1,a2;
    if (k==0){                       // low shelf
      b0 = A*((A+1.0) - (A-1.0)*co + 2.0*sA*al);
      b1 = 2.0*A*((A-1.0) - (A+1.0)*co);
      b2 = A*((A+1.0) - (A-1.0)*co - 2.0*sA*al);
      a0 = (A+1.0) + (A-1.0)*co + 2.0*sA*al;
      a1 = -2.0*((A-1.0) + (A+1.0)*co);
      a2 = (A+1.0) + (A-1.0)*co - 2.0*sA*al;
    } else if (k==5){                // high shelf
      b0 = A*((A+1.0) + (A-1.0)*co + 2.0*sA*al);
      b1 = -2.0*A*((A-1.0) + (A+1.0)*co);
      b2 = A*((A+1.0) + (A-1.0)*co - 2.0*sA*al);
      a0 = (A+1.0) - (A-1.0)*co + 2.0*sA*al;
      a1 = 2.0*((A-1.0) - (A+1.0)*co);
      a2 = (A+1.0) - (A-1.0)*co - 2.0*sA*al;
    } else {                         // peaking
      b0 = 1.0 + al*A; b1 = -2.0*co; b2 = 1.0 - al*A;
      a0 = 1.0 + al/A; a1 = -2.0*co; a2 = 1.0 - al/A;
    }
    double ia0 = 1.0/a0;
    double na1 = a1*ia0, na2 = a2*ia0;
    sp->cb0[k]=(float)(b0*ia0); sp->cb1[k]=(float)(b1*ia0); sp->cb2[k]=(float)(b2*ia0);
    sp->ca1[k]=(float)na1;      sp->ca2[k]=(float)na2;
    double m00=-na1, m01=-na2, m10=1.0, m11=0.0;
    for (int j=0;j<nsq;j++){
      double t00=m00*m00+m01*m10, t01=m00*m01+m01*m11;
      double t10=m10*m00+m11*m10, t11=m10*m01+m11*m11;
      m00=t00;m01=t01;m10=t10;m11=t11;
    }
    mats[k].m00=m00; mats[k].m01=m01; mats[k].m10=m10; mats[k].m11=m11;
  }
  double th    = dn(p[19], -60., 0.);
  double ratio = dn(p[20], 1., 10.);
  double at    = dn(p[21], 5., 250.);
  double knee  = dn(p[23], 3., 12.);
  double mkup  = dn(p[24], 0., 6.);
  double alpha = exp(-log(9.0)/(44100.0*at*0.001));
  sp->alpha=(float)alpha; sp->oma=(float)(1.0-alpha);
  sp->th=(float)th; sp->invr=(float)(1.0/ratio); sp->knee=(float)knee; sp->makeup=(float)mkup;
  *aL = pow(alpha, (double)L);
  if (is_master){
    sp->g_out = (float)exp2(dn(p[25],-48.,48.)*0.16609640474436813);
    sp->gl=0.f; sp->gr=0.f; sp->send=0.f;
  } else {
    sp->g_out = 1.f;
    sp->send = (float)exp2(dn(p[25],-80.,12.)*0.16609640474436813);
    double th2 = dn(p[26],0.,1.)*(PI_D/2.0);
    sp->gl = (float)sqrt((PI_D/2.0-th2)*(2.0/PI_D)*cos(th2));
    sp->gr = (float)sqrt(th2*(2.0/PI_D)*sin(th2));
  }
}

__global__ __launch_bounds__(64) void k_params(const float* __restrict__ tp, const float* __restrict__ mp,
    SigP* Pt, SigP* Pm, MatP* Mt, MatP* Mm, double* aLt, double* aLm)
{
  int i = threadIdx.x;
  if (i < 32)       mk_sig(tp + i*27, L_T, 7, false, &Pt[i], &Mt[i*6], &aLt[i]);
  else if (i < 36){ int j=i-32; mk_sig(mp + (j>>1)*26, L_M, 6, true, &Pm[j], &Mm[j*6], &aLm[j]); }
}

// ---------------- compressor gain computer ----------------
DEVFN float comp_gc(float y, float th, float invr, float kn){
  float av  = fmaxf(fabsf(y), 1e-8f);
  float xdb = C_LOG * __builtin_log2f(av);
  float d   = xdb - th;
  float w = (2.f*d < -kn) ? 0.f
          : ((2.f*fabsf(d) <= kn) ? (d+0.5f*kn)*(d+0.5f*kn)/(2.f*kn) : d);
  return (invr-1.f)*w;
}

// ---------------- section-0 zero-state end (A-pass) ----------------
__global__ __launch_bounds__(256) void k_eqA0(const float* __restrict__ in, const SigP* __restrict__ P,
    float2* __restrict__ endst, int nsig, int C, int L)
{
  int tid = blockIdx.x*256 + threadIdx.x;
  if (tid >= nsig*C) return;
  int sig = tid / C, c = tid - sig*C;
  const SigP* sp = P + sig;
  float g  = sp->g_in;
  float b0 = sp->cb0[0]*g, b1 = sp->cb1[0]*g, b2 = sp->cb2[0]*g;
  float a1 = sp->ca1[0], a2 = sp->ca2[0];
  const float* xp = in + (size_t)sig*SEQ + (size_t)c*L;
  float xm1=0.f, xm2=0.f;
  if (c){ xm1 = xp[-1]; xm2 = xp[-2]; }
  float ym1=0.f, ym2=0.f;
  for (int i=0;i<L;i+=4){
    float4 v = *(const float4*)(xp+i);
    float t0, y;
    t0 = fmaf(b0,v.x, fmaf(b1,xm1, fmaf(b2,xm2, -a2*ym2))); y = fmaf(-a1,ym1,t0); xm2=xm1;xm1=v.x;ym2=ym1;ym1=y;
    t0 = fmaf(b0,v.y, fmaf(b1,xm1, fmaf(b2,xm2, -a2*ym2))); y = fmaf(-a1,ym1,t0); xm2=xm1;xm1=v.y;ym2=ym1;ym1=y;
    t0 = fmaf(b0,v.z, fmaf(b1,xm1, fmaf(b2,xm2, -a2*ym2))); y = fmaf(-a1,ym1,t0); xm2=xm1;xm1=v.z;ym2=ym1;ym1=y;
    t0 = fmaf(b0,v.w, fmaf(b1,xm1, fmaf(b2,xm2, -a2*ym2))); y = fmaf(-a1,ym1,t0); xm2=xm1;xm1=v.w;ym2=ym1;ym1=y;
  }
  endst[tid] = make_float2(ym1, ym2);
}

// ---------------- 2-state affine scan, two-level, LDS serial combine ----------------
__global__ __launch_bounds__(64) void k_scan2p(const float2* __restrict__ endst, float2* __restrict__ inits,
    const MatP* __restrict__ M, int sec, int C, int Q, int lgQ)
{
  __shared__ double agx[64], agy[64], inx[64], iny[64];
  int sig = blockIdx.x;
  int t = threadIdx.x;
  MatP m = M[sig*6 + sec];
  const float2* dp = endst + (size_t)sig*C + (size_t)t*Q;
  double ex=0.0, ey=0.0;
  for (int j=0;j<Q;j++){
    float2 d = dp[j];
    double tx = m.m00*ex + m.m01*ey + (double)d.x;
    double ty = m.m10*ex + m.m11*ey + (double)d.y;
    ex=tx; ey=ty;
  }
  agx[t]=ex; agy[t]=ey;
  __syncthreads();
  if (t == 0){
    double p00=m.m00,p01=m.m01,p10=m.m10,p11=m.m11;
    for (int j=0;j<lgQ;j++){
      double t00=p00*p00+p01*p10, t01=p00*p01+p01*p11;
      double t10=p10*p00+p11*p10, t11=p10*p01+p11*p11;
      p00=t00;p01=t01;p10=t10;p11=t11;
    }
    double sx=0.0, sy=0.0;
    for (int u=0;u<64;u++){
      inx[u]=sx; iny[u]=sy;
      double tx = p00*sx + p01*sy + agx[u];
      double ty = p10*sx + p11*sy + agy[u];
      sx=tx; sy=ty;
    }
  }
  __syncthreads();
  double sx = inx[t], sy = iny[t];
  float2* op = inits + (size_t)sig*C + (size_t)t*Q;
  for (int j=0;j<Q;j++){
    op[j] = make_float2((float)sx, (float)sy);
    float2 d = dp[j];
    double tx = m.m00*sx + m.m01*sy + (double)d.x;
    double ty = m.m10*sx + m.m11*sy + (double)d.y;
    sx=tx; sy=ty;
  }
}

// ---------------- 1-state scan, two-level, LDS serial combine ----------------
__global__ __launch_bounds__(64) void k_scan1p(const float* __restrict__ endst, float* __restrict__ inits,
    const double* __restrict__ aL, int C, int Q, int lgQ)
{
  __shared__ double ag[64], ins[64];
  int sig = blockIdx.x; int t = threadIdx.x;
  double a = aL[sig];
  const float* dp = endst + (size_t)sig*C + (size_t)t*Q;
  double e=0.0;
  for (int j=0;j<Q;j++) e = a*e + (double)dp[j];
  ag[t]=e;
  __syncthreads();
  if (t == 0){
    double p=a;
    for (int j=0;j<lgQ;j++) p = p*p;
    double s=0.0;
    for (int u=0;u<64;u++){
      ins[u]=s;
      s = p*s + ag[u];
    }
  }
  __syncthreads();
  double s = ins[t];
  float* op = inits + (size_t)sig*C + (size_t)t*Q;
  for (int j=0;j<Q;j++){ op[j]=(float)s; s = a*s + (double)dp[j]; }
}

// ---------------- biquad re-run (C-pass), fused next-section d ----------------
template<bool LAST>
__global__ __launch_bounds__(256) void k_eqC(const float* __restrict__ in, float* __restrict__ out,
    const SigP* __restrict__ P, int sec, const float2* __restrict__ inits,
    float2* __restrict__ endn2, float* __restrict__ endn1, int nsig, int C, int L)
{
  int tid = blockIdx.x*256 + threadIdx.x;
  if (tid >= nsig*C) return;
  int sig = tid / C, c = tid - sig*C;
  const SigP* sp = P + sig;
  float g  = (sec==0) ? sp->g_in : 1.f;
  float b0 = sp->cb0[sec]*g, b1 = sp->cb1[sec]*g, b2 = sp->cb2[sec]*g;
  float a1 = sp->ca1[sec], a2 = sp->ca2[sec];
  size_t base = (size_t)sig*SEQ + (size_t)c*L;
  const float* xp = in + base;
  float* op = out + base;
  float xm1=0.f, xm2=0.f;
  if (c){ xm1 = xp[-1]; xm2 = xp[-2]; }
  float2 s0 = inits[tid];
  float ym1 = s0.x, ym2 = s0.y;
  float nb0=0,nb1=0,nb2=0,na1=0,na2=0,pxm1=0,pxm2=0,pym1=0,pym2=0;
  float al=0,oma=0,th=0,invr=0,kn=0,gacc=0;
  if (!LAST){
    nb0=sp->cb0[sec+1]; nb1=sp->cb1[sec+1]; nb2=sp->cb2[sec+1];
    na1=sp->ca1[sec+1]; na2=sp->ca2[sec+1];
    pxm1=s0.x; pxm2=s0.y;
  } else {
    al=sp->alpha; oma=sp->oma; th=sp->th; invr=sp->invr; kn=sp->knee;
  }
  for (int i=0;i<L;i+=4){
    float4 v = *(const float4*)(xp+i);
    float4 o;
    #pragma unroll
    for (int u=0;u<4;u++){
      float x = (u==0)?v.x:(u==1)?v.y:(u==2)?v.z:v.w;
      float t0 = fmaf(b0,x, fmaf(b1,xm1, fmaf(b2,xm2, -a2*ym2)));
      float y  = fmaf(-a1,ym1,t0);
      xm2=xm1; xm1=x; ym2=ym1; ym1=y;
      if (u==0) o.x=y; else if (u==1) o.y=y; else if (u==2) o.z=y; else o.w=y;
      if (!LAST){
        float t1 = fmaf(nb0,y, fmaf(nb1,pxm1, fmaf(nb2,pxm2, -na2*pym2)));
        float z  = fmaf(-na1,pym1,t1);
        pxm2=pxm1; pxm1=y; pym2=pym1; pym1=z;
      } else {
        gacc = fmaf(al, gacc, oma*comp_gc(y,th,invr,kn));
      }
    }
    *(float4*)(op+i) = o;
  }
  if (!LAST) endn2[tid] = make_float2(pym1,pym2);
  else       endn1[tid] = gacc;
}

// ---------------- fused smoother + compressor apply (lookahead = lac chunks) ----------------
__global__ __launch_bounds__(256) void k_smoothcomp(const float* __restrict__ yin,
    const SigP* __restrict__ P, const float* __restrict__ inits1, float* __restrict__ gslast,
    float* __restrict__ outp, int C, int L, int lac)
{
  int tid = blockIdx.x*256 + threadIdx.x;
  int sig = tid / C, c = tid - sig*C;
  const SigP* sp = P + sig;
  float al=sp->alpha, oma=sp->oma, th=sp->th, invr=sp->invr, kn=sp->knee;
  float mk=sp->makeup, go=sp->g_out;
  size_t base = (size_t)sig*SEQ + (size_t)c*L;
  const float* xp = yin + base;
  bool wr = (c >= lac);
  size_t ob = wr ? (base - (size_t)lac*L) : 0;
  const float* yp = yin + ob;
  float* op = outp + ob;
  float gsv = inits1[tid];
  for (int i=0;i<L;i+=4){
    float4 v = *(const float4*)(xp+i);
    float4 gf;
    gsv = fmaf(al, gsv, oma*comp_gc(v.x,th,invr,kn)); gf.x=gsv;
    gsv = fmaf(al, gsv, oma*comp_gc(v.y,th,invr,kn)); gf.y=gsv;
    gsv = fmaf(al, gsv, oma*comp_gc(v.z,th,invr,kn)); gf.z=gsv;
    gsv = fmaf(al, gsv, oma*comp_gc(v.w,th,invr,kn)); gf.w=gsv;
    if (wr){
      float4 y2 = *(const float4*)(yp+i);
      float4 o;
      o.x = y2.x * __builtin_exp2f((gf.x+mk)*C_DB) * go;
      o.y = y2.y * __builtin_exp2f((gf.y+mk)*C_DB) * go;
      o.z = y2.z * __builtin_exp2f((gf.z+mk)*C_DB) * go;
      o.w = y2.w * __builtin_exp2f((gf.w+mk)*C_DB) * go;
      *(float4*)(op+i) = o;
    }
  }
  if (c == C-1) gslast[sig] = gsv;
}

// ---------------- tail: last `la` samples use clamped gs[SEQ-1] ----------------
__global__ __launch_bounds__(256) void k_comptail(const float* __restrict__ yin, const float* __restrict__ gslast,
    const SigP* __restrict__ P, float* __restrict__ outp, int la)
{
  int q = blockIdx.x*256 + threadIdx.x;   // nsig*la/4 threads
  int per = la/4;
  int sig = q / per;
  int r = (q - sig*per)*4;
  int n = SEQ - la + r;
  const SigP* sp = P + sig;
  float f = __builtin_exp2f((gslast[sig]+sp->makeup)*C_DB) * sp->g_out;
  size_t base = (size_t)sig*SEQ + n;
  float4 v = *(const float4*)(yin+base);
  float4 o = { v.x*f, v.y*f, v.z*f, v.w*f };
  *(float4*)(outp+base) = o;
}

// ---------------- pan + master/fx sums ----------------
__global__ __launch_bounds__(256) void k_pan(const float* __restrict__ y, const SigP* __restrict__ P,
    float* __restrict__ panned, float* __restrict__ m0, float* __restrict__ fx)
{
  int q = blockIdx.x*256 + threadIdx.x;   // BS*SEQ/4 threads
  int b = q / (SEQ/4);
  int n = (q - b*(SEQ/4))*4;
  float4 aL={0,0,0,0}, aR={0,0,0,0}, fL={0,0,0,0}, fR={0,0,0,0};
  for (int t=0;t<16;t++){
    const SigP* sp = P + b*16 + t;
    float gl=sp->gl, gr=sp->gr, sd=sp->send;
    float4 v = *(const float4*)(y + (size_t)(b*16+t)*SEQ + n);
    float4 pl = { v.x*gl, v.y*gl, v.z*gl, v.w*gl };
    float4 pr = { v.x*gr, v.y*gr, v.z*gr, v.w*gr };
    *(float4*)(panned + (size_t)(b*32+t)*SEQ + n)    = pl;
    *(float4*)(panned + (size_t)(b*32+16+t)*SEQ + n) = pr;
    aL.x+=pl.x; aL.y+=pl.y; aL.z+=pl.z; aL.w+=pl.w;
    aR.x+=pr.x; aR.y+=pr.y; aR.z+=pr.z; aR.w+=pr.w;
    fL.x=fmaf(pl.x,sd,fL.x); fL.y=fmaf(pl.y,sd,fL.y); fL.z=fmaf(pl.z,sd,fL.z); fL.w=fmaf(pl.w,sd,fL.w);
    fR.x=fmaf(pr.x,sd,fR.x); fR.y=fmaf(pr.y,sd,fR.y); fR.z=fmaf(pr.z,sd,fR.z); fR.w=fmaf(pr.w,sd,fR.w);
  }
  *(float4*)(m0 + (size_t)(b*2+0)*SEQ + n) = aL;
  *(float4*)(m0 + (size_t)(b*2+1)*SEQ + n) = aR;
  *(float4*)(fx + (size_t)(b*2+0)*SEQ + n) = fL;
  *(float4*)(fx + (size_t)(b*2+1)*SEQ + n) = fR;
}

// ---------------- reverb band FIR: filt = valid(conv(noise, fb)) ----------------
__global__ __launch_bounds__(256) void k_fir(const float* __restrict__ noise, const float* __restrict__ fb,
    float* __restrict__ filt)
{
  __shared__ alignas(16) float sx[3456];
  __shared__ alignas(16) float sf[1152];
  int sig = blockIdx.x >> 5;            // 48 sigs, 32 blocks each
  int n0  = (blockIdx.x & 31) * 2048;
  int band = sig % 12;
  const float* np_ = noise + (size_t)sig*NOISE_LEN + n0;
  for (int i=threadIdx.x; i<3072; i+=256) sx[pq(i)] = (i<3070) ? np_[i] : 0.f;
  for (int i=threadIdx.x; i<1024; i+=256) sf[pq(i)] = (i<1023) ? fb[band*TAPS + 1022 - i] : 0.f;
  __syncthreads();
  int t = threadIdx.x;
  float acc[8];
  #pragma unroll
  for (int j=0;j<8;j++) acc[j]=0.f;
  float w[16];
  int wb = 8*t;
  #pragma unroll
  for (int m=0;m<16;m+=4){
    float4 qq = *(const float4*)(sx+pq(wb+m));
    w[m]=qq.x; w[m+1]=qq.y; w[m+2]=qq.z; w[m+3]=qq.w;
  }
  for (int ut=0; ut<128; ut++){
    float4 f0 = *(const float4*)(sf + pq(8*ut));
    float4 f1 = *(const float4*)(sf + pq(8*ut + 4));
    float f[8] = {f0.x,f0.y,f0.z,f0.w,f1.x,f1.y,f1.z,f1.w};
    #pragma unroll
    for (int d=0;d<8;d++)
      #pragma unroll
      for (int j=0;j<8;j++)
        acc[j] = fmaf(f[d], w[j+d], acc[j]);
    if (ut<127){
      #pragma unroll
      for (int m=0;m<8;m++) w[m]=w[m+8];
      float4 q0 = *(const float4*)(sx + pq(wb + 8*ut + 16));
      float4 q1 = *(const float4*)(sx + pq(wb + 8*ut + 20));
      w[8]=q0.x; w[9]=q0.y; w[10]=q0.z; w[11]=q0.w;
      w[12]=q1.x; w[13]=q1.y; w[14]=q1.z; w[15]=q1.w;
    }
  }
  float* op = filt + (size_t)sig*REV_N + n0 + 8*t;
  float4 o0={acc[0],acc[1],acc[2],acc[3]}, o1={acc[4],acc[5],acc[6],acc[7]};
  *(float4*)(op)   = o0;
  *(float4*)(op+4) = o1;
}

// ---------------- ir = mean over bands of filt*env*gain ----------------
__global__ __launch_bounds__(256) void k_ir(const float* __restrict__ filt, const float* __restrict__ fxp,
    float* __restrict__ ir)
{
  int q = blockIdx.x*256 + threadIdx.x;   // 4*REV_N/4 threads
  int sig = q / (REV_N/4);
  int i   = (q - sig*(REV_N/4))*4;
  int b = sig >> 1;
  float4 acc={0,0,0,0};
  const float ts = 1.0f/65535.0f;
  for (int band=0; band<12; band++){
    float gn  = fxp[b*25 + band];
    float dec = fxp[b*25 + 12 + band]*10.f + 1.f;
    float4 f = *(const float4*)(filt + ((size_t)(sig*12+band))*REV_N + i);
    float s = -dec*ts;
    float e0=expf(s*(float)i), e1=expf(s*(float)(i+1)), e2=expf(s*(float)(i+2)), e3=expf(s*(float)(i+3));
    acc.x = fmaf(gn*e0, f.x, acc.x);
    acc.y = fmaf(gn*e1, f.y, acc.y);
    acc.z = fmaf(gn*e2, f.z, acc.z);
    acc.w = fmaf(gn*e3, f.w, acc.w);
  }
  const float inv12 = 1.f/12.f;
  acc.x*=inv12; acc.y*=inv12; acc.z*=inv12; acc.w*=inv12;
  *(float4*)(ir + (size_t)sig*REV_N + i) = acc;
}

// ---------------- bf16 prep: padded x, reversed-padded ir ----------------
__global__ __launch_bounds__(256) void k_prepx(const float* __restrict__ fx, unsigned short* __restrict__ XB)
{
  int q = blockIdx.x*256 + threadIdx.x;           // 4*XBL
  int sig = q / XBL;
  int m   = q - sig*XBL;
  int a = m - PADX;
  float v = (a >= 0 && a < SEQ) ? fx[(size_t)sig*SEQ + a] : 0.f;
  XB[(size_t)sig*XBL + m] = f2bf(v);
}
__global__ __launch_bounds__(256) void k_prepir(const float* __restrict__ ir, unsigned short* __restrict__ IRV)
{
  int q = blockIdx.x*256 + threadIdx.x;           // 4*IRL
  int sig = q / IRL;
  int m   = q - sig*IRL;
  int a = m - 1024;
  float v = (a >= 0 && a < REV_N) ? ir[(size_t)sig*REV_N + (REV_N-1 - a)] : 0.f;
  IRV[(size_t)sig*IRL + m] = f2bf(v);
}

// ---------------- wet conv via MFMA (bf16 inputs, fp32 accum) ----------------
__global__ __launch_bounds__(256,3) void k_wetm(const unsigned short* __restrict__ XB,
    const unsigned short* __restrict__ IRV, unsigned short* __restrict__ WP)
{
  __shared__ alignas(16) unsigned int xs0[4640];
  __shared__ alignas(16) unsigned int xs1[4640];
  __shared__ alignas(16) unsigned short sir[3456];
  int b = blockIdx.x;                 // 1024 = 32 ngrp * 4 sig * 8 kp
  int ng  = b & 31;
  int sig = (b >> 5) & 3;
  int kp  = b >> 7;
  int nblk = ng << 13;                // *8192 outputs per block
  int sbeg = -62 + 520*kp;
  int send = sbeg + 520; if (send > 4097) send = 4097;

  int tid = threadIdx.x;
  int l  = tid & 63, wv = tid >> 6;
  int lj = l & 31, lg = l >> 5, ph = l & 1;
  int hl = (lj + 8*lg - ph) >> 1;
  int offB = 32*lj - 8*lg;
  const unsigned int* xbu = (const unsigned int*)(XB + (size_t)sig*XBL);
  const unsigned short* irg = IRV + (size_t)sig*IRL;
  const unsigned int* xsel = ph ? (const unsigned int*)xs1 : (const unsigned int*)xs0;

  f32x16 acc0 = {};
  f32x16 acc1 = {};
  int n0_0 = nblk + (wv*2+0)*1024;
  int n0_1 = nblk + (wv*2+1)*1024;

  for (int sa = sbeg; sa < send; sa += 128){
    int ns = send - sa; if (ns > 128) ns = 128;
    __syncthreads();
    // ---- stage x (two dword-phase arrays) ----
    int clo = nblk - 16*(sa + ns - 1);                 // even
    int ub  = (PADX + clo) >> 1;
    int nd  = ((nblk + 7168 + 46 - 16*sa) - clo)/2 + 2;
    for (int d = tid; d < nd; d += 256){
      unsigned int u0 = xbu[ub + d], u1 = xbu[ub + d + 1];
      xs0[d] = u0;
      xs1[d] = (u0 >> 16) | (u1 << 16);
    }
    // ---- stage reversed ir with +8/64 pad ----
    int amin = 65535 - 16*(sa + ns - 1) - 992;
    int irlo = ((amin - 7) & ~7) + 7;                  // <= amin, ==7 mod 8
    int irspan = (65535 - 16*sa + 15) - irlo + 1;
    for (int r = tid; r < irspan; r += 256){
      sir[r + ((r>>6)<<3)] = irg[1024 + irlo + r];
    }
    __syncthreads();
    // ---- compute ----
    int db0 = ((n0_0 - clo) >> 1) - 8*sa + hl;
    int db1 = ((n0_1 - clo) >> 1) - 8*sa + hl;
    int Dh0 = 65535 - 16*sa - irlo;
    for (int ss = 0; ss < ns; ss++){
      int rB = (Dh0 - 16*ss) - offB;
      short8v bfrag = *(const short8v*)(sir + rB + ((rB>>6)<<3));
      union { unsigned int u[4]; short8v v; } a0, a1;
      int d0 = db0 - 8*ss, d1 = db1 - 8*ss;
      a0.u[0]=xsel[d0];   a0.u[1]=xsel[d0+1]; a0.u[2]=xsel[d0+2]; a0.u[3]=xsel[d0+3];
      a1.u[0]=xsel[d1];   a1.u[1]=xsel[d1+1]; a1.u[2]=xsel[d1+2]; a1.u[3]=xsel[d1+3];
      acc0 = __builtin_amdgcn_mfma_f32_32x32x16_bf16(a0.v, bfrag, acc0, 0, 0, 0);
      acc1 = __builtin_amdgcn_mfma_f32_32x32x16_bf16(a1.v, bfrag, acc1, 0, 0, 0);
    }
  }
  // ---- writeout bf16 partials ----
  unsigned short* wp = WP + ((size_t)(kp*4+sig))*SEQ;
  #pragma unroll
  for (int reg = 0; reg < 16; reg++){
    int i = (reg & 3) + 8*(reg >> 2) + 4*lg;
    wp[n0_0 + i + 32*lj] = f2bf(acc0[reg]);
    wp[n0_1 + i + 32*lj] = f2bf(acc1[reg]);
  }
}

// ---------------- reduce partials + mix + add to master ----------------
__global__ __launch_bounds__(256) void k_wetred(const unsigned short* __restrict__ wp, const float* __restrict__ fx,
    const float* __restrict__ m0, const float* __restrict__ fxp, float* __restrict__ m1)
{
  int q = blockIdx.x*256 + threadIdx.x;   // 4*SEQ/4 threads
  int sig = q / (SEQ/4);
  int n = (q - sig*(SEQ/4))*4;
  float mix = fxp[(sig>>1)*25+24];
  size_t ob = (size_t)sig*SEQ + n;
  float s0=0.f, s1=0.f, s2=0.f, s3=0.f;
  #pragma unroll
  for (int kp=0; kp<8; kp++){
    const unsigned short* p = wp + ((size_t)(kp*4+sig))*SEQ + n;
    s0 += bf2f(p[0]); s1 += bf2f(p[1]); s2 += bf2f(p[2]); s3 += bf2f(p[3]);
  }
  float4 w0 = *(const float4*)(m0+ob);
  float4 x0 = *(const float4*)(fx+ob);
  float om = 1.f - mix;
  float4 o;
  o.x = w0.x + om*x0.x + mix*s0;
  o.y = w0.y + om*x0.y + mix*s1;
  o.z = w0.z + om*x0.z + mix*s2;
  o.w = w0.w + om*x0.w + mix*s3;
  *(float4*)(m1+ob) = o;
}

// ---------------- launch ----------------
extern "C" void kernel_launch(void* const* d_in, const int* in_sizes, int n_in,
                              void* d_out, int out_size, void* d_ws, size_t ws_size,
                              hipStream_t stream)
{
  const float* tracks = (const float*)d_in[0];
  const float* tp     = (const float*)d_in[1];
  const float* fxp    = (const float*)d_in[2];
  const float* mp     = (const float*)d_in[3];
  const float* noise  = (const float*)d_in[4];
  const float* fbp    = (const float*)d_in[5];
  float* out = (float*)d_out;
  char* w = (char*)d_ws;

  float*  X   = (float*)(w + OFF_X);
  float*  Y   = (float*)(w + OFF_Y);
  float*  FXb = (float*)(w + OFF_FX);
  float*  M0  = (float*)(w + OFF_M0);
  float2* E2  = (float2*)(w + OFF_E2);
  float2* I2  = (float2*)(w + OFF_I2);
  float*  E1  = (float*)(w + OFF_E1);
  float*  I1  = (float*)(w + OFF_I1);
  float*  GLt = (float*)(w + OFF_GL);
  float*  GLm = GLt + 32;
  SigP*   Pt  = (SigP*)(w + OFF_PT);
  SigP*   Pm  = (SigP*)(w + OFF_PM);
  MatP*   Mt  = (MatP*)(w + OFF_MT);
  MatP*   Mm  = (MatP*)(w + OFF_MM);
  double* aLt = (double*)(w + OFF_ALT);
  double* aLm = (double*)(w + OFF_ALM);
  float*  FILT= (float*)(w + OFF_FILT);
  float*  IR  = (float*)(w + OFF_IR);
  float*  XM  = (float*)(w + OFF_XM);
  float*  YM  = (float*)(w + OFF_YM);
  float*  M1  = (float*)(w + OFF_M1);
  unsigned short* WPu = (unsigned short*)(w + OFF_WP);
  unsigned short* XB  = (unsigned short*)(w + OFF_XB);
  unsigned short* IRV = (unsigned short*)(w + OFF_IR2);

  k_params<<<1,64,0,stream>>>(tp, mp, Pt, Pm, Mt, Mm, aLt, aLm);

  // ---- track chain: nsig=32, L=128, C=2048 ----
  const int GT = NS_T*C_T/256;   // 256 blocks
  const int QT = C_T/64, LGQT = 5;
  k_eqA0<<<GT,256,0,stream>>>(tracks, Pt, E2, NS_T, C_T, L_T);
  k_scan2p<<<NS_T,64,0,stream>>>(E2, I2, Mt, 0, C_T, QT, LGQT);
  k_eqC<false><<<GT,256,0,stream>>>(tracks, X, Pt, 0, I2, E2, nullptr, NS_T, C_T, L_T);
  k_scan2p<<<NS_T,64,0,stream>>>(E2, I2, Mt, 1, C_T, QT, LGQT);
  k_eqC<false><<<GT,256,0,stream>>>(X, Y, Pt, 1, I2, E2, nullptr, NS_T, C_T, L_T);
  k_scan2p<<<NS_T,64,0,stream>>>(E2, I2, Mt, 2, C_T, QT, LGQT);
  k_eqC<false><<<GT,256,0,stream>>>(Y, X, Pt, 2, I2, E2, nullptr, NS_T, C_T, L_T);
  k_scan2p<<<NS_T,64,0,stream>>>(E2, I2, Mt, 3, C_T, QT, LGQT);
  k_eqC<false><<<GT,256,0,stream>>>(X, Y, Pt, 3, I2, E2, nullptr, NS_T, C_T, L_T);
  k_scan2p<<<NS_T,64,0,stream>>>(E2, I2, Mt, 4, C_T, QT, LGQT);
  k_eqC<false><<<GT,256,0,stream>>>(Y, X, Pt, 4, I2, E2, nullptr, NS_T, C_T, L_T);
  k_scan2p<<<NS_T,64,0,stream>>>(E2, I2, Mt, 5, C_T, QT, LGQT);
  k_eqC<true><<<GT,256,0,stream>>>(X, Y, Pt, 5, I2, nullptr, E1, NS_T, C_T, L_T);
  k_scan1p<<<NS_T,64,0,stream>>>(E1, I1, aLt, C_T, QT, LGQT);
  k_smoothcomp<<<GT,256,0,stream>>>(Y, Pt, I1, GLt, X, C_T, L_T, LA_T/L_T);
  k_comptail<<<NS_T*(LA_T/4)/256,256,0,stream>>>(Y, GLt, Pt, X, LA_T);
  k_pan<<<2*(SEQ/4)/256,256,0,stream>>>(X, Pt, out, M0, FXb);

  // ---- reverb ----
  k_fir<<<48*32,256,0,stream>>>(noise, fbp, FILT);
  k_ir<<<4*(REV_N/4)/256,256,0,stream>>>(FILT, fxp, IR);
  k_prepx<<<(4*XBL)/256,256,0,stream>>>(FXb, XB);
  k_prepir<<<(4*IRL)/256,256,0,stream>>>(IR, IRV);
  k_wetm<<<1024,256,0,stream>>>(XB, IRV, WPu);
  k_wetred<<<4*(SEQ/4)/256,256,0,stream>>>(WPu, FXb, M0, fxp, M1);

  // ---- master chain: nsig=4, L=64, C=4096 ----
  const int GM = NS_M*C_M/256;   // 64 blocks
  const int QM = C_M/64, LGQM = 6;
  k_eqA0<<<GM,256,0,stream>>>(M1, Pm, E2, NS_M, C_M, L_M);
  k_scan2p<<<NS_M,64,0,stream>>>(E2, I2, Mm, 0, C_M, QM, LGQM);
  k_eqC<false><<<GM,256,0,stream>>>(M1, XM, Pm, 0, I2, E2, nullptr, NS_M, C_M, L_M);
  k_scan2p<<<NS_M,64,0,stream>>>(E2, I2, Mm, 1, C_M, QM, LGQM);
  k_eqC<false><<<GM,256,0,stream>>>(XM, YM, Pm, 1, I2, E2, nullptr, NS_M, C_M, L_M);
  k_scan2p<<<NS_M,64,0,stream>>>(E2, I2, Mm, 2, C_M, QM, LGQM);
  k_eqC<false><<<GM,256,0,stream>>>(YM, XM, Pm, 2, I2, E2, nullptr, NS_M, C_M, L_M);
  k_scan2p<<<NS_M,64,0,stream>>>(E2, I2, Mm, 3, C_M, QM, LGQM);
  k_eqC<false><<<GM,256,0,stream>>>(XM, YM, Pm, 3, I2, E2, nullptr, NS_M, C_M, L_M);
  k_scan2p<<<NS_M,64,0,stream>>>(E2, I2, Mm, 4, C_M, QM, LGQM);
  k_eqC<false><<<GM,256,0,stream>>>(YM, XM, Pm, 4, I2, E2, nullptr, NS_M, C_M, L_M);
  k_scan2p<<<NS_M,64,0,stream>>>(E2, I2, Mm, 5, C_M, QM, LGQM);
  k_eqC<true><<<GM,256,0,stream>>>(XM, YM, Pm, 5, I2, nullptr, E1, NS_M, C_M, L_M);
  k_scan1p<<<NS_M,64,0,stream>>>(E1, I1, aLm, C_M, QM, LGQM);
  k_smoothcomp<<<GM,256,0,stream>>>(YM, Pm, I1, GLm, out + OUT_MASTER_OFF, C_M, L_M, LA_M/L_M);
  k_comptail<<<NS_M*(LA_M/4)/256,256,0,stream>>>(YM, GLm, Pm, out + OUT_MASTER_OFF, LA_M);
}

// Round 9
// 647.667 us; speedup vs baseline: 8.5743x; 1.3288x over previous
//
#include <hip/hip_runtime.h>

#define DEVFN __device__ __forceinline__

constexpr int SEQ = 262144;
constexpr int REV_N = 65536;
constexpr int TAPS = 1023;
constexpr int NOISE_LEN = REV_N + TAPS - 1;   // 66558

constexpr int NS_T = 32, L_T = 128, C_T = 2048;   // track: 2048 chunks of 128
constexpr int NS_M = 4,  L_M = 64,  C_M = 4096;   // master: 4096 chunks of 64
constexpr int LA_T = 2048, LA_M = 1024;           // lookahead (16 chunks both)

// output layout: panned = B*2*NT*SEQ = 16,777,216 floats, then master = B*2*SEQ
constexpr int OUT_MASTER_OFF = 16777216;

// bf16 wet-conv buffers
constexpr int PADX = 65552;
constexpr int XBL  = 327744;
constexpr int IRL  = 67584;

#define C_DB  0.16609640474436813f   /* log2(10)/20 */
#define C_LOG 6.0205999132796239f    /* 20*log10(2) */
#define PI_D  3.14159265358979323846

typedef __attribute__((ext_vector_type(8)))  short short8v;
typedef __attribute__((ext_vector_type(16))) float f32x16;

struct SigP {
  float g_in;
  float cb0[6], cb1[6], cb2[6], ca1[6], ca2[6];
  float alpha, oma;
  float th, invr, knee, makeup;
  float g_out;
  float gl, gr, send;
};

// ---------------- workspace layout (bytes) ----------------
// Live ranges:
//  track chain : tracks(in), Y(y5), X(comp out), E12/I12/E1/I1 @ [FX, FX+6.8M) (FXb+M0 both unwritten yet)
//  k_pan       : X -> out, M0, FXb   (E dead)
//  reverb      : FILT/IR/XB/IRV/WP overlays (X dead), FXb, M0, M1(=Y head)
//  master chain: M1, XM (X region), E region again (FXb+M0 dead after wetred)
constexpr size_t OFF_X   = 0;                       // 33,554,432
constexpr size_t OFF_Y   = 33554432;                // 33,554,432
constexpr size_t OFF_FX  = 67108864;                // 4 MB
constexpr size_t OFF_M0  = 71303168;                // 4 MB
// overlays (X dead after pan):
constexpr size_t OFF_FILT = OFF_X;                       // 12,582,912
constexpr size_t OFF_IR   = OFF_X + 12582912;            // 1 MB
constexpr size_t OFF_XM   = OFF_X + 16777216;            // 4 MB master y5
constexpr size_t OFF_M1   = OFF_Y;                       // 4 MB master input
constexpr size_t OFF_WP   = OFF_Y + 4194304;             // 16 MB wet partials
constexpr size_t OFF_XB   = OFF_WP + 16777216;           // 2.62 MB padded bf16 x
constexpr size_t OFF_IR2  = OFF_XB + (size_t)4*XBL*2;    // 540 KB reversed bf16 ir
// E buffers overlay FXb+M0 (free during both chain phases):
constexpr size_t OFF_E12 = OFF_FX;                       // 32*2048*12*4 = 3,145,728
constexpr size_t OFF_I12 = OFF_FX + 3145728;             // 3,145,728
constexpr size_t OFF_E1  = OFF_FX + 6291456;             // 262,144
constexpr size_t OFF_I1  = OFF_FX + 6553600;             // 262,144 (ends 6,815,744 < 8,388,608)
// persistent small region past M0:
constexpr size_t OFF_GL  = 75497472;
constexpr size_t OFF_PT  = OFF_GL + 1024;
constexpr size_t OFF_PM  = OFF_PT + 32*sizeof(SigP);
constexpr size_t OFF_ALT = (OFF_PM + 4*sizeof(SigP) + 7) & ~(size_t)7;
constexpr size_t OFF_ALM = OFF_ALT + 32*8;
constexpr size_t OFF_AT  = (OFF_ALM + 4*8 + 15) & ~(size_t)15;  // float 32*144*4 = 18,432
constexpr size_t OFF_AM  = OFF_AT + 18432;                      // float 4*144*4 = 2,304

// padded LDS index: one float4 pad per 8 float4s
DEVFN int pq(int i){ return i + ((i >> 5) << 2); }

DEVFN unsigned short f2bf(float f){
  unsigned int u = __float_as_uint(f);
  unsigned int r = (u + 0x7fffu + ((u >> 16) & 1u)) >> 16;
  return (unsigned short)r;
}
DEVFN float bf2f(unsigned short h){ return __uint_as_float(((unsigned int)h) << 16); }

// ---------------- params kernel ----------------
DEVFN double dn(float p, double lo, double hi){ return (double)p*(hi-lo)+lo; }

__device__ void mk_sig(const float* p, int L, bool is_master,
                       SigP* sp, float* Tf, double* aL)
{
  const double flo[6] = {20.,80.,2000.,8000.,12000.,6000.};
  const double fhi[6] = {2000.,2000.,8000.,12000.,21050.,21050.};
  double gdb = dn(p[0], -48., 48.);
  sp->g_in = (float)exp2(gdb * 0.16609640474436813);
  double db0[6],db1[6],db2[6],da1[6],da2[6];
  for (int k=0;k<6;k++){
    double g  = dn(p[1+3*k], -12., 12.);
    double fc = dn(p[2+3*k], flo[k], fhi[k]);
    double q  = dn(p[3+3*k], 0.1, 5.0);
    double A  = pow(10.0, g/40.0);
    double w0 = 2.0*PI_D*(fc/44100.0);
    double al = sin(w0)/(2.0*q), co = cos(w0), sA = sqrt(A);
    double b0,b1,b2,a0,a1,a2;
    if (k==0){                       // low shelf
      b0 = A*((A+1.0) - (A-1.0)*co + 2.0*sA*al);
      b1 = 2.0*A*((A-1.0) - (A+1.0)*co);
      b2 = A*((A+1.0) - (A-1.0)*co - 2.0*sA*al);
      a0 = (A+1.0) + (A-1.0)*co + 2.0*sA*al;
      a1 = -2.0*((A-1.0) + (A+1.0)*co);
      a2 = (A+1.0) + (A-1.0)*co - 2.0*sA*al;
    } else if (k==5){                // high shelf
      b0 = A*((A+1.0) + (A-1.0)*co + 2.0*sA*al);
      b1 = -2.0*A*((A-1.0) + (A+1.0)*co);
      b2 = A*((A+1.0) + (A-1.0)*co - 2.0*sA*al);
      a0 = (A+1.0) - (A-1.0)*co + 2.0*sA*al;
      a1 = 2.0*((A-1.0) - (A+1.0)*co);
      a2 = (A+1.0) - (A-1.0)*co - 2.0*sA*al;
    } else {                         // peaking
      b0 = 1.0 + al*A; b1 = -2.0*co; b2 = 1.0 - al*A;
      a0 = 1.0 + al/A; a1 = -2.0*co; a2 = 1.0 - al/A;
    }
    double ia0 = 1.0/a0;
    db0[k]=b0*ia0; db1[k]=b1*ia0; db2[k]=b2*ia0; da1[k]=a1*ia0; da2[k]=a2*ia0;
    sp->cb0[k]=(float)db0[k]; sp->cb1[k]=(float)db1[k]; sp->cb2[k]=(float)db2[k];
    sp->ca1[k]=(float)da1[k]; sp->ca2[k]=(float)da2[k];
  }
  // 12x12 zero-input transition T by basis propagation
  for (int i=0;i<12;i++){
    double st[12]; for (int r=0;r<12;r++) st[r]=0.0; st[i]=1.0;
    double ns[12];
    double yprev=0.0, pm1=0.0, pm2=0.0;
    for (int k=0;k<6;k++){
      double yk = db0[k]*yprev + db1[k]*pm1 + db2[k]*pm2 - da1[k]*st[2*k] - da2[k]*st[2*k+1];
      ns[2*k]=yk; ns[2*k+1]=st[2*k];
      pm1=st[2*k]; pm2=st[2*k+1];
      yprev=yk;
    }
    for (int r=0;r<12;r++) Tf[r*12+i]=(float)ns[r];
  }
  double th    = dn(p[19], -60., 0.);
  double ratio = dn(p[20], 1., 10.);
  double at    = dn(p[21], 5., 250.);
  double knee  = dn(p[23], 3., 12.);
  double mkup  = dn(p[24], 0., 6.);
  double alpha = exp(-log(9.0)/(44100.0*at*0.001));
  sp->alpha=(float)alpha; sp->oma=(float)(1.0-alpha);
  sp->th=(float)th; sp->invr=(float)(1.0/ratio); sp->knee=(float)knee; sp->makeup=(float)mkup;
  *aL = pow(alpha, (double)L);
  if (is_master){
    sp->g_out = (float)exp2(dn(p[25],-48.,48.)*0.16609640474436813);
    sp->gl=0.f; sp->gr=0.f; sp->send=0.f;
  } else {
    sp->g_out = 1.f;
    sp->send = (float)exp2(dn(p[25],-80.,12.)*0.16609640474436813);
    double th2 = dn(p[26],0.,1.)*(PI_D/2.0);
    sp->gl = (float)sqrt((PI_D/2.0-th2)*(2.0/PI_D)*cos(th2));
    sp->gr = (float)sqrt(th2*(2.0/PI_D)*sin(th2));
  }
}

__global__ __launch_bounds__(64) void k_params(const float* __restrict__ tp, const float* __restrict__ mp,
    SigP* Pt, SigP* Pm, float* AT, float* AM, double* aLt, double* aLm)
{
  int i = threadIdx.x;
  if (i < 32)       mk_sig(tp + i*27, L_T, false, &Pt[i], AT + i*144, &aLt[i]);
  else if (i < 36){ int j=i-32; mk_sig(mp + (j>>1)*26, L_M, true, &Pm[j], AM + j*144, &aLm[j]); }
}

// ---------------- A <- A^(2^lg), 64-lane parallel LDS squaring ----------------
__global__ __launch_bounds__(64) void k_power(float* __restrict__ Ab, int lg)
{
  __shared__ float Ma[144], Mb[144];
  int sig = blockIdx.x, t = threadIdx.x;
  float* A = Ab + (size_t)sig*144;
  for (int idx=t; idx<144; idx+=64) Ma[idx]=A[idx];
  __syncthreads();
  int cur=0;
  for (int j=0;j<lg;j++){
    const float* src = cur? Mb:Ma;
    float* dst = cur? Ma:Mb;
    for (int idx=t; idx<144; idx+=64){
      int r=idx/12, cc=idx-r*12;
      float v=0.f;
      #pragma unroll
      for (int m=0;m<12;m++) v = fmaf(src[r*12+m], src[m*12+cc], v);
      dst[idx]=v;
    }
    __syncthreads();
    cur^=1;
  }
  const float* fin = cur? Mb:Ma;
  for (int idx=t; idx<144; idx+=64) A[idx]=fin[idx];
}

// ---------------- compressor gain computer ----------------
DEVFN float comp_gc(float y, float th, float invr, float kn){
  float av  = fmaxf(fabsf(y), 1e-8f);
  float xdb = C_LOG * __builtin_log2f(av);
  float d   = xdb - th;
  float w = (2.f*d < -kn) ? 0.f
          : ((2.f*fabsf(d) <= kn) ? (d+0.5f*kn)*(d+0.5f*kn)/(2.f*kn) : d);
  return (invr-1.f)*w;
}

// ---------------- A-pass: 6-section cascade, zero state -> 12 end-states ----------------
__global__ __launch_bounds__(256) void k_eqA12(const float* __restrict__ in, const SigP* __restrict__ P,
    float* __restrict__ E12, int C, int L)
{
  int tid = blockIdx.x*256 + threadIdx.x;
  int sig = tid / C, c = tid - sig*C;
  const SigP* sp = P + sig;
  float B0[6],B1[6],B2[6],A1[6],A2[6];
  float g = sp->g_in;
  #pragma unroll
  for (int k=0;k<6;k++){
    float gg = (k==0)? g : 1.f;
    B0[k]=sp->cb0[k]*gg; B1[k]=sp->cb1[k]*gg; B2[k]=sp->cb2[k]*gg;
    A1[k]=sp->ca1[k];    A2[k]=sp->ca2[k];
  }
  const float* xp = in + (size_t)sig*SEQ + (size_t)c*L;
  float xm1=0.f, xm2=0.f;
  if (c){ xm1=xp[-1]; xm2=xp[-2]; }
  float s[12];
  #pragma unroll
  for (int r=0;r<12;r++) s[r]=0.f;
  for (int i=0;i<L;i+=4){
    float4 v = *(const float4*)(xp+i);
    #pragma unroll
    for (int u4=0;u4<4;u4++){
      float u = (u4==0)?v.x:(u4==1)?v.y:(u4==2)?v.z:v.w;
      float yprev=u, pm1=xm1, pm2=xm2;
      float ny[6];
      #pragma unroll
      for (int k=0;k<6;k++){
        float t0 = fmaf(B0[k],yprev, fmaf(B1[k],pm1, fmaf(B2[k],pm2, -A2[k]*s[2*k+1])));
        float yk = fmaf(-A1[k], s[2*k], t0);
        ny[k]=yk;
        pm1=s[2*k]; pm2=s[2*k+1];
        yprev=yk;
      }
      #pragma unroll
      for (int k=0;k<6;k++){ s[2*k+1]=s[2*k]; s[2*k]=ny[k]; }
      xm2=xm1; xm1=u;
    }
  }
  float* ep = E12 + (size_t)tid*12;
  #pragma unroll
  for (int r=0;r<12;r++) ep[r]=s[r];
}

// ---------------- 12-state affine scan (two-level) ----------------
__global__ __launch_bounds__(64) void k_scan12(const float* __restrict__ E, float* __restrict__ I,
    const float* __restrict__ Ab, int C, int Q, int lgQ)
{
  __shared__ float As[144], Pa[144], Pb[144];
  __shared__ float seg[64][12], ini[64][12];
  __shared__ float scur[12], stmp[12];
  int sig = blockIdx.x, t = threadIdx.x;
  const float* Asig = Ab + (size_t)sig*144;
  for (int idx=t; idx<144; idx+=64) As[idx]=Asig[idx];
  __syncthreads();
  // phase 1: per-lane aggregate over Q chunks
  const float* dp = E + ((size_t)sig*C + (size_t)t*Q)*12;
  float s[12];
  #pragma unroll
  for (int r=0;r<12;r++) s[r]=0.f;
  for (int j=0;j<Q;j++){
    const float* d = dp + j*12;
    float ns[12];
    #pragma unroll
    for (int r=0;r<12;r++){
      float v = d[r];
      #pragma unroll
      for (int cc=0;cc<12;cc++) v = fmaf(As[r*12+cc], s[cc], v);
      ns[r]=v;
    }
    #pragma unroll
    for (int r=0;r<12;r++) s[r]=ns[r];
  }
  #pragma unroll
  for (int r=0;r<12;r++) seg[t][r]=s[r];
  // phase 2a: AQ = As^(2^lgQ)
  for (int idx=t; idx<144; idx+=64) Pa[idx]=As[idx];
  __syncthreads();
  int cur=0;
  for (int j=0;j<lgQ;j++){
    const float* src = cur? Pb:Pa;
    float* dst = cur? Pa:Pb;
    for (int idx=t; idx<144; idx+=64){
      int r=idx/12, cc=idx-r*12;
      float v=0.f;
      #pragma unroll
      for (int m=0;m<12;m++) v = fmaf(src[r*12+m], src[m*12+cc], v);
      dst[idx]=v;
    }
    __syncthreads();
    cur^=1;
  }
  const float* AQ = cur? Pb:Pa;
  // phase 2b: sequential combine across 64 segments (12-lane parallel)
  if (t<12) scur[t]=0.f;
  __syncthreads();
  for (int u=0;u<64;u++){
    if (t<12){
      ini[u][t]=scur[t];
      float v = seg[u][t];
      #pragma unroll
      for (int cc=0;cc<12;cc++) v = fmaf(AQ[t*12+cc], scur[cc], v);
      stmp[t]=v;
    }
    __syncthreads();
    if (t<12) scur[t]=stmp[t];
    __syncthreads();
  }
  // phase 3: re-emit per-chunk exclusive states
  #pragma unroll
  for (int r=0;r<12;r++) s[r]=ini[t][r];
  float* op = I + ((size_t)sig*C + (size_t)t*Q)*12;
  for (int j=0;j<Q;j++){
    float* o = op + j*12;
    #pragma unroll
    for (int r=0;r<12;r++) o[r]=s[r];
    const float* d = dp + j*12;
    float ns[12];
    #pragma unroll
    for (int r=0;r<12;r++){
      float v = d[r];
      #pragma unroll
      for (int cc=0;cc<12;cc++) v = fmaf(As[r*12+cc], s[cc], v);
      ns[r]=v;
    }
    #pragma unroll
    for (int r=0;r<12;r++) s[r]=ns[r];
  }
}

// ---------------- 1-state scan (smoother), LDS serial combine ----------------
__global__ __launch_bounds__(64) void k_scan1p(const float* __restrict__ endst, float* __restrict__ inits,
    const double* __restrict__ aL, int C, int Q, int lgQ)
{
  __shared__ double ag[64], ins[64];
  int sig = blockIdx.x; int t = threadIdx.x;
  double a = aL[sig];
  const float* dp = endst + (size_t)sig*C + (size_t)t*Q;
  double e=0.0;
  for (int j=0;j<Q;j++) e = a*e + (double)dp[j];
  ag[t]=e;
  __syncthreads();
  if (t == 0){
    double p=a;
    for (int j=0;j<lgQ;j++) p = p*p;
    double s=0.0;
    for (int u=0;u<64;u++){
      ins[u]=s;
      s = p*s + ag[u];
    }
  }
  __syncthreads();
  double s = ins[t];
  float* op = inits + (size_t)sig*C + (size_t)t*Q;
  for (int j=0;j<Q;j++){ op[j]=(float)s; s = a*s + (double)dp[j]; }
}

// ---------------- C-pass: cascade with inits -> y5 + smoother aggregate ----------------
__global__ __launch_bounds__(256) void k_eqC12(const float* __restrict__ in, float* __restrict__ yout,
    const SigP* __restrict__ P, const float* __restrict__ I12, float* __restrict__ E1, int C, int L)
{
  int tid = blockIdx.x*256 + threadIdx.x;
  int sig = tid / C, c = tid - sig*C;
  const SigP* sp = P + sig;
  float B0[6],B1[6],B2[6],A1[6],A2[6];
  float g = sp->g_in;
  #pragma unroll
  for (int k=0;k<6;k++){
    float gg = (k==0)? g : 1.f;
    B0[k]=sp->cb0[k]*gg; B1[k]=sp->cb1[k]*gg; B2[k]=sp->cb2[k]*gg;
    A1[k]=sp->ca1[k];    A2[k]=sp->ca2[k];
  }
  float al=sp->alpha, oma=sp->oma, th=sp->th, invr=sp->invr, kn=sp->knee;
  size_t base = (size_t)sig*SEQ + (size_t)c*L;
  const float* xp = in + base;
  float* op = yout + base;
  float xm1=0.f, xm2=0.f;
  if (c){ xm1=xp[-1]; xm2=xp[-2]; }
  const float* ip = I12 + (size_t)tid*12;
  float s[12];
  #pragma unroll
  for (int r=0;r<12;r++) s[r]=ip[r];
  float gacc=0.f;
  for (int i=0;i<L;i+=4){
    float4 v = *(const float4*)(xp+i);
    float4 o;
    #pragma unroll
    for (int u4=0;u4<4;u4++){
      float u = (u4==0)?v.x:(u4==1)?v.y:(u4==2)?v.z:v.w;
      float yprev=u, pm1=xm1, pm2=xm2;
      float ny[6];
      #pragma unroll
      for (int k=0;k<6;k++){
        float t0 = fmaf(B0[k],yprev, fmaf(B1[k],pm1, fmaf(B2[k],pm2, -A2[k]*s[2*k+1])));
        float yk = fmaf(-A1[k], s[2*k], t0);
        ny[k]=yk;
        pm1=s[2*k]; pm2=s[2*k+1];
        yprev=yk;
      }
      #pragma unroll
      for (int k=0;k<6;k++){ s[2*k+1]=s[2*k]; s[2*k]=ny[k]; }
      xm2=xm1; xm1=u;
      float y5 = ny[5];
      if (u4==0) o.x=y5; else if (u4==1) o.y=y5; else if (u4==2) o.z=y5; else o.w=y5;
      gacc = fmaf(al, gacc, oma*comp_gc(y5,th,invr,kn));
    }
    *(float4*)(op+i) = o;
  }
  E1[tid]=gacc;
}

// ---------------- fused smoother + compressor apply ----------------
__global__ __launch_bounds__(256) void k_smoothcomp(const float* __restrict__ yin,
    const SigP* __restrict__ P, const float* __restrict__ inits1, float* __restrict__ gslast,
    float* __restrict__ outp, int C, int L, int lac)
{
  int tid = blockIdx.x*256 + threadIdx.x;
  int sig = tid / C, c = tid - sig*C;
  const SigP* sp = P + sig;
  float al=sp->alpha, oma=sp->oma, th=sp->th, invr=sp->invr, kn=sp->knee;
  float mk=sp->makeup, go=sp->g_out;
  size_t base = (size_t)sig*SEQ + (size_t)c*L;
  const float* xp = yin + base;
  bool wr = (c >= lac);
  size_t ob = wr ? (base - (size_t)lac*L) : 0;
  const float* yp = yin + ob;
  float* op = outp + ob;
  float gsv = inits1[tid];
  for (int i=0;i<L;i+=4){
    float4 v = *(const float4*)(xp+i);
    float4 gf;
    gsv = fmaf(al, gsv, oma*comp_gc(v.x,th,invr,kn)); gf.x=gsv;
    gsv = fmaf(al, gsv, oma*comp_gc(v.y,th,invr,kn)); gf.y=gsv;
    gsv = fmaf(al, gsv, oma*comp_gc(v.z,th,invr,kn)); gf.z=gsv;
    gsv = fmaf(al, gsv, oma*comp_gc(v.w,th,invr,kn)); gf.w=gsv;
    if (wr){
      float4 y2 = *(const float4*)(yp+i);
      float4 o;
      o.x = y2.x * __builtin_exp2f((gf.x+mk)*C_DB) * go;
      o.y = y2.y * __builtin_exp2f((gf.y+mk)*C_DB) * go;
      o.z = y2.z * __builtin_exp2f((gf.z+mk)*C_DB) * go;
      o.w = y2.w * __builtin_exp2f((gf.w+mk)*C_DB) * go;
      *(float4*)(op+i) = o;
    }
  }
  if (c == C-1) gslast[sig] = gsv;
}

// ---------------- tail: last `la` samples use clamped gs[SEQ-1] ----------------
__global__ __launch_bounds__(256) void k_comptail(const float* __restrict__ yin, const float* __restrict__ gslast,
    const SigP* __restrict__ P, float* __restrict__ outp, int la)
{
  int q = blockIdx.x*256 + threadIdx.x;
  int per = la/4;
  int sig = q / per;
  int r = (q - sig*per)*4;
  int n = SEQ - la + r;
  const SigP* sp = P + sig;
  float f = __builtin_exp2f((gslast[sig]+sp->makeup)*C_DB) * sp->g_out;
  size_t base = (size_t)sig*SEQ + n;
  float4 v = *(const float4*)(yin+base);
  float4 o = { v.x*f, v.y*f, v.z*f, v.w*f };
  *(float4*)(outp+base) = o;
}

// ---------------- pan + master/fx sums ----------------
__global__ __launch_bounds__(256) void k_pan(const float* __restrict__ y, const SigP* __restrict__ P,
    float* __restrict__ panned, float* __restrict__ m0, float* __restrict__ fx)
{
  int q = blockIdx.x*256 + threadIdx.x;
  int b = q / (SEQ/4);
  int n = (q - b*(SEQ/4))*4;
  float4 aL={0,0,0,0}, aR={0,0,0,0}, fL={0,0,0,0}, fR={0,0,0,0};
  for (int t=0;t<16;t++){
    const SigP* sp = P + b*16 + t;
    float gl=sp->gl, gr=sp->gr, sd=sp->send;
    float4 v = *(const float4*)(y + (size_t)(b*16+t)*SEQ + n);
    float4 pl = { v.x*gl, v.y*gl, v.z*gl, v.w*gl };
    float4 pr = { v.x*gr, v.y*gr, v.z*gr, v.w*gr };
    *(float4*)(panned + (size_t)(b*32+t)*SEQ + n)    = pl;
    *(float4*)(panned + (size_t)(b*32+16+t)*SEQ + n) = pr;
    aL.x+=pl.x; aL.y+=pl.y; aL.z+=pl.z; aL.w+=pl.w;
    aR.x+=pr.x; aR.y+=pr.y; aR.z+=pr.z; aR.w+=pr.w;
    fL.x=fmaf(pl.x,sd,fL.x); fL.y=fmaf(pl.y,sd,fL.y); fL.z=fmaf(pl.z,sd,fL.z); fL.w=fmaf(pl.w,sd,fL.w);
    fR.x=fmaf(pr.x,sd,fR.x); fR.y=fmaf(pr.y,sd,fR.y); fR.z=fmaf(pr.z,sd,fR.z); fR.w=fmaf(pr.w,sd,fR.w);
  }
  *(float4*)(m0 + (size_t)(b*2+0)*SEQ + n) = aL;
  *(float4*)(m0 + (size_t)(b*2+1)*SEQ + n) = aR;
  *(float4*)(fx + (size_t)(b*2+0)*SEQ + n) = fL;
  *(float4*)(fx + (size_t)(b*2+1)*SEQ + n) = fR;
}

// ---------------- reverb band FIR ----------------
__global__ __launch_bounds__(256) void k_fir(const float* __restrict__ noise, const float* __restrict__ fb,
    float* __restrict__ filt)
{
  __shared__ alignas(16) float sx[3456];
  __shared__ alignas(16) float sf[1152];
  int sig = blockIdx.x >> 5;
  int n0  = (blockIdx.x & 31) * 2048;
  int band = sig % 12;
  const float* np_ = noise + (size_t)sig*NOISE_LEN + n0;
  for (int i=threadIdx.x; i<3072; i+=256) sx[pq(i)] = (i<3070) ? np_[i] : 0.f;
  for (int i=threadIdx.x; i<1024; i+=256) sf[pq(i)] = (i<1023) ? fb[band*TAPS + 1022 - i] : 0.f;
  __syncthreads();
  int t = threadIdx.x;
  float acc[8];
  #pragma unroll
  for (int j=0;j<8;j++) acc[j]=0.f;
  float w[16];
  int wb = 8*t;
  #pragma unroll
  for (int m=0;m<16;m+=4){
    float4 qq = *(const float4*)(sx+pq(wb+m));
    w[m]=qq.x; w[m+1]=qq.y; w[m+2]=qq.z; w[m+3]=qq.w;
  }
  for (int ut=0; ut<128; ut++){
    float4 f0 = *(const float4*)(sf + pq(8*ut));
    float4 f1 = *(const float4*)(sf + pq(8*ut + 4));
    float f[8] = {f0.x,f0.y,f0.z,f0.w,f1.x,f1.y,f1.z,f1.w};
    #pragma unroll
    for (int d=0;d<8;d++)
      #pragma unroll
      for (int j=0;j<8;j++)
        acc[j] = fmaf(f[d], w[j+d], acc[j]);
    if (ut<127){
      #pragma unroll
      for (int m=0;m<8;m++) w[m]=w[m+8];
      float4 q0 = *(const float4*)(sx + pq(wb + 8*ut + 16));
      float4 q1 = *(const float4*)(sx + pq(wb + 8*ut + 20));
      w[8]=q0.x; w[9]=q0.y; w[10]=q0.z; w[11]=q0.w;
      w[12]=q1.x; w[13]=q1.y; w[14]=q1.z; w[15]=q1.w;
    }
  }
  float* op = filt + (size_t)sig*REV_N + n0 + 8*t;
  float4 o0={acc[0],acc[1],acc[2],acc[3]}, o1={acc[4],acc[5],acc[6],acc[7]};
  *(float4*)(op)   = o0;
  *(float4*)(op+4) = o1;
}

// ---------------- ir = mean over bands of filt*env*gain ----------------
__global__ __launch_bounds__(256) void k_ir(const float* __restrict__ filt, const float* __restrict__ fxp,
    float* __restrict__ ir)
{
  int q = blockIdx.x*256 + threadIdx.x;
  int sig = q / (REV_N/4);
  int i   = (q - sig*(REV_N/4))*4;
  int b = sig >> 1;
  float4 acc={0,0,0,0};
  const float ts = 1.0f/65535.0f;
  for (int band=0; band<12; band++){
    float gn  = fxp[b*25 + band];
    float dec = fxp[b*25 + 12 + band]*10.f + 1.f;
    float4 f = *(const float4*)(filt + ((size_t)(sig*12+band))*REV_N + i);
    float s = -dec*ts;
    float e0=expf(s*(float)i), e1=expf(s*(float)(i+1)), e2=expf(s*(float)(i+2)), e3=expf(s*(float)(i+3));
    acc.x = fmaf(gn*e0, f.x, acc.x);
    acc.y = fmaf(gn*e1, f.y, acc.y);
    acc.z = fmaf(gn*e2, f.z, acc.z);
    acc.w = fmaf(gn*e3, f.w, acc.w);
  }
  const float inv12 = 1.f/12.f;
  acc.x*=inv12; acc.y*=inv12; acc.z*=inv12; acc.w*=inv12;
  *(float4*)(ir + (size_t)sig*REV_N + i) = acc;
}

// ---------------- bf16 prep ----------------
__global__ __launch_bounds__(256) void k_prepx(const float* __restrict__ fx, unsigned short* __restrict__ XB)
{
  int q = blockIdx.x*256 + threadIdx.x;
  int sig = q / XBL;
  int m   = q - sig*XBL;
  int a = m - PADX;
  float v = (a >= 0 && a < SEQ) ? fx[(size_t)sig*SEQ + a] : 0.f;
  XB[(size_t)sig*XBL + m] = f2bf(v);
}
__global__ __launch_bounds__(256) void k_prepir(const float* __restrict__ ir, unsigned short* __restrict__ IRV)
{
  int q = blockIdx.x*256 + threadIdx.x;
  int sig = q / IRL;
  int m   = q - sig*IRL;
  int a = m - 1024;
  float v = (a >= 0 && a < REV_N) ? ir[(size_t)sig*REV_N + (REV_N-1 - a)] : 0.f;
  IRV[(size_t)sig*IRL + m] = f2bf(v);
}

// ---------------- wet conv via MFMA ----------------
__global__ __launch_bounds__(256,3) void k_wetm(const unsigned short* __restrict__ XB,
    const unsigned short* __restrict__ IRV, unsigned short* __restrict__ WP)
{
  __shared__ alignas(16) unsigned int xs0[4640];
  __shared__ alignas(16) unsigned int xs1[4640];
  __shared__ alignas(16) unsigned short sir[3456];
  int b = blockIdx.x;
  int ng  = b & 31;
  int sig = (b >> 5) & 3;
  int kp  = b >> 7;
  int nblk = ng << 13;
  int sbeg = -62 + 520*kp;
  int send = sbeg + 520; if (send > 4097) send = 4097;

  int tid = threadIdx.x;
  int l  = tid & 63, wv = tid >> 6;
  int lj = l & 31, lg = l >> 5, ph = l & 1;
  int hl = (lj + 8*lg - ph) >> 1;
  int offB = 32*lj - 8*lg;
  const unsigned int* xbu = (const unsigned int*)(XB + (size_t)sig*XBL);
  const unsigned short* irg = IRV + (size_t)sig*IRL;
  const unsigned int* xsel = ph ? (const unsigned int*)xs1 : (const unsigned int*)xs0;

  f32x16 acc0 = {};
  f32x16 acc1 = {};
  int n0_0 = nblk + (wv*2+0)*1024;
  int n0_1 = nblk + (wv*2+1)*1024;

  for (int sa = sbeg; sa < send; sa += 128){
    int ns = send - sa; if (ns > 128) ns = 128;
    __syncthreads();
    int clo = nblk - 16*(sa + ns - 1);
    int ub  = (PADX + clo) >> 1;
    int nd  = ((nblk + 7168 + 46 - 16*sa) - clo)/2 + 2;
    for (int d = tid; d < nd; d += 256){
      unsigned int u0 = xbu[ub + d], u1 = xbu[ub + d + 1];
      xs0[d] = u0;
      xs1[d] = (u0 >> 16) | (u1 << 16);
    }
    int amin = 65535 - 16*(sa + ns - 1) - 992;
    int irlo = ((amin - 7) & ~7) + 7;
    int irspan = (65535 - 16*sa + 15) - irlo + 1;
    for (int r = tid; r < irspan; r += 256){
      sir[r + ((r>>6)<<3)] = irg[1024 + irlo + r];
    }
    __syncthreads();
    int db0 = ((n0_0 - clo) >> 1) - 8*sa + hl;
    int db1 = ((n0_1 - clo) >> 1) - 8*sa + hl;
    int Dh0 = 65535 - 16*sa - irlo;
    for (int ss = 0; ss < ns; ss++){
      int rB = (Dh0 - 16*ss) - offB;
      short8v bfrag = *(const short8v*)(sir + rB + ((rB>>6)<<3));
      union { unsigned int u[4]; short8v v; } a0, a1;
      int d0 = db0 - 8*ss, d1 = db1 - 8*ss;
      a0.u[0]=xsel[d0];   a0.u[1]=xsel[d0+1]; a0.u[2]=xsel[d0+2]; a0.u[3]=xsel[d0+3];
      a1.u[0]=xsel[d1];   a1.u[1]=xsel[d1+1]; a1.u[2]=xsel[d1+2]; a1.u[3]=xsel[d1+3];
      acc0 = __builtin_amdgcn_mfma_f32_32x32x16_bf16(a0.v, bfrag, acc0, 0, 0, 0);
      acc1 = __builtin_amdgcn_mfma_f32_32x32x16_bf16(a1.v, bfrag, acc1, 0, 0, 0);
    }
  }
  unsigned short* wp = WP + ((size_t)(kp*4+sig))*SEQ;
  #pragma unroll
  for (int reg = 0; reg < 16; reg++){
    int i = (reg & 3) + 8*(reg >> 2) + 4*lg;
    wp[n0_0 + i + 32*lj] = f2bf(acc0[reg]);
    wp[n0_1 + i + 32*lj] = f2bf(acc1[reg]);
  }
}

// ---------------- reduce partials + mix + add to master ----------------
__global__ __launch_bounds__(256) void k_wetred(const unsigned short* __restrict__ wp, const float* __restrict__ fx,
    const float* __restrict__ m0, const float* __restrict__ fxp, float* __restrict__ m1)
{
  int q = blockIdx.x*256 + threadIdx.x;
  int sig = q / (SEQ/4);
  int n = (q - sig*(SEQ/4))*4;
  float mix = fxp[(sig>>1)*25+24];
  size_t ob = (size_t)sig*SEQ + n;
  float s0=0.f, s1=0.f, s2=0.f, s3=0.f;
  #pragma unroll
  for (int kp=0; kp<8; kp++){
    const unsigned short* p = wp + ((size_t)(kp*4+sig))*SEQ + n;
    s0 += bf2f(p[0]); s1 += bf2f(p[1]); s2 += bf2f(p[2]); s3 += bf2f(p[3]);
  }
  float4 w0 = *(const float4*)(m0+ob);
  float4 x0 = *(const float4*)(fx+ob);
  float om = 1.f - mix;
  float4 o;
  o.x = w0.x + om*x0.x + mix*s0;
  o.y = w0.y + om*x0.y + mix*s1;
  o.z = w0.z + om*x0.z + mix*s2;
  o.w = w0.w + om*x0.w + mix*s3;
  *(float4*)(m1+ob) = o;
}

// ---------------- launch ----------------
extern "C" void kernel_launch(void* const* d_in, const int* in_sizes, int n_in,
                              void* d_out, int out_size, void* d_ws, size_t ws_size,
                              hipStream_t stream)
{
  const float* tracks = (const float*)d_in[0];
  const float* tp     = (const float*)d_in[1];
  const float* fxp    = (const float*)d_in[2];
  const float* mp     = (const float*)d_in[3];
  const float* noise  = (const float*)d_in[4];
  const float* fbp    = (const float*)d_in[5];
  float* out = (float*)d_out;
  char* w = (char*)d_ws;

  float*  X   = (float*)(w + OFF_X);
  float*  Y   = (float*)(w + OFF_Y);
  float*  FXb = (float*)(w + OFF_FX);
  float*  M0  = (float*)(w + OFF_M0);
  float*  E12 = (float*)(w + OFF_E12);
  float*  I12 = (float*)(w + OFF_I12);
  float*  E1  = (float*)(w + OFF_E1);
  float*  I1  = (float*)(w + OFF_I1);
  float*  GLt = (float*)(w + OFF_GL);
  float*  GLm = GLt + 32;
  SigP*   Pt  = (SigP*)(w + OFF_PT);
  SigP*   Pm  = (SigP*)(w + OFF_PM);
  double* aLt = (double*)(w + OFF_ALT);
  double* aLm = (double*)(w + OFF_ALM);
  float*  AT  = (float*)(w + OFF_AT);
  float*  AM  = (float*)(w + OFF_AM);
  float*  FILT= (float*)(w + OFF_FILT);
  float*  IR  = (float*)(w + OFF_IR);
  float*  XM  = (float*)(w + OFF_XM);
  float*  M1  = (float*)(w + OFF_M1);
  unsigned short* WPu = (unsigned short*)(w + OFF_WP);
  unsigned short* XB  = (unsigned short*)(w + OFF_XB);
  unsigned short* IRV = (unsigned short*)(w + OFF_IR2);

  k_params<<<1,64,0,stream>>>(tp, mp, Pt, Pm, AT, AM, aLt, aLm);
  k_power<<<32,64,0,stream>>>(AT, 7);   // T^128
  k_power<<<4,64,0,stream>>>(AM, 6);    // T^64

  // ---- track chain: nsig=32, L=128, C=2048 ----
  const int GT = NS_T*C_T/256;   // 256 blocks
  k_eqA12<<<GT,256,0,stream>>>(tracks, Pt, E12, C_T, L_T);
  k_scan12<<<NS_T,64,0,stream>>>(E12, I12, AT, C_T, C_T/64, 5);
  k_eqC12<<<GT,256,0,stream>>>(tracks, Y, Pt, I12, E1, C_T, L_T);
  k_scan1p<<<NS_T,64,0,stream>>>(E1, I1, aLt, C_T, C_T/64, 5);
  k_smoothcomp<<<GT,256,0,stream>>>(Y, Pt, I1, GLt, X, C_T, L_T, LA_T/L_T);
  k_comptail<<<NS_T*(LA_T/4)/256,256,0,stream>>>(Y, GLt, Pt, X, LA_T);
  k_pan<<<2*(SEQ/4)/256,256,0,stream>>>(X, Pt, out, M0, FXb);

  // ---- reverb ----
  k_fir<<<48*32,256,0,stream>>>(noise, fbp, FILT);
  k_ir<<<4*(REV_N/4)/256,256,0,stream>>>(FILT, fxp, IR);
  k_prepx<<<(4*XBL)/256,256,0,stream>>>(FXb, XB);
  k_prepir<<<(4*IRL)/256,256,0,stream>>>(IR, IRV);
  k_wetm<<<1024,256,0,stream>>>(XB, IRV, WPu);
  k_wetred<<<4*(SEQ/4)/256,256,0,stream>>>(WPu, FXb, M0, fxp, M1);

  // ---- master chain: nsig=4, L=64, C=4096 ----
  const int GM = NS_M*C_M/256;   // 64 blocks
  k_eqA12<<<GM,256,0,stream>>>(M1, Pm, E12, C_M, L_M);
  k_scan12<<<NS_M,64,0,stream>>>(E12, I12, AM, C_M, C_M/64, 6);
  k_eqC12<<<GM,256,0,stream>>>(M1, XM, Pm, I12, E1, C_M, L_M);
  k_scan1p<<<NS_M,64,0,stream>>>(E1, I1, aLm, C_M, C_M/64, 6);
  k_smoothcomp<<<GM,256,0,stream>>>(XM, Pm, I1, GLm, out + OUT_MASTER_OFF, C_M, L_M, LA_M/L_M);
  k_comptail<<<NS_M*(LA_M/4)/256,256,0,stream>>>(XM, GLm, Pm, out + OUT_MASTER_OFF, LA_M);
}

// Round 11
// 585.352 us; speedup vs baseline: 9.4871x; 1.1065x over previous
//
#include <hip/hip_runtime.h>

#define DEVFN __device__ __forceinline__

constexpr int SEQ = 262144;
constexpr int REV_N = 65536;
constexpr int TAPS = 1023;
constexpr int NOISE_LEN = REV_N + TAPS - 1;   // 66558

constexpr int NS_T = 32, L_T = 128, C_T = 2048;
constexpr int NS_M = 4,  L_M = 64,  C_M = 4096;
constexpr int LA_T = 2048, LA_M = 1024;

constexpr int OUT_MASTER_OFF = 16777216;

// bf16 wet-conv buffers
constexpr int PADX = 65552;
constexpr int XBL  = 327744;
constexpr int IRL  = 67584;
// bf16 fir buffers
constexpr int PADN = 2016;
constexpr int XNL  = 68640;   // per-sig48 padded noise' length (shorts), even
constexpr int FPAD = 2048;
constexpr int FBL  = 4160;    // per-band reversed fb length (shorts), even

#define C_DB  0.16609640474436813f
#define C_LOG 6.0205999132796239f
#define PI_D  3.14159265358979323846

typedef __attribute__((ext_vector_type(8)))  short short8v;
typedef __attribute__((ext_vector_type(16))) float f32x16;

struct SigP {
  float g_in;
  float cb0[6], cb1[6], cb2[6], ca1[6], ca2[6];
  float alpha, oma;
  float th, invr, knee, makeup;
  float g_out;
  float gl, gr, send;
};

// ---------------- workspace layout (bytes) ----------------
constexpr size_t OFF_X   = 0;                       // 33,554,432
constexpr size_t OFF_Y   = 33554432;                // 33,554,432
constexpr size_t OFF_FX  = 67108864;                // 4 MB
constexpr size_t OFF_M0  = 71303168;                // 4 MB
// overlays (X dead after pan):
constexpr size_t OFF_FILT = OFF_X;                       // 12,582,912
constexpr size_t OFF_IR   = OFF_X + 12582912;            // 1 MB
constexpr size_t OFF_XM   = OFF_X + 16777216;            // 4 MB master y5
constexpr size_t OFF_M1   = OFF_Y;                       // 4 MB master input
constexpr size_t OFF_WP   = OFF_Y + 4194304;             // 16 MB wet partials [37.7M,54.5M)
constexpr size_t OFF_XB   = OFF_WP + 16777216;           // 2.62 MB padded bf16 x
constexpr size_t OFF_IR2  = OFF_XB + (size_t)4*XBL*2;    // 540 KB reversed bf16 ir (ends ~57.76M)
constexpr size_t OFF_XBN  = 58720256;                    // 6.59 MB padded bf16 noise' (ends 65,309,696)
constexpr size_t OFF_FBV  = 65536000;                    // 100 KB reversed bf16 fb (ends 65,635,840)
// E buffers overlay FXb+M0 (free during both chain phases):
constexpr size_t OFF_E12 = OFF_FX;                       // 3,145,728
constexpr size_t OFF_I12 = OFF_FX + 3145728;             // 3,145,728
constexpr size_t OFF_E1  = OFF_FX + 6291456;             // 262,144
constexpr size_t OFF_I1  = OFF_FX + 6553600;             // 262,144
// persistent small region past M0:
constexpr size_t OFF_GL  = 75497472;
constexpr size_t OFF_PT  = OFF_GL + 1024;
constexpr size_t OFF_PM  = OFF_PT + 32*sizeof(SigP);
constexpr size_t OFF_ALT = (OFF_PM + 4*sizeof(SigP) + 7) & ~(size_t)7;
constexpr size_t OFF_ALM = OFF_ALT + 32*8;
constexpr size_t OFF_AT  = (OFF_ALM + 4*8 + 15) & ~(size_t)15;
constexpr size_t OFF_AM  = OFF_AT + 18432;

DEVFN int pq(int i){ return i + ((i >> 5) << 2); }

DEVFN unsigned short f2bf(float f){
  unsigned int u = __float_as_uint(f);
  unsigned int r = (u + 0x7fffu + ((u >> 16) & 1u)) >> 16;
  return (unsigned short)r;
}
DEVFN float bf2f(unsigned short h){ return __uint_as_float(((unsigned int)h) << 16); }

// ---------------- params kernel ----------------
DEVFN double dn(float p, double lo, double hi){ return (double)p*(hi-lo)+lo; }

__device__ void mk_sig(const float* p, int L, bool is_master,
                       SigP* sp, float* Tf, double* aL)
{
  const double flo[6] = {20.,80.,2000.,8000.,12000.,6000.};
  const double fhi[6] = {2000.,2000.,8000.,12000.,21050.,21050.};
  double gdb = dn(p[0], -48., 48.);
  sp->g_in = (float)exp2(gdb * 0.16609640474436813);
  double db0[6],db1[6],db2[6],da1[6],da2[6];
  for (int k=0;k<6;k++){
    double g  = dn(p[1+3*k], -12., 12.);
    double fc = dn(p[2+3*k], flo[k], fhi[k]);
    double q  = dn(p[3+3*k], 0.1, 5.0);
    double A  = pow(10.0, g/40.0);
    double w0 = 2.0*PI_D*(fc/44100.0);
    double al = sin(w0)/(2.0*q), co = cos(w0), sA = sqrt(A);
    double b0,b1,b2,a0,a1,a2;
    if (k==0){
      b0 = A*((A+1.0) - (A-1.0)*co + 2.0*sA*al);
      b1 = 2.0*A*((A-1.0) - (A+1.0)*co);
      b2 = A*((A+1.0) - (A-1.0)*co - 2.0*sA*al);
      a0 = (A+1.0) + (A-1.0)*co + 2.0*sA*al;
      a1 = -2.0*((A-1.0) + (A+1.0)*co);
      a2 = (A+1.0) + (A-1.0)*co - 2.0*sA*al;
    } else if (k==5){
      b0 = A*((A+1.0) + (A-1.0)*co + 2.0*sA*al);
      b1 = -2.0*A*((A-1.0) + (A+1.0)*co);
      b2 = A*((A+1.0) + (A-1.0)*co - 2.0*sA*al);
      a0 = (A+1.0) - (A-1.0)*co + 2.0*sA*al;
      a1 = 2.0*((A-1.0) - (A+1.0)*co);
      a2 = (A+1.0) - (A-1.0)*co - 2.0*sA*al;
    } else {
      b0 = 1.0 + al*A; b1 = -2.0*co; b2 = 1.0 - al*A;
      a0 = 1.0 + al/A; a1 = -2.0*co; a2 = 1.0 - al/A;
    }
    double ia0 = 1.0/a0;
    db0[k]=b0*ia0; db1[k]=b1*ia0; db2[k]=b2*ia0; da1[k]=a1*ia0; da2[k]=a2*ia0;
    sp->cb0[k]=(float)db0[k]; sp->cb1[k]=(float)db1[k]; sp->cb2[k]=(float)db2[k];
    sp->ca1[k]=(float)da1[k]; sp->ca2[k]=(float)da2[k];
  }
  for (int i=0;i<12;i++){
    double st[12]; for (int r=0;r<12;r++) st[r]=0.0; st[i]=1.0;
    double ns[12];
    double yprev=0.0, pm1=0.0, pm2=0.0;
    for (int k=0;k<6;k++){
      double yk = db0[k]*yprev + db1[k]*pm1 + db2[k]*pm2 - da1[k]*st[2*k] - da2[k]*st[2*k+1];
      ns[2*k]=yk; ns[2*k+1]=st[2*k];
      pm1=st[2*k]; pm2=st[2*k+1];
      yprev=yk;
    }
    for (int r=0;r<12;r++) Tf[r*12+i]=(float)ns[r];
  }
  double th    = dn(p[19], -60., 0.);
  double ratio = dn(p[20], 1., 10.);
  double at    = dn(p[21], 5., 250.);
  double knee  = dn(p[23], 3., 12.);
  double mkup  = dn(p[24], 0., 6.);
  double alpha = exp(-log(9.0)/(44100.0*at*0.001));
  sp->alpha=(float)alpha; sp->oma=(float)(1.0-alpha);
  sp->th=(float)th; sp->invr=(float)(1.0/ratio); sp->knee=(float)knee; sp->makeup=(float)mkup;
  *aL = pow(alpha, (double)L);
  if (is_master){
    sp->g_out = (float)exp2(dn(p[25],-48.,48.)*0.16609640474436813);
    sp->gl=0.f; sp->gr=0.f; sp->send=0.f;
  } else {
    sp->g_out = 1.f;
    sp->send = (float)exp2(dn(p[25],-80.,12.)*0.16609640474436813);
    double th2 = dn(p[26],0.,1.)*(PI_D/2.0);
    sp->gl = (float)sqrt((PI_D/2.0-th2)*(2.0/PI_D)*cos(th2));
    sp->gr = (float)sqrt(th2*(2.0/PI_D)*sin(th2));
  }
}

__global__ __launch_bounds__(64) void k_params(const float* __restrict__ tp, const float* __restrict__ mp,
    SigP* Pt, SigP* Pm, float* AT, float* AM, double* aLt, double* aLm)
{
  int i = threadIdx.x;
  if (i < 32)       mk_sig(tp + i*27, L_T, false, &Pt[i], AT + i*144, &aLt[i]);
  else if (i < 36){ int j=i-32; mk_sig(mp + (j>>1)*26, L_M, true, &Pm[j], AM + j*144, &aLm[j]); }
}

__global__ __launch_bounds__(64) void k_power(float* __restrict__ Ab, int lg)
{
  __shared__ float Ma[144], Mb[144];
  int sig = blockIdx.x, t = threadIdx.x;
  float* A = Ab + (size_t)sig*144;
  for (int idx=t; idx<144; idx+=64) Ma[idx]=A[idx];
  __syncthreads();
  int cur=0;
  for (int j=0;j<lg;j++){
    const float* src = cur? Mb:Ma;
    float* dst = cur? Ma:Mb;
    for (int idx=t; idx<144; idx+=64){
      int r=idx/12, cc=idx-r*12;
      float v=0.f;
      #pragma unroll
      for (int m=0;m<12;m++) v = fmaf(src[r*12+m], src[m*12+cc], v);
      dst[idx]=v;
    }
    __syncthreads();
    cur^=1;
  }
  const float* fin = cur? Mb:Ma;
  for (int idx=t; idx<144; idx+=64) A[idx]=fin[idx];
}

DEVFN float comp_gc(float y, float th, float invr, float kn){
  float av  = fmaxf(fabsf(y), 1e-8f);
  float xdb = C_LOG * __builtin_log2f(av);
  float d   = xdb - th;
  float w = (2.f*d < -kn) ? 0.f
          : ((2.f*fabsf(d) <= kn) ? (d+0.5f*kn)*(d+0.5f*kn)/(2.f*kn) : d);
  return (invr-1.f)*w;
}

// ---------------- A-pass ----------------
__global__ __launch_bounds__(256) void k_eqA12(const float* __restrict__ in, const SigP* __restrict__ P,
    float* __restrict__ E12, int C, int L)
{
  int tid = blockIdx.x*256 + threadIdx.x;
  int sig = tid / C, c = tid - sig*C;
  const SigP* sp = P + sig;
  float B0[6],B1[6],B2[6],A1[6],A2[6];
  float g = sp->g_in;
  #pragma unroll
  for (int k=0;k<6;k++){
    float gg = (k==0)? g : 1.f;
    B0[k]=sp->cb0[k]*gg; B1[k]=sp->cb1[k]*gg; B2[k]=sp->cb2[k]*gg;
    A1[k]=sp->ca1[k];    A2[k]=sp->ca2[k];
  }
  const float* xp = in + (size_t)sig*SEQ + (size_t)c*L;
  float xm1=0.f, xm2=0.f;
  if (c){ xm1=xp[-1]; xm2=xp[-2]; }
  float s[12];
  #pragma unroll
  for (int r=0;r<12;r++) s[r]=0.f;
  for (int i=0;i<L;i+=4){
    float4 v = *(const float4*)(xp+i);
    #pragma unroll
    for (int u4=0;u4<4;u4++){
      float u = (u4==0)?v.x:(u4==1)?v.y:(u4==2)?v.z:v.w;
      float yprev=u, pm1=xm1, pm2=xm2;
      float ny[6];
      #pragma unroll
      for (int k=0;k<6;k++){
        float t0 = fmaf(B0[k],yprev, fmaf(B1[k],pm1, fmaf(B2[k],pm2, -A2[k]*s[2*k+1])));
        float yk = fmaf(-A1[k], s[2*k], t0);
        ny[k]=yk;
        pm1=s[2*k]; pm2=s[2*k+1];
        yprev=yk;
      }
      #pragma unroll
      for (int k=0;k<6;k++){ s[2*k+1]=s[2*k]; s[2*k]=ny[k]; }
      xm2=xm1; xm1=u;
    }
  }
  float* ep = E12 + (size_t)tid*12;
  #pragma unroll
  for (int r=0;r<12;r++) ep[r]=s[r];
}

// ---------------- 12-state affine scan ----------------
__global__ __launch_bounds__(64) void k_scan12(const float* __restrict__ E, float* __restrict__ I,
    const float* __restrict__ Ab, int C, int Q, int lgQ)
{
  __shared__ float As[144], Pa[144], Pb[144];
  __shared__ float seg[64][12], ini[64][12];
  __shared__ float scur[12], stmp[12];
  int sig = blockIdx.x, t = threadIdx.x;
  const float* Asig = Ab + (size_t)sig*144;
  for (int idx=t; idx<144; idx+=64) As[idx]=Asig[idx];
  __syncthreads();
  const float* dp = E + ((size_t)sig*C + (size_t)t*Q)*12;
  float s[12];
  #pragma unroll
  for (int r=0;r<12;r++) s[r]=0.f;
  for (int j=0;j<Q;j++){
    const float* d = dp + j*12;
    float ns[12];
    #pragma unroll
    for (int r=0;r<12;r++){
      float v = d[r];
      #pragma unroll
      for (int cc=0;cc<12;cc++) v = fmaf(As[r*12+cc], s[cc], v);
      ns[r]=v;
    }
    #pragma unroll
    for (int r=0;r<12;r++) s[r]=ns[r];
  }
  #pragma unroll
  for (int r=0;r<12;r++) seg[t][r]=s[r];
  for (int idx=t; idx<144; idx+=64) Pa[idx]=As[idx];
  __syncthreads();
  int cur=0;
  for (int j=0;j<lgQ;j++){
    const float* src = cur? Pb:Pa;
    float* dst = cur? Pa:Pb;
    for (int idx=t; idx<144; idx+=64){
      int r=idx/12, cc=idx-r*12;
      float v=0.f;
      #pragma unroll
      for (int m=0;m<12;m++) v = fmaf(src[r*12+m], src[m*12+cc], v);
      dst[idx]=v;
    }
    __syncthreads();
    cur^=1;
  }
  const float* AQ = cur? Pb:Pa;
  if (t<12) scur[t]=0.f;
  __syncthreads();
  for (int u=0;u<64;u++){
    if (t<12){
      ini[u][t]=scur[t];
      float v = seg[u][t];
      #pragma unroll
      for (int cc=0;cc<12;cc++) v = fmaf(AQ[t*12+cc], scur[cc], v);
      stmp[t]=v;
    }
    __syncthreads();
    if (t<12) scur[t]=stmp[t];
    __syncthreads();
  }
  #pragma unroll
  for (int r=0;r<12;r++) s[r]=ini[t][r];
  float* op = I + ((size_t)sig*C + (size_t)t*Q)*12;
  for (int j=0;j<Q;j++){
    float* o = op + j*12;
    #pragma unroll
    for (int r=0;r<12;r++) o[r]=s[r];
    const float* d = dp + j*12;
    float ns[12];
    #pragma unroll
    for (int r=0;r<12;r++){
      float v = d[r];
      #pragma unroll
      for (int cc=0;cc<12;cc++) v = fmaf(As[r*12+cc], s[cc], v);
      ns[r]=v;
    }
    #pragma unroll
    for (int r=0;r<12;r++) s[r]=ns[r];
  }
}

// ---------------- 1-state scan ----------------
__global__ __launch_bounds__(64) void k_scan1p(const float* __restrict__ endst, float* __restrict__ inits,
    const double* __restrict__ aL, int C, int Q, int lgQ)
{
  __shared__ double ag[64], ins[64];
  int sig = blockIdx.x; int t = threadIdx.x;
  double a = aL[sig];
  const float* dp = endst + (size_t)sig*C + (size_t)t*Q;
  double e=0.0;
  for (int j=0;j<Q;j++) e = a*e + (double)dp[j];
  ag[t]=e;
  __syncthreads();
  if (t == 0){
    double p=a;
    for (int j=0;j<lgQ;j++) p = p*p;
    double s=0.0;
    for (int u=0;u<64;u++){
      ins[u]=s;
      s = p*s + ag[u];
    }
  }
  __syncthreads();
  double s = ins[t];
  float* op = inits + (size_t)sig*C + (size_t)t*Q;
  for (int j=0;j<Q;j++){ op[j]=(float)s; s = a*s + (double)dp[j]; }
}

// ---------------- C-pass ----------------
__global__ __launch_bounds__(256) void k_eqC12(const float* __restrict__ in, float* __restrict__ yout,
    const SigP* __restrict__ P, const float* __restrict__ I12, float* __restrict__ E1, int C, int L)
{
  int tid = blockIdx.x*256 + threadIdx.x;
  int sig = tid / C, c = tid - sig*C;
  const SigP* sp = P + sig;
  float B0[6],B1[6],B2[6],A1[6],A2[6];
  float g = sp->g_in;
  #pragma unroll
  for (int k=0;k<6;k++){
    float gg = (k==0)? g : 1.f;
    B0[k]=sp->cb0[k]*gg; B1[k]=sp->cb1[k]*gg; B2[k]=sp->cb2[k]*gg;
    A1[k]=sp->ca1[k];    A2[k]=sp->ca2[k];
  }
  float al=sp->alpha, oma=sp->oma, th=sp->th, invr=sp->invr, kn=sp->knee;
  size_t base = (size_t)sig*SEQ + (size_t)c*L;
  const float* xp = in + base;
  float* op = yout + base;
  float xm1=0.f, xm2=0.f;
  if (c){ xm1=xp[-1]; xm2=xp[-2]; }
  const float* ip = I12 + (size_t)tid*12;
  float s[12];
  #pragma unroll
  for (int r=0;r<12;r++) s[r]=ip[r];
  float gacc=0.f;
  for (int i=0;i<L;i+=4){
    float4 v = *(const float4*)(xp+i);
    float4 o;
    #pragma unroll
    for (int u4=0;u4<4;u4++){
      float u = (u4==0)?v.x:(u4==1)?v.y:(u4==2)?v.z:v.w;
      float yprev=u, pm1=xm1, pm2=xm2;
      float ny[6];
      #pragma unroll
      for (int k=0;k<6;k++){
        float t0 = fmaf(B0[k],yprev, fmaf(B1[k],pm1, fmaf(B2[k],pm2, -A2[k]*s[2*k+1])));
        float yk = fmaf(-A1[k], s[2*k], t0);
        ny[k]=yk;
        pm1=s[2*k]; pm2=s[2*k+1];
        yprev=yk;
      }
      #pragma unroll
      for (int k=0;k<6;k++){ s[2*k+1]=s[2*k]; s[2*k]=ny[k]; }
      xm2=xm1; xm1=u;
      float y5 = ny[5];
      if (u4==0) o.x=y5; else if (u4==1) o.y=y5; else if (u4==2) o.z=y5; else o.w=y5;
      gacc = fmaf(al, gacc, oma*comp_gc(y5,th,invr,kn));
    }
    *(float4*)(op+i) = o;
  }
  E1[tid]=gacc;
}

// ---------------- fused smoother + compressor apply ----------------
__global__ __launch_bounds__(256) void k_smoothcomp(const float* __restrict__ yin,
    const SigP* __restrict__ P, const float* __restrict__ inits1, float* __restrict__ gslast,
    float* __restrict__ outp, int C, int L, int lac)
{
  int tid = blockIdx.x*256 + threadIdx.x;
  int sig = tid / C, c = tid - sig*C;
  const SigP* sp = P + sig;
  float al=sp->alpha, oma=sp->oma, th=sp->th, invr=sp->invr, kn=sp->knee;
  float mk=sp->makeup, go=sp->g_out;
  size_t base = (size_t)sig*SEQ + (size_t)c*L;
  const float* xp = yin + base;
  bool wr = (c >= lac);
  size_t ob = wr ? (base - (size_t)lac*L) : 0;
  const float* yp = yin + ob;
  float* op = outp + ob;
  float gsv = inits1[tid];
  for (int i=0;i<L;i+=4){
    float4 v = *(const float4*)(xp+i);
    float4 gf;
    gsv = fmaf(al, gsv, oma*comp_gc(v.x,th,invr,kn)); gf.x=gsv;
    gsv = fmaf(al, gsv, oma*comp_gc(v.y,th,invr,kn)); gf.y=gsv;
    gsv = fmaf(al, gsv, oma*comp_gc(v.z,th,invr,kn)); gf.z=gsv;
    gsv = fmaf(al, gsv, oma*comp_gc(v.w,th,invr,kn)); gf.w=gsv;
    if (wr){
      float4 y2 = *(const float4*)(yp+i);
      float4 o;
      o.x = y2.x * __builtin_exp2f((gf.x+mk)*C_DB) * go;
      o.y = y2.y * __builtin_exp2f((gf.y+mk)*C_DB) * go;
      o.z = y2.z * __builtin_exp2f((gf.z+mk)*C_DB) * go;
      o.w = y2.w * __builtin_exp2f((gf.w+mk)*C_DB) * go;
      *(float4*)(op+i) = o;
    }
  }
  if (c == C-1) gslast[sig] = gsv;
}

__global__ __launch_bounds__(256) void k_comptail(const float* __restrict__ yin, const float* __restrict__ gslast,
    const SigP* __restrict__ P, float* __restrict__ outp, int la)
{
  int q = blockIdx.x*256 + threadIdx.x;
  int per = la/4;
  int sig = q / per;
  int r = (q - sig*per)*4;
  int n = SEQ - la + r;
  const SigP* sp = P + sig;
  float f = __builtin_exp2f((gslast[sig]+sp->makeup)*C_DB) * sp->g_out;
  size_t base = (size_t)sig*SEQ + n;
  float4 v = *(const float4*)(yin+base);
  float4 o = { v.x*f, v.y*f, v.z*f, v.w*f };
  *(float4*)(outp+base) = o;
}

// ---------------- pan + master/fx sums ----------------
__global__ __launch_bounds__(256) void k_pan(const float* __restrict__ y, const SigP* __restrict__ P,
    float* __restrict__ panned, float* __restrict__ m0, float* __restrict__ fx)
{
  int q = blockIdx.x*256 + threadIdx.x;
  int b = q / (SEQ/4);
  int n = (q - b*(SEQ/4))*4;
  float4 aL={0,0,0,0}, aR={0,0,0,0}, fL={0,0,0,0}, fR={0,0,0,0};
  for (int t=0;t<16;t++){
    const SigP* sp = P + b*16 + t;
    float gl=sp->gl, gr=sp->gr, sd=sp->send;
    float4 v = *(const float4*)(y + (size_t)(b*16+t)*SEQ + n);
    float4 pl = { v.x*gl, v.y*gl, v.z*gl, v.w*gl };
    float4 pr = { v.x*gr, v.y*gr, v.z*gr, v.w*gr };
    *(float4*)(panned + (size_t)(b*32+t)*SEQ + n)    = pl;
    *(float4*)(panned + (size_t)(b*32+16+t)*SEQ + n) = pr;
    aL.x+=pl.x; aL.y+=pl.y; aL.z+=pl.z; aL.w+=pl.w;
    aR.x+=pr.x; aR.y+=pr.y; aR.z+=pr.z; aR.w+=pr.w;
    fL.x=fmaf(pl.x,sd,fL.x); fL.y=fmaf(pl.y,sd,fL.y); fL.z=fmaf(pl.z,sd,fL.z); fL.w=fmaf(pl.w,sd,fL.w);
    fR.x=fmaf(pr.x,sd,fR.x); fR.y=fmaf(pr.y,sd,fR.y); fR.z=fmaf(pr.z,sd,fR.z); fR.w=fmaf(pr.w,sd,fR.w);
  }
  *(float4*)(m0 + (size_t)(b*2+0)*SEQ + n) = aL;
  *(float4*)(m0 + (size_t)(b*2+1)*SEQ + n) = aR;
  *(float4*)(fx + (size_t)(b*2+0)*SEQ + n) = fL;
  *(float4*)(fx + (size_t)(b*2+1)*SEQ + n) = fR;
}

// ---------------- ir = mean over bands of filt*env*gain ----------------
__global__ __launch_bounds__(256) void k_ir(const float* __restrict__ filt, const float* __restrict__ fxp,
    float* __restrict__ ir)
{
  int q = blockIdx.x*256 + threadIdx.x;
  int sig = q / (REV_N/4);
  int i   = (q - sig*(REV_N/4))*4;
  int b = sig >> 1;
  float4 acc={0,0,0,0};
  const float ts = 1.0f/65535.0f;
  for (int band=0; band<12; band++){
    float gn  = fxp[b*25 + band];
    float dec = fxp[b*25 + 12 + band]*10.f + 1.f;
    float4 f = *(const float4*)(filt + ((size_t)(sig*12+band))*REV_N + i);
    float s = -dec*ts;
    float e0=expf(s*(float)i), e1=expf(s*(float)(i+1)), e2=expf(s*(float)(i+2)), e3=expf(s*(float)(i+3));
    acc.x = fmaf(gn*e0, f.x, acc.x);
    acc.y = fmaf(gn*e1, f.y, acc.y);
    acc.z = fmaf(gn*e2, f.z, acc.z);
    acc.w = fmaf(gn*e3, f.w, acc.w);
  }
  const float inv12 = 1.f/12.f;
  acc.x*=inv12; acc.y*=inv12; acc.z*=inv12; acc.w*=inv12;
  *(float4*)(ir + (size_t)sig*REV_N + i) = acc;
}

// ---------------- bf16 prep ----------------
__global__ __launch_bounds__(256) void k_prepx(const float* __restrict__ fx, unsigned short* __restrict__ XB)
{
  int q = blockIdx.x*256 + threadIdx.x;
  int sig = q / XBL;
  int m   = q - sig*XBL;
  int a = m - PADX;
  float v = (a >= 0 && a < SEQ) ? fx[(size_t)sig*SEQ + a] : 0.f;
  XB[(size_t)sig*XBL + m] = f2bf(v);
}
__global__ __launch_bounds__(256) void k_prepir(const float* __restrict__ ir, unsigned short* __restrict__ IRV)
{
  int q = blockIdx.x*256 + threadIdx.x;
  int sig = q / IRL;
  int m   = q - sig*IRL;
  int a = m - 1024;
  float v = (a >= 0 && a < REV_N) ? ir[(size_t)sig*REV_N + (REV_N-1 - a)] : 0.f;
  IRV[(size_t)sig*IRL + m] = f2bf(v);
}
__global__ __launch_bounds__(256) void k_prepn(const float* __restrict__ noise, unsigned short* __restrict__ XBN)
{
  int q = blockIdx.x*256 + threadIdx.x;
  int sig = q / XNL;
  if (sig >= 48) return;
  int m   = q - sig*XNL;
  int a = m - PADN + 1022;       // noise' index -> noise index
  float v = (a >= 0 && a < NOISE_LEN) ? noise[(size_t)sig*NOISE_LEN + a] : 0.f;
  XBN[(size_t)sig*XNL + m] = f2bf(v);
}
__global__ __launch_bounds__(256) void k_prepfb(const float* __restrict__ fb, unsigned short* __restrict__ FBV)
{
  int q = blockIdx.x*256 + threadIdx.x;
  int band = q / FBL;
  if (band >= 12) return;
  int m = q - band*FBL;
  int a = m - FPAD;
  float v = (a >= 0 && a < TAPS) ? fb[band*TAPS + (TAPS-1 - a)] : 0.f;
  FBV[(size_t)band*FBL + m] = f2bf(v);
}

// ---------------- band FIR via MFMA: filt = corr(noise, fb) ----------------
// out[n] = sum_m fb[m] noise'[n-m], noise'[j]=noise[j+1022]; K taps = 1023.
// ALIGNMENT: maxtap=1022 === 6 (mod 8) => irlo === 6 (mod 8) so Dh0 === 0 (mod 8).
__global__ __launch_bounds__(256,3) void k_firm(const unsigned short* __restrict__ XBN,
    const unsigned short* __restrict__ FBV, float* __restrict__ filt)
{
  __shared__ alignas(16) unsigned int xs0[4640];
  __shared__ alignas(16) unsigned int xs1[4640];
  __shared__ alignas(16) unsigned short sir[3456];
  int b = blockIdx.x;                 // 384 = 8 ngrp * 48 sig
  int ng  = b & 7;
  int sig = b >> 3;
  int band = sig % 12;
  int nblk = ng << 13;                // 8192 outputs per block
  const int sbeg = -62;
  const int send = 126;

  int tid = threadIdx.x;
  int l  = tid & 63, wv = tid >> 6;
  int lj = l & 31, lg = l >> 5, ph = l & 1;
  int hl = (lj + 8*lg - ph) >> 1;
  int offB = 32*lj - 8*lg;
  const unsigned int* xbu = (const unsigned int*)(XBN + (size_t)sig*XNL);
  const unsigned short* irg = FBV + (size_t)band*FBL;
  const unsigned int* xsel = ph ? (const unsigned int*)xs1 : (const unsigned int*)xs0;

  f32x16 acc0 = {};
  f32x16 acc1 = {};
  int n0_0 = nblk + (wv*2+0)*1024;
  int n0_1 = nblk + (wv*2+1)*1024;

  for (int sa = sbeg; sa < send; sa += 128){
    int ns = send - sa; if (ns > 128) ns = 128;
    __syncthreads();
    int clo = nblk - 16*(sa + ns - 1);
    int ub  = (PADN + clo) >> 1;
    int nd  = ((nblk + 7168 + 46 - 16*sa) - clo)/2 + 2;
    for (int d = tid; d < nd; d += 256){
      unsigned int u0 = xbu[ub + d], u1 = xbu[ub + d + 1];
      xs0[d] = u0;
      xs1[d] = (u0 >> 16) | (u1 << 16);
    }
    int amin = 1022 - 16*(sa + ns - 1) - 992;
    int irlo = ((amin - 6) & ~7) + 6;                  // <= amin, === 6 mod 8
    int irspan = (1022 - 16*sa + 15) - irlo + 1;
    for (int r = tid; r < irspan; r += 256){
      sir[r + ((r>>6)<<3)] = irg[FPAD + irlo + r];
    }
    __syncthreads();
    int db0 = ((n0_0 - clo) >> 1) - 8*sa + hl;
    int db1 = ((n0_1 - clo) >> 1) - 8*sa + hl;
    int Dh0 = 1022 - 16*sa - irlo;
    for (int ss = 0; ss < ns; ss++){
      int rB = (Dh0 - 16*ss) - offB;
      short8v bfrag = *(const short8v*)(sir + rB + ((rB>>6)<<3));
      union { unsigned int u[4]; short8v v; } a0, a1;
      int d0 = db0 - 8*ss, d1 = db1 - 8*ss;
      a0.u[0]=xsel[d0];   a0.u[1]=xsel[d0+1]; a0.u[2]=xsel[d0+2]; a0.u[3]=xsel[d0+3];
      a1.u[0]=xsel[d1];   a1.u[1]=xsel[d1+1]; a1.u[2]=xsel[d1+2]; a1.u[3]=xsel[d1+3];
      acc0 = __builtin_amdgcn_mfma_f32_32x32x16_bf16(a0.v, bfrag, acc0, 0, 0, 0);
      acc1 = __builtin_amdgcn_mfma_f32_32x32x16_bf16(a1.v, bfrag, acc1, 0, 0, 0);
    }
  }
  float* fp = filt + (size_t)sig*REV_N;
  #pragma unroll
  for (int reg = 0; reg < 16; reg++){
    int i = (reg & 3) + 8*(reg >> 2) + 4*lg;
    fp[n0_0 + i + 32*lj] = acc0[reg];
    fp[n0_1 + i + 32*lj] = acc1[reg];
  }
}

// ---------------- wet conv via MFMA ----------------
__global__ __launch_bounds__(256,3) void k_wetm(const unsigned short* __restrict__ XB,
    const unsigned short* __restrict__ IRV, unsigned short* __restrict__ WP)
{
  __shared__ alignas(16) unsigned int xs0[4640];
  __shared__ alignas(16) unsigned int xs1[4640];
  __shared__ alignas(16) unsigned short sir[3456];
  int b = blockIdx.x;
  int ng  = b & 31;
  int sig = (b >> 5) & 3;
  int kp  = b >> 7;
  int nblk = ng << 13;
  int sbeg = -62 + 520*kp;
  int send = sbeg + 520; if (send > 4097) send = 4097;

  int tid = threadIdx.x;
  int l  = tid & 63, wv = tid >> 6;
  int lj = l & 31, lg = l >> 5, ph = l & 1;
  int hl = (lj + 8*lg - ph) >> 1;
  int offB = 32*lj - 8*lg;
  const unsigned int* xbu = (const unsigned int*)(XB + (size_t)sig*XBL);
  const unsigned short* irg = IRV + (size_t)sig*IRL;
  const unsigned int* xsel = ph ? (const unsigned int*)xs1 : (const unsigned int*)xs0;

  f32x16 acc0 = {};
  f32x16 acc1 = {};
  int n0_0 = nblk + (wv*2+0)*1024;
  int n0_1 = nblk + (wv*2+1)*1024;

  for (int sa = sbeg; sa < send; sa += 128){
    int ns = send - sa; if (ns > 128) ns = 128;
    __syncthreads();
    int clo = nblk - 16*(sa + ns - 1);
    int ub  = (PADX + clo) >> 1;
    int nd  = ((nblk + 7168 + 46 - 16*sa) - clo)/2 + 2;
    for (int d = tid; d < nd; d += 256){
      unsigned int u0 = xbu[ub + d], u1 = xbu[ub + d + 1];
      xs0[d] = u0;
      xs1[d] = (u0 >> 16) | (u1 << 16);
    }
    int amin = 65535 - 16*(sa + ns - 1) - 992;
    int irlo = ((amin - 7) & ~7) + 7;                  // 65535 === 7 mod 8
    int irspan = (65535 - 16*sa + 15) - irlo + 1;
    for (int r = tid; r < irspan; r += 256){
      sir[r + ((r>>6)<<3)] = irg[1024 + irlo + r];
    }
    __syncthreads();
    int db0 = ((n0_0 - clo) >> 1) - 8*sa + hl;
    int db1 = ((n0_1 - clo) >> 1) - 8*sa + hl;
    int Dh0 = 65535 - 16*sa - irlo;
    for (int ss = 0; ss < ns; ss++){
      int rB = (Dh0 - 16*ss) - offB;
      short8v bfrag = *(const short8v*)(sir + rB + ((rB>>6)<<3));
      union { unsigned int u[4]; short8v v; } a0, a1;
      int d0 = db0 - 8*ss, d1 = db1 - 8*ss;
      a0.u[0]=xsel[d0];   a0.u[1]=xsel[d0+1]; a0.u[2]=xsel[d0+2]; a0.u[3]=xsel[d0+3];
      a1.u[0]=xsel[d1];   a1.u[1]=xsel[d1+1]; a1.u[2]=xsel[d1+2]; a1.u[3]=xsel[d1+3];
      acc0 = __builtin_amdgcn_mfma_f32_32x32x16_bf16(a0.v, bfrag, acc0, 0, 0, 0);
      acc1 = __builtin_amdgcn_mfma_f32_32x32x16_bf16(a1.v, bfrag, acc1, 0, 0, 0);
    }
  }
  unsigned short* wp = WP + ((size_t)(kp*4+sig))*SEQ;
  #pragma unroll
  for (int reg = 0; reg < 16; reg++){
    int i = (reg & 3) + 8*(reg >> 2) + 4*lg;
    wp[n0_0 + i + 32*lj] = f2bf(acc0[reg]);
    wp[n0_1 + i + 32*lj] = f2bf(acc1[reg]);
  }
}

// ---------------- reduce partials + mix + add to master ----------------
__global__ __launch_bounds__(256) void k_wetred(const unsigned short* __restrict__ wp, const float* __restrict__ fx,
    const float* __restrict__ m0, const float* __restrict__ fxp, float* __restrict__ m1)
{
  int q = blockIdx.x*256 + threadIdx.x;
  int sig = q / (SEQ/4);
  int n = (q - sig*(SEQ/4))*4;
  float mix = fxp[(sig>>1)*25+24];
  size_t ob = (size_t)sig*SEQ + n;
  float s0=0.f, s1=0.f, s2=0.f, s3=0.f;
  #pragma unroll
  for (int kp=0; kp<8; kp++){
    const unsigned short* p = wp + ((size_t)(kp*4+sig))*SEQ + n;
    s0 += bf2f(p[0]); s1 += bf2f(p[1]); s2 += bf2f(p[2]); s3 += bf2f(p[3]);
  }
  float4 w0 = *(const float4*)(m0+ob);
  float4 x0 = *(const float4*)(fx+ob);
  float om = 1.f - mix;
  float4 o;
  o.x = w0.x + om*x0.x + mix*s0;
  o.y = w0.y + om*x0.y + mix*s1;
  o.z = w0.z + om*x0.z + mix*s2;
  o.w = w0.w + om*x0.w + mix*s3;
  *(float4*)(m1+ob) = o;
}

// ---------------- launch ----------------
extern "C" void kernel_launch(void* const* d_in, const int* in_sizes, int n_in,
                              void* d_out, int out_size, void* d_ws, size_t ws_size,
                              hipStream_t stream)
{
  const float* tracks = (const float*)d_in[0];
  const float* tp     = (const float*)d_in[1];
  const float* fxp    = (const float*)d_in[2];
  const float* mp     = (const float*)d_in[3];
  const float* noise  = (const float*)d_in[4];
  const float* fbp    = (const float*)d_in[5];
  float* out = (float*)d_out;
  char* w = (char*)d_ws;

  float*  X   = (float*)(w + OFF_X);
  float*  Y   = (float*)(w + OFF_Y);
  float*  FXb = (float*)(w + OFF_FX);
  float*  M0  = (float*)(w + OFF_M0);
  float*  E12 = (float*)(w + OFF_E12);
  float*  I12 = (float*)(w + OFF_I12);
  float*  E1  = (float*)(w + OFF_E1);
  float*  I1  = (float*)(w + OFF_I1);
  float*  GLt = (float*)(w + OFF_GL);
  float*  GLm = GLt + 32;
  SigP*   Pt  = (SigP*)(w + OFF_PT);
  SigP*   Pm  = (SigP*)(w + OFF_PM);
  double* aLt = (double*)(w + OFF_ALT);
  double* aLm = (double*)(w + OFF_ALM);
  float*  AT  = (float*)(w + OFF_AT);
  float*  AM  = (float*)(w + OFF_AM);
  float*  FILT= (float*)(w + OFF_FILT);
  float*  IR  = (float*)(w + OFF_IR);
  float*  XM  = (float*)(w + OFF_XM);
  float*  M1  = (float*)(w + OFF_M1);
  unsigned short* WPu = (unsigned short*)(w + OFF_WP);
  unsigned short* XB  = (unsigned short*)(w + OFF_XB);
  unsigned short* IRV = (unsigned short*)(w + OFF_IR2);
  unsigned short* XBN = (unsigned short*)(w + OFF_XBN);
  unsigned short* FBV = (unsigned short*)(w + OFF_FBV);

  k_params<<<1,64,0,stream>>>(tp, mp, Pt, Pm, AT, AM, aLt, aLm);
  k_power<<<32,64,0,stream>>>(AT, 7);   // T^128
  k_power<<<4,64,0,stream>>>(AM, 6);    // T^64

  // ---- track chain ----
  const int GT = NS_T*C_T/256;
  k_eqA12<<<GT,256,0,stream>>>(tracks, Pt, E12, C_T, L_T);
  k_scan12<<<NS_T,64,0,stream>>>(E12, I12, AT, C_T, C_T/64, 5);
  k_eqC12<<<GT,256,0,stream>>>(tracks, Y, Pt, I12, E1, C_T, L_T);
  k_scan1p<<<NS_T,64,0,stream>>>(E1, I1, aLt, C_T, C_T/64, 5);
  k_smoothcomp<<<GT,256,0,stream>>>(Y, Pt, I1, GLt, X, C_T, L_T, LA_T/L_T);
  k_comptail<<<NS_T*(LA_T/4)/256,256,0,stream>>>(Y, GLt, Pt, X, LA_T);
  k_pan<<<2*(SEQ/4)/256,256,0,stream>>>(X, Pt, out, M0, FXb);

  // ---- reverb ----
  k_prepn<<<(48*XNL+255)/256,256,0,stream>>>(noise, XBN);
  k_prepfb<<<(12*FBL+255)/256,256,0,stream>>>(fbp, FBV);
  k_firm<<<384,256,0,stream>>>(XBN, FBV, FILT);
  k_ir<<<4*(REV_N/4)/256,256,0,stream>>>(FILT, fxp, IR);
  k_prepx<<<(4*XBL)/256,256,0,stream>>>(FXb, XB);
  k_prepir<<<(4*IRL)/256,256,0,stream>>>(IR, IRV);
  k_wetm<<<1024,256,0,stream>>>(XB, IRV, WPu);
  k_wetred<<<4*(SEQ/4)/256,256,0,stream>>>(WPu, FXb, M0, fxp, M1);

  // ---- master chain ----
  const int GM = NS_M*C_M/256;
  k_eqA12<<<GM,256,0,stream>>>(M1, Pm, E12, C_M, L_M);
  k_scan12<<<NS_M,64,0,stream>>>(E12, I12, AM, C_M, C_M/64, 6);
  k_eqC12<<<GM,256,0,stream>>>(M1, XM, Pm, I12, E1, C_M, L_M);
  k_scan1p<<<NS_M,64,0,stream>>>(E1, I1, aLm, C_M, C_M/64, 6);
  k_smoothcomp<<<GM,256,0,stream>>>(XM, Pm, I1, GLm, out + OUT_MASTER_OFF, C_M, L_M, LA_M/L_M);
  k_comptail<<<NS_M*(LA_M/4)/256,256,0,stream>>>(XM, GLm, Pm, out + OUT_MASTER_OFF, LA_M);
}

// Round 12
// 522.540 us; speedup vs baseline: 10.6275x; 1.1202x over previous
//
#include <hip/hip_runtime.h>

#define DEVFN __device__ __forceinline__

constexpr int SEQ = 262144;
constexpr int REV_N = 65536;
constexpr int TAPS = 1023;
constexpr int NOISE_LEN = REV_N + TAPS - 1;   // 66558

constexpr int NS_T = 32, L_T = 128, C_T = 2048;
constexpr int NS_M = 4,  L_M = 64,  C_M = 4096;
constexpr int LA_T = 2048, LA_M = 1024;

constexpr int OUT_MASTER_OFF = 16777216;

// bf16 wet-conv buffers
constexpr int PADX = 65552;
constexpr int XBL  = 327744;
constexpr int IRPAD = 4096;
constexpr int IRL  = 73728;   // 4096 front pad + 65536 + tail
// bf16 fir buffers
constexpr int PADN = 2016;
constexpr int XNL  = 68640;
constexpr int FPAD = 2048;
constexpr int FBL  = 4160;

#define C_DB  0.16609640474436813f
#define C_LOG 6.0205999132796239f
#define PI_D  3.14159265358979323846

typedef __attribute__((ext_vector_type(8)))  short short8v;
typedef __attribute__((ext_vector_type(16))) float f32x16;

struct SigP {
  float g_in;
  float cb0[6], cb1[6], cb2[6], ca1[6], ca2[6];
  float alpha, oma;
  float th, invr, knee, makeup;
  float g_out;
  float gl, gr, send;
};

// ---------------- workspace layout (bytes) ----------------
constexpr size_t OFF_X   = 0;                       // 33,554,432
constexpr size_t OFF_Y   = 33554432;                // 33,554,432
constexpr size_t OFF_FX  = 67108864;                // 4 MB
constexpr size_t OFF_M0  = 71303168;                // 4 MB
// overlays (X dead after pan):
constexpr size_t OFF_FILT = OFF_X;                       // 12,582,912
constexpr size_t OFF_IR   = OFF_X + 12582912;            // 1 MB
constexpr size_t OFF_XM   = OFF_X + 16777216;            // 4 MB master y5
constexpr size_t OFF_M1   = OFF_Y;                       // 4 MB master input
constexpr size_t OFF_WP   = OFF_Y + 4194304;             // 16 MB wet partials [37.7M,54.5M)
constexpr size_t OFF_XB   = OFF_WP + 16777216;           // 2.62 MB padded bf16 x
constexpr size_t OFF_IR2  = OFF_XB + (size_t)4*XBL*2;    // 4*IRL*2 = 589,824 (ends 57,737,728)
constexpr size_t OFF_XBN  = 58720256;                    // 6.59 MB padded bf16 noise'
constexpr size_t OFF_FBV  = 65536000;                    // 100 KB reversed bf16 fb
// E buffers overlay FXb+M0 (free during both chain phases):
constexpr size_t OFF_E12 = OFF_FX;                       // 3,145,728
constexpr size_t OFF_I12 = OFF_FX + 3145728;             // 3,145,728
constexpr size_t OFF_E1  = OFF_FX + 6291456;             // 262,144
constexpr size_t OFF_I1  = OFF_FX + 6553600;             // 262,144
// persistent small region past M0:
constexpr size_t OFF_GL  = 75497472;
constexpr size_t OFF_PT  = OFF_GL + 1024;
constexpr size_t OFF_PM  = OFF_PT + 32*sizeof(SigP);
constexpr size_t OFF_ALT = (OFF_PM + 4*sizeof(SigP) + 7) & ~(size_t)7;
constexpr size_t OFF_ALM = OFF_ALT + 32*8;
constexpr size_t OFF_AT  = (OFF_ALM + 4*8 + 15) & ~(size_t)15;
constexpr size_t OFF_AM  = OFF_AT + 18432;

DEVFN int pq(int i){ return i + ((i >> 5) << 2); }

DEVFN unsigned short f2bf(float f){
  unsigned int u = __float_as_uint(f);
  unsigned int r = (u + 0x7fffu + ((u >> 16) & 1u)) >> 16;
  return (unsigned short)r;
}
DEVFN float bf2f(unsigned short h){ return __uint_as_float(((unsigned int)h) << 16); }

// ---------------- params kernel ----------------
DEVFN double dn(float p, double lo, double hi){ return (double)p*(hi-lo)+lo; }

__device__ void mk_sig(const float* p, int L, bool is_master,
                       SigP* sp, float* Tf, double* aL)
{
  const double flo[6] = {20.,80.,2000.,8000.,12000.,6000.};
  const double fhi[6] = {2000.,2000.,8000.,12000.,21050.,21050.};
  double gdb = dn(p[0], -48., 48.);
  sp->g_in = (float)exp2(gdb * 0.16609640474436813);
  double db0[6],db1[6],db2[6],da1[6],da2[6];
  for (int k=0;k<6;k++){
    double g  = dn(p[1+3*k], -12., 12.);
    double fc = dn(p[2+3*k], flo[k], fhi[k]);
    double q  = dn(p[3+3*k], 0.1, 5.0);
    double A  = pow(10.0, g/40.0);
    double w0 = 2.0*PI_D*(fc/44100.0);
    double al = sin(w0)/(2.0*q), co = cos(w0), sA = sqrt(A);
    double b0,b1,b2,a0,a1,a2;
    if (k==0){
      b0 = A*((A+1.0) - (A-1.0)*co + 2.0*sA*al);
      b1 = 2.0*A*((A-1.0) - (A+1.0)*co);
      b2 = A*((A+1.0) - (A-1.0)*co - 2.0*sA*al);
      a0 = (A+1.0) + (A-1.0)*co + 2.0*sA*al;
      a1 = -2.0*((A-1.0) + (A+1.0)*co);
      a2 = (A+1.0) + (A-1.0)*co - 2.0*sA*al;
    } else if (k==5){
      b0 = A*((A+1.0) + (A-1.0)*co + 2.0*sA*al);
      b1 = -2.0*A*((A-1.0) + (A+1.0)*co);
      b2 = A*((A+1.0) + (A-1.0)*co - 2.0*sA*al);
      a0 = (A+1.0) - (A-1.0)*co + 2.0*sA*al;
      a1 = 2.0*((A-1.0) - (A+1.0)*co);
      a2 = (A+1.0) - (A-1.0)*co - 2.0*sA*al;
    } else {
      b0 = 1.0 + al*A; b1 = -2.0*co; b2 = 1.0 - al*A;
      a0 = 1.0 + al/A; a1 = -2.0*co; a2 = 1.0 - al/A;
    }
    double ia0 = 1.0/a0;
    db0[k]=b0*ia0; db1[k]=b1*ia0; db2[k]=b2*ia0; da1[k]=a1*ia0; da2[k]=a2*ia0;
    sp->cb0[k]=(float)db0[k]; sp->cb1[k]=(float)db1[k]; sp->cb2[k]=(float)db2[k];
    sp->ca1[k]=(float)da1[k]; sp->ca2[k]=(float)da2[k];
  }
  for (int i=0;i<12;i++){
    double st[12]; for (int r=0;r<12;r++) st[r]=0.0; st[i]=1.0;
    double ns[12];
    double yprev=0.0, pm1=0.0, pm2=0.0;
    for (int k=0;k<6;k++){
      double yk = db0[k]*yprev + db1[k]*pm1 + db2[k]*pm2 - da1[k]*st[2*k] - da2[k]*st[2*k+1];
      ns[2*k]=yk; ns[2*k+1]=st[2*k];
      pm1=st[2*k]; pm2=st[2*k+1];
      yprev=yk;
    }
    for (int r=0;r<12;r++) Tf[r*12+i]=(float)ns[r];
  }
  double th    = dn(p[19], -60., 0.);
  double ratio = dn(p[20], 1., 10.);
  double at    = dn(p[21], 5., 250.);
  double knee  = dn(p[23], 3., 12.);
  double mkup  = dn(p[24], 0., 6.);
  double alpha = exp(-log(9.0)/(44100.0*at*0.001));
  sp->alpha=(float)alpha; sp->oma=(float)(1.0-alpha);
  sp->th=(float)th; sp->invr=(float)(1.0/ratio); sp->knee=(float)knee; sp->makeup=(float)mkup;
  *aL = pow(alpha, (double)L);
  if (is_master){
    sp->g_out = (float)exp2(dn(p[25],-48.,48.)*0.16609640474436813);
    sp->gl=0.f; sp->gr=0.f; sp->send=0.f;
  } else {
    sp->g_out = 1.f;
    sp->send = (float)exp2(dn(p[25],-80.,12.)*0.16609640474436813);
    double th2 = dn(p[26],0.,1.)*(PI_D/2.0);
    sp->gl = (float)sqrt((PI_D/2.0-th2)*(2.0/PI_D)*cos(th2));
    sp->gr = (float)sqrt(th2*(2.0/PI_D)*sin(th2));
  }
}

__global__ __launch_bounds__(64) void k_params(const float* __restrict__ tp, const float* __restrict__ mp,
    SigP* Pt, SigP* Pm, float* AT, float* AM, double* aLt, double* aLm)
{
  int i = threadIdx.x;
  if (i < 32)       mk_sig(tp + i*27, L_T, false, &Pt[i], AT + i*144, &aLt[i]);
  else if (i < 36){ int j=i-32; mk_sig(mp + (j>>1)*26, L_M, true, &Pm[j], AM + j*144, &aLm[j]); }
}

__global__ __launch_bounds__(64) void k_power(float* __restrict__ Ab, int lg)
{
  __shared__ float Ma[144], Mb[144];
  int sig = blockIdx.x, t = threadIdx.x;
  float* A = Ab + (size_t)sig*144;
  for (int idx=t; idx<144; idx+=64) Ma[idx]=A[idx];
  __syncthreads();
  int cur=0;
  for (int j=0;j<lg;j++){
    const float* src = cur? Mb:Ma;
    float* dst = cur? Ma:Mb;
    for (int idx=t; idx<144; idx+=64){
      int r=idx/12, cc=idx-r*12;
      float v=0.f;
      #pragma unroll
      for (int m=0;m<12;m++) v = fmaf(src[r*12+m], src[m*12+cc], v);
      dst[idx]=v;
    }
    __syncthreads();
    cur^=1;
  }
  const float* fin = cur? Mb:Ma;
  for (int idx=t; idx<144; idx+=64) A[idx]=fin[idx];
}

DEVFN float comp_gc(float y, float th, float invr, float kn){
  float av  = fmaxf(fabsf(y), 1e-8f);
  float xdb = C_LOG * __builtin_log2f(av);
  float d   = xdb - th;
  float w = (2.f*d < -kn) ? 0.f
          : ((2.f*fabsf(d) <= kn) ? (d+0.5f*kn)*(d+0.5f*kn)/(2.f*kn) : d);
  return (invr-1.f)*w;
}

// ---------------- A-pass ----------------
__global__ __launch_bounds__(256) void k_eqA12(const float* __restrict__ in, const SigP* __restrict__ P,
    float* __restrict__ E12, int C, int L)
{
  int tid = blockIdx.x*256 + threadIdx.x;
  int sig = tid / C, c = tid - sig*C;
  const SigP* sp = P + sig;
  float B0[6],B1[6],B2[6],A1[6],A2[6];
  float g = sp->g_in;
  #pragma unroll
  for (int k=0;k<6;k++){
    float gg = (k==0)? g : 1.f;
    B0[k]=sp->cb0[k]*gg; B1[k]=sp->cb1[k]*gg; B2[k]=sp->cb2[k]*gg;
    A1[k]=sp->ca1[k];    A2[k]=sp->ca2[k];
  }
  const float* xp = in + (size_t)sig*SEQ + (size_t)c*L;
  float xm1=0.f, xm2=0.f;
  if (c){ xm1=xp[-1]; xm2=xp[-2]; }
  float s[12];
  #pragma unroll
  for (int r=0;r<12;r++) s[r]=0.f;
  for (int i=0;i<L;i+=4){
    float4 v = *(const float4*)(xp+i);
    #pragma unroll
    for (int u4=0;u4<4;u4++){
      float u = (u4==0)?v.x:(u4==1)?v.y:(u4==2)?v.z:v.w;
      float yprev=u, pm1=xm1, pm2=xm2;
      float ny[6];
      #pragma unroll
      for (int k=0;k<6;k++){
        float t0 = fmaf(B0[k],yprev, fmaf(B1[k],pm1, fmaf(B2[k],pm2, -A2[k]*s[2*k+1])));
        float yk = fmaf(-A1[k], s[2*k], t0);
        ny[k]=yk;
        pm1=s[2*k]; pm2=s[2*k+1];
        yprev=yk;
      }
      #pragma unroll
      for (int k=0;k<6;k++){ s[2*k+1]=s[2*k]; s[2*k]=ny[k]; }
      xm2=xm1; xm1=u;
    }
  }
  float* ep = E12 + (size_t)tid*12;
  #pragma unroll
  for (int r=0;r<12;r++) ep[r]=s[r];
}

// ---------------- 12-state affine scan ----------------
__global__ __launch_bounds__(64) void k_scan12(const float* __restrict__ E, float* __restrict__ I,
    const float* __restrict__ Ab, int C, int Q, int lgQ)
{
  __shared__ float As[144], Pa[144], Pb[144];
  __shared__ float seg[64][12], ini[64][12];
  __shared__ float scur[12], stmp[12];
  int sig = blockIdx.x, t = threadIdx.x;
  const float* Asig = Ab + (size_t)sig*144;
  for (int idx=t; idx<144; idx+=64) As[idx]=Asig[idx];
  __syncthreads();
  const float* dp = E + ((size_t)sig*C + (size_t)t*Q)*12;
  float s[12];
  #pragma unroll
  for (int r=0;r<12;r++) s[r]=0.f;
  for (int j=0;j<Q;j++){
    const float* d = dp + j*12;
    float ns[12];
    #pragma unroll
    for (int r=0;r<12;r++){
      float v = d[r];
      #pragma unroll
      for (int cc=0;cc<12;cc++) v = fmaf(As[r*12+cc], s[cc], v);
      ns[r]=v;
    }
    #pragma unroll
    for (int r=0;r<12;r++) s[r]=ns[r];
  }
  #pragma unroll
  for (int r=0;r<12;r++) seg[t][r]=s[r];
  for (int idx=t; idx<144; idx+=64) Pa[idx]=As[idx];
  __syncthreads();
  int cur=0;
  for (int j=0;j<lgQ;j++){
    const float* src = cur? Pb:Pa;
    float* dst = cur? Pa:Pb;
    for (int idx=t; idx<144; idx+=64){
      int r=idx/12, cc=idx-r*12;
      float v=0.f;
      #pragma unroll
      for (int m=0;m<12;m++) v = fmaf(src[r*12+m], src[m*12+cc], v);
      dst[idx]=v;
    }
    __syncthreads();
    cur^=1;
  }
  const float* AQ = cur? Pb:Pa;
  if (t<12) scur[t]=0.f;
  __syncthreads();
  for (int u=0;u<64;u++){
    if (t<12){
      ini[u][t]=scur[t];
      float v = seg[u][t];
      #pragma unroll
      for (int cc=0;cc<12;cc++) v = fmaf(AQ[t*12+cc], scur[cc], v);
      stmp[t]=v;
    }
    __syncthreads();
    if (t<12) scur[t]=stmp[t];
    __syncthreads();
  }
  #pragma unroll
  for (int r=0;r<12;r++) s[r]=ini[t][r];
  float* op = I + ((size_t)sig*C + (size_t)t*Q)*12;
  for (int j=0;j<Q;j++){
    float* o = op + j*12;
    #pragma unroll
    for (int r=0;r<12;r++) o[r]=s[r];
    const float* d = dp + j*12;
    float ns[12];
    #pragma unroll
    for (int r=0;r<12;r++){
      float v = d[r];
      #pragma unroll
      for (int cc=0;cc<12;cc++) v = fmaf(As[r*12+cc], s[cc], v);
      ns[r]=v;
    }
    #pragma unroll
    for (int r=0;r<12;r++) s[r]=ns[r];
  }
}

// ---------------- 1-state scan ----------------
__global__ __launch_bounds__(64) void k_scan1p(const float* __restrict__ endst, float* __restrict__ inits,
    const double* __restrict__ aL, int C, int Q, int lgQ)
{
  __shared__ double ag[64], ins[64];
  int sig = blockIdx.x; int t = threadIdx.x;
  double a = aL[sig];
  const float* dp = endst + (size_t)sig*C + (size_t)t*Q;
  double e=0.0;
  for (int j=0;j<Q;j++) e = a*e + (double)dp[j];
  ag[t]=e;
  __syncthreads();
  if (t == 0){
    double p=a;
    for (int j=0;j<lgQ;j++) p = p*p;
    double s=0.0;
    for (int u=0;u<64;u++){
      ins[u]=s;
      s = p*s + ag[u];
    }
  }
  __syncthreads();
  double s = ins[t];
  float* op = inits + (size_t)sig*C + (size_t)t*Q;
  for (int j=0;j<Q;j++){ op[j]=(float)s; s = a*s + (double)dp[j]; }
}

// ---------------- C-pass ----------------
__global__ __launch_bounds__(256) void k_eqC12(const float* __restrict__ in, float* __restrict__ yout,
    const SigP* __restrict__ P, const float* __restrict__ I12, float* __restrict__ E1, int C, int L)
{
  int tid = blockIdx.x*256 + threadIdx.x;
  int sig = tid / C, c = tid - sig*C;
  const SigP* sp = P + sig;
  float B0[6],B1[6],B2[6],A1[6],A2[6];
  float g = sp->g_in;
  #pragma unroll
  for (int k=0;k<6;k++){
    float gg = (k==0)? g : 1.f;
    B0[k]=sp->cb0[k]*gg; B1[k]=sp->cb1[k]*gg; B2[k]=sp->cb2[k]*gg;
    A1[k]=sp->ca1[k];    A2[k]=sp->ca2[k];
  }
  float al=sp->alpha, oma=sp->oma, th=sp->th, invr=sp->invr, kn=sp->knee;
  size_t base = (size_t)sig*SEQ + (size_t)c*L;
  const float* xp = in + base;
  float* op = yout + base;
  float xm1=0.f, xm2=0.f;
  if (c){ xm1=xp[-1]; xm2=xp[-2]; }
  const float* ip = I12 + (size_t)tid*12;
  float s[12];
  #pragma unroll
  for (int r=0;r<12;r++) s[r]=ip[r];
  float gacc=0.f;
  for (int i=0;i<L;i+=4){
    float4 v = *(const float4*)(xp+i);
    float4 o;
    #pragma unroll
    for (int u4=0;u4<4;u4++){
      float u = (u4==0)?v.x:(u4==1)?v.y:(u4==2)?v.z:v.w;
      float yprev=u, pm1=xm1, pm2=xm2;
      float ny[6];
      #pragma unroll
      for (int k=0;k<6;k++){
        float t0 = fmaf(B0[k],yprev, fmaf(B1[k],pm1, fmaf(B2[k],pm2, -A2[k]*s[2*k+1])));
        float yk = fmaf(-A1[k], s[2*k], t0);
        ny[k]=yk;
        pm1=s[2*k]; pm2=s[2*k+1];
        yprev=yk;
      }
      #pragma unroll
      for (int k=0;k<6;k++){ s[2*k+1]=s[2*k]; s[2*k]=ny[k]; }
      xm2=xm1; xm1=u;
      float y5 = ny[5];
      if (u4==0) o.x=y5; else if (u4==1) o.y=y5; else if (u4==2) o.z=y5; else o.w=y5;
      gacc = fmaf(al, gacc, oma*comp_gc(y5,th,invr,kn));
    }
    *(float4*)(op+i) = o;
  }
  E1[tid]=gacc;
}

// ---------------- fused smoother + compressor apply ----------------
__global__ __launch_bounds__(256) void k_smoothcomp(const float* __restrict__ yin,
    const SigP* __restrict__ P, const float* __restrict__ inits1, float* __restrict__ gslast,
    float* __restrict__ outp, int C, int L, int lac)
{
  int tid = blockIdx.x*256 + threadIdx.x;
  int sig = tid / C, c = tid - sig*C;
  const SigP* sp = P + sig;
  float al=sp->alpha, oma=sp->oma, th=sp->th, invr=sp->invr, kn=sp->knee;
  float mk=sp->makeup, go=sp->g_out;
  size_t base = (size_t)sig*SEQ + (size_t)c*L;
  const float* xp = yin + base;
  bool wr = (c >= lac);
  size_t ob = wr ? (base - (size_t)lac*L) : 0;
  const float* yp = yin + ob;
  float* op = outp + ob;
  float gsv = inits1[tid];
  for (int i=0;i<L;i+=4){
    float4 v = *(const float4*)(xp+i);
    float4 gf;
    gsv = fmaf(al, gsv, oma*comp_gc(v.x,th,invr,kn)); gf.x=gsv;
    gsv = fmaf(al, gsv, oma*comp_gc(v.y,th,invr,kn)); gf.y=gsv;
    gsv = fmaf(al, gsv, oma*comp_gc(v.z,th,invr,kn)); gf.z=gsv;
    gsv = fmaf(al, gsv, oma*comp_gc(v.w,th,invr,kn)); gf.w=gsv;
    if (wr){
      float4 y2 = *(const float4*)(yp+i);
      float4 o;
      o.x = y2.x * __builtin_exp2f((gf.x+mk)*C_DB) * go;
      o.y = y2.y * __builtin_exp2f((gf.y+mk)*C_DB) * go;
      o.z = y2.z * __builtin_exp2f((gf.z+mk)*C_DB) * go;
      o.w = y2.w * __builtin_exp2f((gf.w+mk)*C_DB) * go;
      *(float4*)(op+i) = o;
    }
  }
  if (c == C-1) gslast[sig] = gsv;
}

__global__ __launch_bounds__(256) void k_comptail(const float* __restrict__ yin, const float* __restrict__ gslast,
    const SigP* __restrict__ P, float* __restrict__ outp, int la)
{
  int q = blockIdx.x*256 + threadIdx.x;
  int per = la/4;
  int sig = q / per;
  int r = (q - sig*per)*4;
  int n = SEQ - la + r;
  const SigP* sp = P + sig;
  float f = __builtin_exp2f((gslast[sig]+sp->makeup)*C_DB) * sp->g_out;
  size_t base = (size_t)sig*SEQ + n;
  float4 v = *(const float4*)(yin+base);
  float4 o = { v.x*f, v.y*f, v.z*f, v.w*f };
  *(float4*)(outp+base) = o;
}

// ---------------- pan + master/fx sums ----------------
__global__ __launch_bounds__(256) void k_pan(const float* __restrict__ y, const SigP* __restrict__ P,
    float* __restrict__ panned, float* __restrict__ m0, float* __restrict__ fx)
{
  int q = blockIdx.x*256 + threadIdx.x;
  int b = q / (SEQ/4);
  int n = (q - b*(SEQ/4))*4;
  float4 aL={0,0,0,0}, aR={0,0,0,0}, fL={0,0,0,0}, fR={0,0,0,0};
  for (int t=0;t<16;t++){
    const SigP* sp = P + b*16 + t;
    float gl=sp->gl, gr=sp->gr, sd=sp->send;
    float4 v = *(const float4*)(y + (size_t)(b*16+t)*SEQ + n);
    float4 pl = { v.x*gl, v.y*gl, v.z*gl, v.w*gl };
    float4 pr = { v.x*gr, v.y*gr, v.z*gr, v.w*gr };
    *(float4*)(panned + (size_t)(b*32+t)*SEQ + n)    = pl;
    *(float4*)(panned + (size_t)(b*32+16+t)*SEQ + n) = pr;
    aL.x+=pl.x; aL.y+=pl.y; aL.z+=pl.z; aL.w+=pl.w;
    aR.x+=pr.x; aR.y+=pr.y; aR.z+=pr.z; aR.w+=pr.w;
    fL.x=fmaf(pl.x,sd,fL.x); fL.y=fmaf(pl.y,sd,fL.y); fL.z=fmaf(pl.z,sd,fL.z); fL.w=fmaf(pl.w,sd,fL.w);
    fR.x=fmaf(pr.x,sd,fR.x); fR.y=fmaf(pr.y,sd,fR.y); fR.z=fmaf(pr.z,sd,fR.z); fR.w=fmaf(pr.w,sd,fR.w);
  }
  *(float4*)(m0 + (size_t)(b*2+0)*SEQ + n) = aL;
  *(float4*)(m0 + (size_t)(b*2+1)*SEQ + n) = aR;
  *(float4*)(fx + (size_t)(b*2+0)*SEQ + n) = fL;
  *(float4*)(fx + (size_t)(b*2+1)*SEQ + n) = fR;
}

// ---------------- ir = mean over bands of filt*env*gain ----------------
__global__ __launch_bounds__(256) void k_ir(const float* __restrict__ filt, const float* __restrict__ fxp,
    float* __restrict__ ir)
{
  int q = blockIdx.x*256 + threadIdx.x;
  int sig = q / (REV_N/4);
  int i   = (q - sig*(REV_N/4))*4;
  int b = sig >> 1;
  float4 acc={0,0,0,0};
  const float ts = 1.0f/65535.0f;
  for (int band=0; band<12; band++){
    float gn  = fxp[b*25 + band];
    float dec = fxp[b*25 + 12 + band]*10.f + 1.f;
    float4 f = *(const float4*)(filt + ((size_t)(sig*12+band))*REV_N + i);
    float s = -dec*ts;
    float e0=expf(s*(float)i), e1=expf(s*(float)(i+1)), e2=expf(s*(float)(i+2)), e3=expf(s*(float)(i+3));
    acc.x = fmaf(gn*e0, f.x, acc.x);
    acc.y = fmaf(gn*e1, f.y, acc.y);
    acc.z = fmaf(gn*e2, f.z, acc.z);
    acc.w = fmaf(gn*e3, f.w, acc.w);
  }
  const float inv12 = 1.f/12.f;
  acc.x*=inv12; acc.y*=inv12; acc.z*=inv12; acc.w*=inv12;
  *(float4*)(ir + (size_t)sig*REV_N + i) = acc;
}

// ---------------- bf16 prep ----------------
__global__ __launch_bounds__(256) void k_prepx(const float* __restrict__ fx, unsigned short* __restrict__ XB)
{
  int q = blockIdx.x*256 + threadIdx.x;
  int sig = q / XBL;
  int m   = q - sig*XBL;
  int a = m - PADX;
  float v = (a >= 0 && a < SEQ) ? fx[(size_t)sig*SEQ + a] : 0.f;
  XB[(size_t)sig*XBL + m] = f2bf(v);
}
__global__ __launch_bounds__(256) void k_prepir(const float* __restrict__ ir, unsigned short* __restrict__ IRV)
{
  int q = blockIdx.x*256 + threadIdx.x;
  int sig = q / IRL;
  int m   = q - sig*IRL;
  int a = m - IRPAD;
  float v = (a >= 0 && a < REV_N) ? ir[(size_t)sig*REV_N + (REV_N-1 - a)] : 0.f;
  IRV[(size_t)sig*IRL + m] = f2bf(v);
}
__global__ __launch_bounds__(256) void k_prepn(const float* __restrict__ noise, unsigned short* __restrict__ XBN)
{
  int q = blockIdx.x*256 + threadIdx.x;
  int sig = q / XNL;
  if (sig >= 48) return;
  int m   = q - sig*XNL;
  int a = m - PADN + 1022;
  float v = (a >= 0 && a < NOISE_LEN) ? noise[(size_t)sig*NOISE_LEN + a] : 0.f;
  XBN[(size_t)sig*XNL + m] = f2bf(v);
}
__global__ __launch_bounds__(256) void k_prepfb(const float* __restrict__ fb, unsigned short* __restrict__ FBV)
{
  int q = blockIdx.x*256 + threadIdx.x;
  int band = q / FBL;
  if (band >= 12) return;
  int m = q - band*FBL;
  int a = m - FPAD;
  float v = (a >= 0 && a < TAPS) ? fb[band*TAPS + (TAPS-1 - a)] : 0.f;
  FBV[(size_t)band*FBL + m] = f2bf(v);
}

// ---------------- band FIR via MFMA (unchanged structure) ----------------
__global__ __launch_bounds__(256,3) void k_firm(const unsigned short* __restrict__ XBN,
    const unsigned short* __restrict__ FBV, float* __restrict__ filt)
{
  __shared__ alignas(16) unsigned int xs0[4640];
  __shared__ alignas(16) unsigned int xs1[4640];
  __shared__ alignas(16) unsigned short sir[3456];
  int b = blockIdx.x;                 // 384 = 8 ngrp * 48 sig
  int ng  = b & 7;
  int sig = b >> 3;
  int band = sig % 12;
  int nblk = ng << 13;
  const int sbeg = -62;
  const int send = 126;

  int tid = threadIdx.x;
  int l  = tid & 63, wv = tid >> 6;
  int lj = l & 31, lg = l >> 5, ph = l & 1;
  int hl = (lj + 8*lg - ph) >> 1;
  int offB = 32*lj - 8*lg;
  const unsigned int* xbu = (const unsigned int*)(XBN + (size_t)sig*XNL);
  const unsigned short* irg = FBV + (size_t)band*FBL;
  const unsigned int* xsel = ph ? (const unsigned int*)xs1 : (const unsigned int*)xs0;

  f32x16 acc0 = {};
  f32x16 acc1 = {};
  int n0_0 = nblk + (wv*2+0)*1024;
  int n0_1 = nblk + (wv*2+1)*1024;

  for (int sa = sbeg; sa < send; sa += 128){
    int ns = send - sa; if (ns > 128) ns = 128;
    __syncthreads();
    int clo = nblk - 16*(sa + ns - 1);
    int ub  = (PADN + clo) >> 1;
    int nd  = ((nblk + 7168 + 46 - 16*sa) - clo)/2 + 2;
    for (int d = tid; d < nd; d += 256){
      unsigned int u0 = xbu[ub + d], u1 = xbu[ub + d + 1];
      xs0[d] = u0;
      xs1[d] = (u0 >> 16) | (u1 << 16);
    }
    int amin = 1022 - 16*(sa + ns - 1) - 992;
    int irlo = ((amin - 6) & ~7) + 6;
    int irspan = (1022 - 16*sa + 15) - irlo + 1;
    for (int r = tid; r < irspan; r += 256){
      sir[r + ((r>>6)<<3)] = irg[FPAD + irlo + r];
    }
    __syncthreads();
    int db0 = ((n0_0 - clo) >> 1) - 8*sa + hl;
    int db1 = ((n0_1 - clo) >> 1) - 8*sa + hl;
    int Dh0 = 1022 - 16*sa - irlo;
    for (int ss = 0; ss < ns; ss++){
      int rB = (Dh0 - 16*ss) - offB;
      short8v bfrag = *(const short8v*)(sir + rB + ((rB>>6)<<3));
      union { unsigned int u[4]; short8v v; } a0, a1;
      int d0 = db0 - 8*ss, d1 = db1 - 8*ss;
      a0.u[0]=xsel[d0];   a0.u[1]=xsel[d0+1]; a0.u[2]=xsel[d0+2]; a0.u[3]=xsel[d0+3];
      a1.u[0]=xsel[d1];   a1.u[1]=xsel[d1+1]; a1.u[2]=xsel[d1+2]; a1.u[3]=xsel[d1+3];
      acc0 = __builtin_amdgcn_mfma_f32_32x32x16_bf16(a0.v, bfrag, acc0, 0, 0, 0);
      acc1 = __builtin_amdgcn_mfma_f32_32x32x16_bf16(a1.v, bfrag, acc1, 0, 0, 0);
    }
  }
  float* fp = filt + (size_t)sig*REV_N;
  #pragma unroll
  for (int reg = 0; reg < 16; reg++){
    int i = (reg & 3) + 8*(reg >> 2) + 4*lg;
    fp[n0_0 + i + 32*lj] = acc0[reg];
    fp[n0_1 + i + 32*lj] = acc1[reg];
  }
}

// ---------------- wet conv via MFMA: 1 A-frag x 4 B-frags per wave ----------------
// Wave covers outputs [n0_w, n0_w+4096): acc_b covers n0_w + 1024b + i + 32j.
// B-frag b reads sir at padded offset pb - 1152*b (tap offset +1024b).
// s range [-254, 4097) so every output's tap union covers [0,65536); extras hit zero pad.
__global__ __launch_bounds__(256,2) void k_wetm(const unsigned short* __restrict__ XB,
    const unsigned short* __restrict__ IRV, unsigned short* __restrict__ WP)
{
  __shared__ alignas(16) unsigned int xs0[6688];
  __shared__ alignas(16) unsigned int xs1[6688];
  __shared__ alignas(16) unsigned short sir[5760];
  int b = blockIdx.x;                 // 512 = 16 ngrp * 4 sig * 8 kp
  int ng  = b & 15;
  int sig = (b >> 4) & 3;
  int kp  = b >> 6;
  int nblk = ng << 14;                // 16384 outputs per block
  int sbeg = -254 + 544*kp;
  int send = sbeg + 544; if (send > 4097) send = 4097;

  int tid = threadIdx.x;
  int l  = tid & 63, wv = tid >> 6;
  int lj = l & 31, lg = l >> 5, ph = l & 1;
  int hl = (lj + 8*lg - ph) >> 1;
  int offB = 32*lj - 8*lg;
  const unsigned int* xbu = (const unsigned int*)(XB + (size_t)sig*XBL);
  const unsigned short* irg = IRV + (size_t)sig*IRL;
  const unsigned int* xsel = ph ? (const unsigned int*)xs1 : (const unsigned int*)xs0;

  f32x16 acc0 = {}, acc1 = {}, acc2 = {}, acc3 = {};
  int n0_w = nblk + wv*4096;

  for (int sa = sbeg; sa < send; sa += 64){
    int ns = send - sa; if (ns > 64) ns = 64;
    __syncthreads();
    // ---- stage x: window [clo, clo + 12334 + 16(ns-1)] ----
    int clo = nblk - 16*(sa + ns - 1);
    int ub  = (PADX + clo) >> 1;
    int nd  = (12336 + 16*(ns-1))/2 + 2;
    for (int d = tid; d < nd; d += 256){
      unsigned int u0 = xbu[ub + d], u1 = xbu[ub + d + 1];
      xs0[d] = u0;
      xs1[d] = (u0 >> 16) | (u1 << 16);
    }
    // ---- stage reversed ir: positions [irlo, 65535-16sa+15], irlo === 7 mod 8 ----
    int amin = 65535 - 16*(sa + ns - 1) - 4064;
    int irlo = ((amin - 7) & ~7) + 7;
    int irspan = (65535 - 16*sa + 15) - irlo + 1;
    for (int r = tid; r < irspan; r += 256){
      sir[r + ((r>>6)<<3)] = irg[IRPAD + irlo + r];
    }
    __syncthreads();
    // ---- compute ----
    int db0 = ((n0_w - clo) >> 1) - 8*sa + hl;
    int Dh0 = 65535 - 16*sa - irlo;
    for (int ss = 0; ss < ns; ss++){
      int rB = (Dh0 - 16*ss) - offB;
      int pb = rB + ((rB>>6)<<3);
      short8v bf0 = *(const short8v*)(sir + pb);
      short8v bf1 = *(const short8v*)(sir + pb - 1152);
      short8v bf2 = *(const short8v*)(sir + pb - 2304);
      short8v bf3 = *(const short8v*)(sir + pb - 3456);
      union { unsigned int u[4]; short8v v; } a0;
      int d0 = db0 - 8*ss;
      a0.u[0]=xsel[d0]; a0.u[1]=xsel[d0+1]; a0.u[2]=xsel[d0+2]; a0.u[3]=xsel[d0+3];
      acc0 = __builtin_amdgcn_mfma_f32_32x32x16_bf16(a0.v, bf0, acc0, 0, 0, 0);
      acc1 = __builtin_amdgcn_mfma_f32_32x32x16_bf16(a0.v, bf1, acc1, 0, 0, 0);
      acc2 = __builtin_amdgcn_mfma_f32_32x32x16_bf16(a0.v, bf2, acc2, 0, 0, 0);
      acc3 = __builtin_amdgcn_mfma_f32_32x32x16_bf16(a0.v, bf3, acc3, 0, 0, 0);
    }
  }
  // ---- writeout bf16 partials ----
  unsigned short* wp = WP + ((size_t)(kp*4+sig))*SEQ;
  #pragma unroll
  for (int reg = 0; reg < 16; reg++){
    int i = (reg & 3) + 8*(reg >> 2) + 4*lg;
    int o = n0_w + i + 32*lj;
    wp[o]        = f2bf(acc0[reg]);
    wp[o + 1024] = f2bf(acc1[reg]);
    wp[o + 2048] = f2bf(acc2[reg]);
    wp[o + 3072] = f2bf(acc3[reg]);
  }
}

// ---------------- reduce partials + mix + add to master ----------------
__global__ __launch_bounds__(256) void k_wetred(const unsigned short* __restrict__ wp, const float* __restrict__ fx,
    const float* __restrict__ m0, const float* __restrict__ fxp, float* __restrict__ m1)
{
  int q = blockIdx.x*256 + threadIdx.x;
  int sig = q / (SEQ/4);
  int n = (q - sig*(SEQ/4))*4;
  float mix = fxp[(sig>>1)*25+24];
  size_t ob = (size_t)sig*SEQ + n;
  float s0=0.f, s1=0.f, s2=0.f, s3=0.f;
  #pragma unroll
  for (int kp=0; kp<8; kp++){
    const unsigned short* p = wp + ((size_t)(kp*4+sig))*SEQ + n;
    s0 += bf2f(p[0]); s1 += bf2f(p[1]); s2 += bf2f(p[2]); s3 += bf2f(p[3]);
  }
  float4 w0 = *(const float4*)(m0+ob);
  float4 x0 = *(const float4*)(fx+ob);
  float om = 1.f - mix;
  float4 o;
  o.x = w0.x + om*x0.x + mix*s0;
  o.y = w0.y + om*x0.y + mix*s1;
  o.z = w0.z + om*x0.z + mix*s2;
  o.w = w0.w + om*x0.w + mix*s3;
  *(float4*)(m1+ob) = o;
}

// ---------------- launch ----------------
extern "C" void kernel_launch(void* const* d_in, const int* in_sizes, int n_in,
                              void* d_out, int out_size, void* d_ws, size_t ws_size,
                              hipStream_t stream)
{
  const float* tracks = (const float*)d_in[0];
  const float* tp     = (const float*)d_in[1];
  const float* fxp    = (const float*)d_in[2];
  const float* mp     = (const float*)d_in[3];
  const float* noise  = (const float*)d_in[4];
  const float* fbp    = (const float*)d_in[5];
  float* out = (float*)d_out;
  char* w = (char*)d_ws;

  float*  X   = (float*)(w + OFF_X);
  float*  Y   = (float*)(w + OFF_Y);
  float*  FXb = (float*)(w + OFF_FX);
  float*  M0  = (float*)(w + OFF_M0);
  float*  E12 = (float*)(w + OFF_E12);
  float*  I12 = (float*)(w + OFF_I12);
  float*  E1  = (float*)(w + OFF_E1);
  float*  I1  = (float*)(w + OFF_I1);
  float*  GLt = (float*)(w + OFF_GL);
  float*  GLm = GLt + 32;
  SigP*   Pt  = (SigP*)(w + OFF_PT);
  SigP*   Pm  = (SigP*)(w + OFF_PM);
  double* aLt = (double*)(w + OFF_ALT);
  double* aLm = (double*)(w + OFF_ALM);
  float*  AT  = (float*)(w + OFF_AT);
  float*  AM  = (float*)(w + OFF_AM);
  float*  FILT= (float*)(w + OFF_FILT);
  float*  IR  = (float*)(w + OFF_IR);
  float*  XM  = (float*)(w + OFF_XM);
  float*  M1  = (float*)(w + OFF_M1);
  unsigned short* WPu = (unsigned short*)(w + OFF_WP);
  unsigned short* XB  = (unsigned short*)(w + OFF_XB);
  unsigned short* IRV = (unsigned short*)(w + OFF_IR2);
  unsigned short* XBN = (unsigned short*)(w + OFF_XBN);
  unsigned short* FBV = (unsigned short*)(w + OFF_FBV);

  k_params<<<1,64,0,stream>>>(tp, mp, Pt, Pm, AT, AM, aLt, aLm);
  k_power<<<32,64,0,stream>>>(AT, 7);   // T^128
  k_power<<<4,64,0,stream>>>(AM, 6);    // T^64

  // ---- track chain ----
  const int GT = NS_T*C_T/256;
  k_eqA12<<<GT,256,0,stream>>>(tracks, Pt, E12, C_T, L_T);
  k_scan12<<<NS_T,64,0,stream>>>(E12, I12, AT, C_T, C_T/64, 5);
  k_eqC12<<<GT,256,0,stream>>>(tracks, Y, Pt, I12, E1, C_T, L_T);
  k_scan1p<<<NS_T,64,0,stream>>>(E1, I1, aLt, C_T, C_T/64, 5);
  k_smoothcomp<<<GT,256,0,stream>>>(Y, Pt, I1, GLt, X, C_T, L_T, LA_T/L_T);
  k_comptail<<<NS_T*(LA_T/4)/256,256,0,stream>>>(Y, GLt, Pt, X, LA_T);
  k_pan<<<2*(SEQ/4)/256,256,0,stream>>>(X, Pt, out, M0, FXb);

  // ---- reverb ----
  k_prepn<<<(48*XNL+255)/256,256,0,stream>>>(noise, XBN);
  k_prepfb<<<(12*FBL+255)/256,256,0,stream>>>(fbp, FBV);
  k_firm<<<384,256,0,stream>>>(XBN, FBV, FILT);
  k_ir<<<4*(REV_N/4)/256,256,0,stream>>>(FILT, fxp, IR);
  k_prepx<<<(4*XBL)/256,256,0,stream>>>(FXb, XB);
  k_prepir<<<(4*IRL)/256,256,0,stream>>>(IR, IRV);
  k_wetm<<<512,256,0,stream>>>(XB, IRV, WPu);
  k_wetred<<<4*(SEQ/4)/256,256,0,stream>>>(WPu, FXb, M0, fxp, M1);

  // ---- master chain ----
  const int GM = NS_M*C_M/256;
  k_eqA12<<<GM,256,0,stream>>>(M1, Pm, E12, C_M, L_M);
  k_scan12<<<NS_M,64,0,stream>>>(E12, I12, AM, C_M, C_M/64, 6);
  k_eqC12<<<GM,256,0,stream>>>(M1, XM, Pm, I12, E1, C_M, L_M);
  k_scan1p<<<NS_M,64,0,stream>>>(E1, I1, aLm, C_M, C_M/64, 6);
  k_smoothcomp<<<GM,256,0,stream>>>(XM, Pm, I1, GLm, out + OUT_MASTER_OFF, C_M, L_M, LA_M/L_M);
  k_comptail<<<NS_M*(LA_M/4)/256,256,0,stream>>>(XM, GLm, Pm, out + OUT_MASTER_OFF, LA_M);
}

// Round 13
// 509.744 us; speedup vs baseline: 10.8943x; 1.0251x over previous
//
#include <hip/hip_runtime.h>

#define DEVFN __device__ __forceinline__

constexpr int SEQ = 262144;
constexpr int REV_N = 65536;
constexpr int TAPS = 1023;
constexpr int NOISE_LEN = REV_N + TAPS - 1;   // 66558

constexpr int NS_T = 32, L_T = 128, C_T = 2048;
constexpr int NS_M = 4,  L_M = 64,  C_M = 4096;
constexpr int LA_T = 2048, LA_M = 1024;

constexpr int OUT_MASTER_OFF = 16777216;

// bf16 wet-conv buffers
constexpr int PADX = 65552;
constexpr int XBL  = 327744;
constexpr int IRPAD = 4096;
constexpr int IRL  = 73728;
// bf16 fir buffers
constexpr int PADN = 2016;
constexpr int XNL  = 68640;
constexpr int FPAD = 2048;
constexpr int FBL  = 4160;

#define C_DB  0.16609640474436813f
#define C_LOG 6.0205999132796239f
#define PI_D  3.14159265358979323846

typedef __attribute__((ext_vector_type(8)))  short short8v;
typedef __attribute__((ext_vector_type(16))) float f32x16;

struct SigP {
  float g_in;
  float cb0[6], cb1[6], cb2[6], ca1[6], ca2[6];
  float alpha, oma;
  float th, invr, knee, makeup;
  float g_out;
  float gl, gr, send;
};

// ---------------- workspace layout (bytes) ----------------
constexpr size_t OFF_X   = 0;
constexpr size_t OFF_Y   = 33554432;
constexpr size_t OFF_FX  = 67108864;
constexpr size_t OFF_M0  = 71303168;
constexpr size_t OFF_FILT = OFF_X;
constexpr size_t OFF_IR   = OFF_X + 12582912;
constexpr size_t OFF_XM   = OFF_X + 16777216;
constexpr size_t OFF_M1   = OFF_Y;
constexpr size_t OFF_WP   = OFF_Y + 4194304;
constexpr size_t OFF_XB   = OFF_WP + 16777216;
constexpr size_t OFF_IR2  = OFF_XB + (size_t)4*XBL*2;
constexpr size_t OFF_XBN  = 58720256;
constexpr size_t OFF_FBV  = 65536000;
constexpr size_t OFF_E12 = OFF_FX;
constexpr size_t OFF_I12 = OFF_FX + 3145728;
constexpr size_t OFF_E1  = OFF_FX + 6291456;
constexpr size_t OFF_I1  = OFF_FX + 6553600;
constexpr size_t OFF_GL  = 75497472;
constexpr size_t OFF_PT  = OFF_GL + 1024;
constexpr size_t OFF_PM  = OFF_PT + 32*sizeof(SigP);
constexpr size_t OFF_ALT = (OFF_PM + 4*sizeof(SigP) + 7) & ~(size_t)7;
constexpr size_t OFF_ALM = OFF_ALT + 32*8;
constexpr size_t OFF_AT  = (OFF_ALM + 4*8 + 15) & ~(size_t)15;
constexpr size_t OFF_AM  = OFF_AT + 18432;

DEVFN int pq(int i){ return i + ((i >> 5) << 2); }
// B-side pad: +8 elems per 32 -> strided b128 (64B lane stride) conflict-free
DEVFN int pqb(int i){ return i + ((i >> 5) << 3); }

DEVFN unsigned short f2bf(float f){
  unsigned int u = __float_as_uint(f);
  unsigned int r = (u + 0x7fffu + ((u >> 16) & 1u)) >> 16;
  return (unsigned short)r;
}
DEVFN float bf2f(unsigned short h){ return __uint_as_float(((unsigned int)h) << 16); }

// ---------------- params kernel ----------------
DEVFN double dn(float p, double lo, double hi){ return (double)p*(hi-lo)+lo; }

__device__ void mk_sig(const float* p, int L, bool is_master,
                       SigP* sp, float* Tf, double* aL)
{
  const double flo[6] = {20.,80.,2000.,8000.,12000.,6000.};
  const double fhi[6] = {2000.,2000.,8000.,12000.,21050.,21050.};
  double gdb = dn(p[0], -48., 48.);
  sp->g_in = (float)exp2(gdb * 0.16609640474436813);
  double db0[6],db1[6],db2[6],da1[6],da2[6];
  for (int k=0;k<6;k++){
    double g  = dn(p[1+3*k], -12., 12.);
    double fc = dn(p[2+3*k], flo[k], fhi[k]);
    double q  = dn(p[3+3*k], 0.1, 5.0);
    double A  = pow(10.0, g/40.0);
    double w0 = 2.0*PI_D*(fc/44100.0);
    double al = sin(w0)/(2.0*q), co = cos(w0), sA = sqrt(A);
    double b0,b1,b2,a0,a1,a2;
    if (k==0){
      b0 = A*((A+1.0) - (A-1.0)*co + 2.0*sA*al);
      b1 = 2.0*A*((A-1.0) - (A+1.0)*co);
      b2 = A*((A+1.0) - (A-1.0)*co - 2.0*sA*al);
      a0 = (A+1.0) + (A-1.0)*co + 2.0*sA*al;
      a1 = -2.0*((A-1.0) + (A+1.0)*co);
      a2 = (A+1.0) + (A-1.0)*co - 2.0*sA*al;
    } else if (k==5){
      b0 = A*((A+1.0) + (A-1.0)*co + 2.0*sA*al);
      b1 = -2.0*A*((A-1.0) + (A+1.0)*co);
      b2 = A*((A+1.0) + (A-1.0)*co - 2.0*sA*al);
      a0 = (A+1.0) - (A-1.0)*co + 2.0*sA*al;
      a1 = 2.0*((A-1.0) - (A+1.0)*co);
      a2 = (A+1.0) - (A-1.0)*co - 2.0*sA*al;
    } else {
      b0 = 1.0 + al*A; b1 = -2.0*co; b2 = 1.0 - al*A;
      a0 = 1.0 + al/A; a1 = -2.0*co; a2 = 1.0 - al/A;
    }
    double ia0 = 1.0/a0;
    db0[k]=b0*ia0; db1[k]=b1*ia0; db2[k]=b2*ia0; da1[k]=a1*ia0; da2[k]=a2*ia0;
    sp->cb0[k]=(float)db0[k]; sp->cb1[k]=(float)db1[k]; sp->cb2[k]=(float)db2[k];
    sp->ca1[k]=(float)da1[k]; sp->ca2[k]=(float)da2[k];
  }
  for (int i=0;i<12;i++){
    double st[12]; for (int r=0;r<12;r++) st[r]=0.0; st[i]=1.0;
    double ns[12];
    double yprev=0.0, pm1=0.0, pm2=0.0;
    for (int k=0;k<6;k++){
      double yk = db0[k]*yprev + db1[k]*pm1 + db2[k]*pm2 - da1[k]*st[2*k] - da2[k]*st[2*k+1];
      ns[2*k]=yk; ns[2*k+1]=st[2*k];
      pm1=st[2*k]; pm2=st[2*k+1];
      yprev=yk;
    }
    for (int r=0;r<12;r++) Tf[r*12+i]=(float)ns[r];
  }
  double th    = dn(p[19], -60., 0.);
  double ratio = dn(p[20], 1., 10.);
  double at    = dn(p[21], 5., 250.);
  double knee  = dn(p[23], 3., 12.);
  double mkup  = dn(p[24], 0., 6.);
  double alpha = exp(-log(9.0)/(44100.0*at*0.001));
  sp->alpha=(float)alpha; sp->oma=(float)(1.0-alpha);
  sp->th=(float)th; sp->invr=(float)(1.0/ratio); sp->knee=(float)knee; sp->makeup=(float)mkup;
  *aL = pow(alpha, (double)L);
  if (is_master){
    sp->g_out = (float)exp2(dn(p[25],-48.,48.)*0.16609640474436813);
    sp->gl=0.f; sp->gr=0.f; sp->send=0.f;
  } else {
    sp->g_out = 1.f;
    sp->send = (float)exp2(dn(p[25],-80.,12.)*0.16609640474436813);
    double th2 = dn(p[26],0.,1.)*(PI_D/2.0);
    sp->gl = (float)sqrt((PI_D/2.0-th2)*(2.0/PI_D)*cos(th2));
    sp->gr = (float)sqrt(th2*(2.0/PI_D)*sin(th2));
  }
}

__global__ __launch_bounds__(64) void k_params(const float* __restrict__ tp, const float* __restrict__ mp,
    SigP* Pt, SigP* Pm, float* AT, float* AM, double* aLt, double* aLm)
{
  int i = threadIdx.x;
  if (i < 32)       mk_sig(tp + i*27, L_T, false, &Pt[i], AT + i*144, &aLt[i]);
  else if (i < 36){ int j=i-32; mk_sig(mp + (j>>1)*26, L_M, true, &Pm[j], AM + j*144, &aLm[j]); }
}

__global__ __launch_bounds__(64) void k_power(float* __restrict__ Ab, int lg)
{
  __shared__ float Ma[144], Mb[144];
  int sig = blockIdx.x, t = threadIdx.x;
  float* A = Ab + (size_t)sig*144;
  for (int idx=t; idx<144; idx+=64) Ma[idx]=A[idx];
  __syncthreads();
  int cur=0;
  for (int j=0;j<lg;j++){
    const float* src = cur? Mb:Ma;
    float* dst = cur? Ma:Mb;
    for (int idx=t; idx<144; idx+=64){
      int r=idx/12, cc=idx-r*12;
      float v=0.f;
      #pragma unroll
      for (int m=0;m<12;m++) v = fmaf(src[r*12+m], src[m*12+cc], v);
      dst[idx]=v;
    }
    __syncthreads();
    cur^=1;
  }
  const float* fin = cur? Mb:Ma;
  for (int idx=t; idx<144; idx+=64) A[idx]=fin[idx];
}

DEVFN float comp_gc(float y, float th, float invr, float kn){
  float av  = fmaxf(fabsf(y), 1e-8f);
  float xdb = C_LOG * __builtin_log2f(av);
  float d   = xdb - th;
  float w = (2.f*d < -kn) ? 0.f
          : ((2.f*fabsf(d) <= kn) ? (d+0.5f*kn)*(d+0.5f*kn)/(2.f*kn) : d);
  return (invr-1.f)*w;
}

// ---------------- A-pass ----------------
__global__ __launch_bounds__(256) void k_eqA12(const float* __restrict__ in, const SigP* __restrict__ P,
    float* __restrict__ E12, int C, int L)
{
  int tid = blockIdx.x*256 + threadIdx.x;
  int sig = tid / C, c = tid - sig*C;
  const SigP* sp = P + sig;
  float B0[6],B1[6],B2[6],A1[6],A2[6];
  float g = sp->g_in;
  #pragma unroll
  for (int k=0;k<6;k++){
    float gg = (k==0)? g : 1.f;
    B0[k]=sp->cb0[k]*gg; B1[k]=sp->cb1[k]*gg; B2[k]=sp->cb2[k]*gg;
    A1[k]=sp->ca1[k];    A2[k]=sp->ca2[k];
  }
  const float* xp = in + (size_t)sig*SEQ + (size_t)c*L;
  float xm1=0.f, xm2=0.f;
  if (c){ xm1=xp[-1]; xm2=xp[-2]; }
  float s[12];
  #pragma unroll
  for (int r=0;r<12;r++) s[r]=0.f;
  for (int i=0;i<L;i+=4){
    float4 v = *(const float4*)(xp+i);
    #pragma unroll
    for (int u4=0;u4<4;u4++){
      float u = (u4==0)?v.x:(u4==1)?v.y:(u4==2)?v.z:v.w;
      float yprev=u, pm1=xm1, pm2=xm2;
      float ny[6];
      #pragma unroll
      for (int k=0;k<6;k++){
        float t0 = fmaf(B0[k],yprev, fmaf(B1[k],pm1, fmaf(B2[k],pm2, -A2[k]*s[2*k+1])));
        float yk = fmaf(-A1[k], s[2*k], t0);
        ny[k]=yk;
        pm1=s[2*k]; pm2=s[2*k+1];
        yprev=yk;
      }
      #pragma unroll
      for (int k=0;k<6;k++){ s[2*k+1]=s[2*k]; s[2*k]=ny[k]; }
      xm2=xm1; xm1=u;
    }
  }
  float* ep = E12 + (size_t)tid*12;
  #pragma unroll
  for (int r=0;r<12;r++) ep[r]=s[r];
}

// ---------------- 12-state affine scan ----------------
__global__ __launch_bounds__(64) void k_scan12(const float* __restrict__ E, float* __restrict__ I,
    const float* __restrict__ Ab, int C, int Q, int lgQ)
{
  __shared__ float As[144], Pa[144], Pb[144];
  __shared__ float seg[64][12], ini[64][12];
  __shared__ float scur[12], stmp[12];
  int sig = blockIdx.x, t = threadIdx.x;
  const float* Asig = Ab + (size_t)sig*144;
  for (int idx=t; idx<144; idx+=64) As[idx]=Asig[idx];
  __syncthreads();
  const float* dp = E + ((size_t)sig*C + (size_t)t*Q)*12;
  float s[12];
  #pragma unroll
  for (int r=0;r<12;r++) s[r]=0.f;
  for (int j=0;j<Q;j++){
    const float* d = dp + j*12;
    float ns[12];
    #pragma unroll
    for (int r=0;r<12;r++){
      float v = d[r];
      #pragma unroll
      for (int cc=0;cc<12;cc++) v = fmaf(As[r*12+cc], s[cc], v);
      ns[r]=v;
    }
    #pragma unroll
    for (int r=0;r<12;r++) s[r]=ns[r];
  }
  #pragma unroll
  for (int r=0;r<12;r++) seg[t][r]=s[r];
  for (int idx=t; idx<144; idx+=64) Pa[idx]=As[idx];
  __syncthreads();
  int cur=0;
  for (int j=0;j<lgQ;j++){
    const float* src = cur? Pb:Pa;
    float* dst = cur? Pa:Pb;
    for (int idx=t; idx<144; idx+=64){
      int r=idx/12, cc=idx-r*12;
      float v=0.f;
      #pragma unroll
      for (int m=0;m<12;m++) v = fmaf(src[r*12+m], src[m*12+cc], v);
      dst[idx]=v;
    }
    __syncthreads();
    cur^=1;
  }
  const float* AQ = cur? Pb:Pa;
  if (t<12) scur[t]=0.f;
  __syncthreads();
  for (int u=0;u<64;u++){
    if (t<12){
      ini[u][t]=scur[t];
      float v = seg[u][t];
      #pragma unroll
      for (int cc=0;cc<12;cc++) v = fmaf(AQ[t*12+cc], scur[cc], v);
      stmp[t]=v;
    }
    __syncthreads();
    if (t<12) scur[t]=stmp[t];
    __syncthreads();
  }
  #pragma unroll
  for (int r=0;r<12;r++) s[r]=ini[t][r];
  float* op = I + ((size_t)sig*C + (size_t)t*Q)*12;
  for (int j=0;j<Q;j++){
    float* o = op + j*12;
    #pragma unroll
    for (int r=0;r<12;r++) o[r]=s[r];
    const float* d = dp + j*12;
    float ns[12];
    #pragma unroll
    for (int r=0;r<12;r++){
      float v = d[r];
      #pragma unroll
      for (int cc=0;cc<12;cc++) v = fmaf(As[r*12+cc], s[cc], v);
      ns[r]=v;
    }
    #pragma unroll
    for (int r=0;r<12;r++) s[r]=ns[r];
  }
}

// ---------------- 1-state scan ----------------
__global__ __launch_bounds__(64) void k_scan1p(const float* __restrict__ endst, float* __restrict__ inits,
    const double* __restrict__ aL, int C, int Q, int lgQ)
{
  __shared__ double ag[64], ins[64];
  int sig = blockIdx.x; int t = threadIdx.x;
  double a = aL[sig];
  const float* dp = endst + (size_t)sig*C + (size_t)t*Q;
  double e=0.0;
  for (int j=0;j<Q;j++) e = a*e + (double)dp[j];
  ag[t]=e;
  __syncthreads();
  if (t == 0){
    double p=a;
    for (int j=0;j<lgQ;j++) p = p*p;
    double s=0.0;
    for (int u=0;u<64;u++){
      ins[u]=s;
      s = p*s + ag[u];
    }
  }
  __syncthreads();
  double s = ins[t];
  float* op = inits + (size_t)sig*C + (size_t)t*Q;
  for (int j=0;j<Q;j++){ op[j]=(float)s; s = a*s + (double)dp[j]; }
}

// ---------------- C-pass ----------------
__global__ __launch_bounds__(256) void k_eqC12(const float* __restrict__ in, float* __restrict__ yout,
    const SigP* __restrict__ P, const float* __restrict__ I12, float* __restrict__ E1, int C, int L)
{
  int tid = blockIdx.x*256 + threadIdx.x;
  int sig = tid / C, c = tid - sig*C;
  const SigP* sp = P + sig;
  float B0[6],B1[6],B2[6],A1[6],A2[6];
  float g = sp->g_in;
  #pragma unroll
  for (int k=0;k<6;k++){
    float gg = (k==0)? g : 1.f;
    B0[k]=sp->cb0[k]*gg; B1[k]=sp->cb1[k]*gg; B2[k]=sp->cb2[k]*gg;
    A1[k]=sp->ca1[k];    A2[k]=sp->ca2[k];
  }
  float al=sp->alpha, oma=sp->oma, th=sp->th, invr=sp->invr, kn=sp->knee;
  size_t base = (size_t)sig*SEQ + (size_t)c*L;
  const float* xp = in + base;
  float* op = yout + base;
  float xm1=0.f, xm2=0.f;
  if (c){ xm1=xp[-1]; xm2=xp[-2]; }
  const float* ip = I12 + (size_t)tid*12;
  float s[12];
  #pragma unroll
  for (int r=0;r<12;r++) s[r]=ip[r];
  float gacc=0.f;
  for (int i=0;i<L;i+=4){
    float4 v = *(const float4*)(xp+i);
    float4 o;
    #pragma unroll
    for (int u4=0;u4<4;u4++){
      float u = (u4==0)?v.x:(u4==1)?v.y:(u4==2)?v.z:v.w;
      float yprev=u, pm1=xm1, pm2=xm2;
      float ny[6];
      #pragma unroll
      for (int k=0;k<6;k++){
        float t0 = fmaf(B0[k],yprev, fmaf(B1[k],pm1, fmaf(B2[k],pm2, -A2[k]*s[2*k+1])));
        float yk = fmaf(-A1[k], s[2*k], t0);
        ny[k]=yk;
        pm1=s[2*k]; pm2=s[2*k+1];
        yprev=yk;
      }
      #pragma unroll
      for (int k=0;k<6;k++){ s[2*k+1]=s[2*k]; s[2*k]=ny[k]; }
      xm2=xm1; xm1=u;
      float y5 = ny[5];
      if (u4==0) o.x=y5; else if (u4==1) o.y=y5; else if (u4==2) o.z=y5; else o.w=y5;
      gacc = fmaf(al, gacc, oma*comp_gc(y5,th,invr,kn));
    }
    *(float4*)(op+i) = o;
  }
  E1[tid]=gacc;
}

// ---------------- fused smoother + compressor apply ----------------
__global__ __launch_bounds__(256) void k_smoothcomp(const float* __restrict__ yin,
    const SigP* __restrict__ P, const float* __restrict__ inits1, float* __restrict__ gslast,
    float* __restrict__ outp, int C, int L, int lac)
{
  int tid = blockIdx.x*256 + threadIdx.x;
  int sig = tid / C, c = tid - sig*C;
  const SigP* sp = P + sig;
  float al=sp->alpha, oma=sp->oma, th=sp->th, invr=sp->invr, kn=sp->knee;
  float mk=sp->makeup, go=sp->g_out;
  size_t base = (size_t)sig*SEQ + (size_t)c*L;
  const float* xp = yin + base;
  bool wr = (c >= lac);
  size_t ob = wr ? (base - (size_t)lac*L) : 0;
  const float* yp = yin + ob;
  float* op = outp + ob;
  float gsv = inits1[tid];
  for (int i=0;i<L;i+=4){
    float4 v = *(const float4*)(xp+i);
    float4 gf;
    gsv = fmaf(al, gsv, oma*comp_gc(v.x,th,invr,kn)); gf.x=gsv;
    gsv = fmaf(al, gsv, oma*comp_gc(v.y,th,invr,kn)); gf.y=gsv;
    gsv = fmaf(al, gsv, oma*comp_gc(v.z,th,invr,kn)); gf.z=gsv;
    gsv = fmaf(al, gsv, oma*comp_gc(v.w,th,invr,kn)); gf.w=gsv;
    if (wr){
      float4 y2 = *(const float4*)(yp+i);
      float4 o;
      o.x = y2.x * __builtin_exp2f((gf.x+mk)*C_DB) * go;
      o.y = y2.y * __builtin_exp2f((gf.y+mk)*C_DB) * go;
      o.z = y2.z * __builtin_exp2f((gf.z+mk)*C_DB) * go;
      o.w = y2.w * __builtin_exp2f((gf.w+mk)*C_DB) * go;
      *(float4*)(op+i) = o;
    }
  }
  if (c == C-1) gslast[sig] = gsv;
}

__global__ __launch_bounds__(256) void k_comptail(const float* __restrict__ yin, const float* __restrict__ gslast,
    const SigP* __restrict__ P, float* __restrict__ outp, int la)
{
  int q = blockIdx.x*256 + threadIdx.x;
  int per = la/4;
  int sig = q / per;
  int r = (q - sig*per)*4;
  int n = SEQ - la + r;
  const SigP* sp = P + sig;
  float f = __builtin_exp2f((gslast[sig]+sp->makeup)*C_DB) * sp->g_out;
  size_t base = (size_t)sig*SEQ + n;
  float4 v = *(const float4*)(yin+base);
  float4 o = { v.x*f, v.y*f, v.z*f, v.w*f };
  *(float4*)(outp+base) = o;
}

// ---------------- pan + master/fx sums ----------------
__global__ __launch_bounds__(256) void k_pan(const float* __restrict__ y, const SigP* __restrict__ P,
    float* __restrict__ panned, float* __restrict__ m0, float* __restrict__ fx)
{
  int q = blockIdx.x*256 + threadIdx.x;
  int b = q / (SEQ/4);
  int n = (q - b*(SEQ/4))*4;
  float4 aL={0,0,0,0}, aR={0,0,0,0}, fL={0,0,0,0}, fR={0,0,0,0};
  for (int t=0;t<16;t++){
    const SigP* sp = P + b*16 + t;
    float gl=sp->gl, gr=sp->gr, sd=sp->send;
    float4 v = *(const float4*)(y + (size_t)(b*16+t)*SEQ + n);
    float4 pl = { v.x*gl, v.y*gl, v.z*gl, v.w*gl };
    float4 pr = { v.x*gr, v.y*gr, v.z*gr, v.w*gr };
    *(float4*)(panned + (size_t)(b*32+t)*SEQ + n)    = pl;
    *(float4*)(panned + (size_t)(b*32+16+t)*SEQ + n) = pr;
    aL.x+=pl.x; aL.y+=pl.y; aL.z+=pl.z; aL.w+=pl.w;
    aR.x+=pr.x; aR.y+=pr.y; aR.z+=pr.z; aR.w+=pr.w;
    fL.x=fmaf(pl.x,sd,fL.x); fL.y=fmaf(pl.y,sd,fL.y); fL.z=fmaf(pl.z,sd,fL.z); fL.w=fmaf(pl.w,sd,fL.w);
    fR.x=fmaf(pr.x,sd,fR.x); fR.y=fmaf(pr.y,sd,fR.y); fR.z=fmaf(pr.z,sd,fR.z); fR.w=fmaf(pr.w,sd,fR.w);
  }
  *(float4*)(m0 + (size_t)(b*2+0)*SEQ + n) = aL;
  *(float4*)(m0 + (size_t)(b*2+1)*SEQ + n) = aR;
  *(float4*)(fx + (size_t)(b*2+0)*SEQ + n) = fL;
  *(float4*)(fx + (size_t)(b*2+1)*SEQ + n) = fR;
}

// ---------------- ir = mean over bands of filt*env*gain ----------------
__global__ __launch_bounds__(256) void k_ir(const float* __restrict__ filt, const float* __restrict__ fxp,
    float* __restrict__ ir)
{
  int q = blockIdx.x*256 + threadIdx.x;
  int sig = q / (REV_N/4);
  int i   = (q - sig*(REV_N/4))*4;
  int b = sig >> 1;
  float4 acc={0,0,0,0};
  const float ts = 1.0f/65535.0f;
  for (int band=0; band<12; band++){
    float gn  = fxp[b*25 + band];
    float dec = fxp[b*25 + 12 + band]*10.f + 1.f;
    float4 f = *(const float4*)(filt + ((size_t)(sig*12+band))*REV_N + i);
    float s = -dec*ts;
    float e0=expf(s*(float)i), e1=expf(s*(float)(i+1)), e2=expf(s*(float)(i+2)), e3=expf(s*(float)(i+3));
    acc.x = fmaf(gn*e0, f.x, acc.x);
    acc.y = fmaf(gn*e1, f.y, acc.y);
    acc.z = fmaf(gn*e2, f.z, acc.z);
    acc.w = fmaf(gn*e3, f.w, acc.w);
  }
  const float inv12 = 1.f/12.f;
  acc.x*=inv12; acc.y*=inv12; acc.z*=inv12; acc.w*=inv12;
  *(float4*)(ir + (size_t)sig*REV_N + i) = acc;
}

// ---------------- bf16 prep ----------------
__global__ __launch_bounds__(256) void k_prepx(const float* __restrict__ fx, unsigned short* __restrict__ XB)
{
  int q = blockIdx.x*256 + threadIdx.x;
  int sig = q / XBL;
  int m   = q - sig*XBL;
  int a = m - PADX;
  float v = (a >= 0 && a < SEQ) ? fx[(size_t)sig*SEQ + a] : 0.f;
  XB[(size_t)sig*XBL + m] = f2bf(v);
}
__global__ __launch_bounds__(256) void k_prepir(const float* __restrict__ ir, unsigned short* __restrict__ IRV)
{
  int q = blockIdx.x*256 + threadIdx.x;
  int sig = q / IRL;
  int m   = q - sig*IRL;
  int a = m - IRPAD;
  float v = (a >= 0 && a < REV_N) ? ir[(size_t)sig*REV_N + (REV_N-1 - a)] : 0.f;
  IRV[(size_t)sig*IRL + m] = f2bf(v);
}
__global__ __launch_bounds__(256) void k_prepn(const float* __restrict__ noise, unsigned short* __restrict__ XBN)
{
  int q = blockIdx.x*256 + threadIdx.x;
  int sig = q / XNL;
  if (sig >= 48) return;
  int m   = q - sig*XNL;
  int a = m - PADN + 1022;
  float v = (a >= 0 && a < NOISE_LEN) ? noise[(size_t)sig*NOISE_LEN + a] : 0.f;
  XBN[(size_t)sig*XNL + m] = f2bf(v);
}
__global__ __launch_bounds__(256) void k_prepfb(const float* __restrict__ fb, unsigned short* __restrict__ FBV)
{
  int q = blockIdx.x*256 + threadIdx.x;
  int band = q / FBL;
  if (band >= 12) return;
  int m = q - band*FBL;
  int a = m - FPAD;
  float v = (a >= 0 && a < TAPS) ? fb[band*TAPS + (TAPS-1 - a)] : 0.f;
  FBV[(size_t)band*FBL + m] = f2bf(v);
}

// ---------------- band FIR via MFMA ----------------
__global__ __launch_bounds__(256,3) void k_firm(const unsigned short* __restrict__ XBN,
    const unsigned short* __restrict__ FBV, float* __restrict__ filt)
{
  __shared__ alignas(16) unsigned int xs0[4640];
  __shared__ alignas(16) unsigned int xs1[4640];
  __shared__ alignas(16) unsigned short sir[3840];
  int b = blockIdx.x;                 // 384 = 8 ngrp * 48 sig
  int ng  = b & 7;
  int sig = b >> 3;
  int band = sig % 12;
  int nblk = ng << 13;
  const int sbeg = -62;
  const int send = 126;

  int tid = threadIdx.x;
  int l  = tid & 63, wv = tid >> 6;
  int lj = l & 31, lg = l >> 5, ph = l & 1;
  int hl = (lj + 8*lg - ph) >> 1;
  int offB = 32*lj - 8*lg;
  const unsigned int* xbu = (const unsigned int*)(XBN + (size_t)sig*XNL);
  const unsigned short* irg = FBV + (size_t)band*FBL;
  const unsigned int* xsel = ph ? (const unsigned int*)xs1 : (const unsigned int*)xs0;

  f32x16 acc0 = {};
  f32x16 acc1 = {};
  int n0_0 = nblk + (wv*2+0)*1024;
  int n0_1 = nblk + (wv*2+1)*1024;

  for (int sa = sbeg; sa < send; sa += 128){
    int ns = send - sa; if (ns > 128) ns = 128;
    __syncthreads();
    int clo = nblk - 16*(sa + ns - 1);
    int ub  = (PADN + clo) >> 1;
    int nd  = ((nblk + 7168 + 46 - 16*sa) - clo)/2 + 2;
    for (int d = tid; d < nd; d += 256){
      unsigned int u0 = xbu[ub + d], u1 = xbu[ub + d + 1];
      xs0[d] = u0;
      xs1[d] = (u0 >> 16) | (u1 << 16);
    }
    int amin = 1022 - 16*(sa + ns - 1) - 992;
    int irlo = ((amin - 6) & ~7) + 6;
    int irspan = (1022 - 16*sa + 15) - irlo + 1;
    for (int r = tid; r < irspan; r += 256){
      sir[pqb(r)] = irg[FPAD + irlo + r];
    }
    __syncthreads();
    int db0 = ((n0_0 - clo) >> 1) - 8*sa + hl;
    int db1 = ((n0_1 - clo) >> 1) - 8*sa + hl;
    int Dh0 = 1022 - 16*sa - irlo;
    for (int ss = 0; ss < ns; ss++){
      int rB = (Dh0 - 16*ss) - offB;
      short8v bfrag = *(const short8v*)(sir + pqb(rB));
      union { unsigned int u[4]; short8v v; } a0, a1;
      int d0 = db0 - 8*ss, d1 = db1 - 8*ss;
      a0.u[0]=xsel[d0];   a0.u[1]=xsel[d0+1]; a0.u[2]=xsel[d0+2]; a0.u[3]=xsel[d0+3];
      a1.u[0]=xsel[d1];   a1.u[1]=xsel[d1+1]; a1.u[2]=xsel[d1+2]; a1.u[3]=xsel[d1+3];
      acc0 = __builtin_amdgcn_mfma_f32_32x32x16_bf16(a0.v, bfrag, acc0, 0, 0, 0);
      acc1 = __builtin_amdgcn_mfma_f32_32x32x16_bf16(a1.v, bfrag, acc1, 0, 0, 0);
    }
  }
  float* fp = filt + (size_t)sig*REV_N;
  #pragma unroll
  for (int reg = 0; reg < 16; reg++){
    int i = (reg & 3) + 8*(reg >> 2) + 4*lg;
    fp[n0_0 + i + 32*lj] = acc0[reg];
    fp[n0_1 + i + 32*lj] = acc1[reg];
  }
}

// ---------------- wet conv via MFMA: 1 A-frag x 4 B-frags, conflict-free B pad ----------------
__global__ __launch_bounds__(256,2) void k_wetm(const unsigned short* __restrict__ XB,
    const unsigned short* __restrict__ IRV, unsigned short* __restrict__ WP)
{
  __shared__ alignas(16) unsigned int xs0[6688];
  __shared__ alignas(16) unsigned int xs1[6688];
  __shared__ alignas(16) unsigned short sir[6400];
  int b = blockIdx.x;                 // 512 = 16 ngrp * 4 sig * 8 kp
  int ng  = b & 15;
  int sig = (b >> 4) & 3;
  int kp  = b >> 6;
  int nblk = ng << 14;
  int sbeg = -254 + 544*kp;
  int send = sbeg + 544; if (send > 4097) send = 4097;

  int tid = threadIdx.x;
  int l  = tid & 63, wv = tid >> 6;
  int lj = l & 31, lg = l >> 5, ph = l & 1;
  int hl = (lj + 8*lg - ph) >> 1;
  int offB = 32*lj - 8*lg;
  const unsigned int* xbu = (const unsigned int*)(XB + (size_t)sig*XBL);
  const unsigned short* irg = IRV + (size_t)sig*IRL;
  const unsigned int* xsel = ph ? (const unsigned int*)xs1 : (const unsigned int*)xs0;

  f32x16 acc0 = {}, acc1 = {}, acc2 = {}, acc3 = {};
  int n0_w = nblk + wv*4096;

  for (int sa = sbeg; sa < send; sa += 64){
    int ns = send - sa; if (ns > 64) ns = 64;
    __syncthreads();
    int clo = nblk - 16*(sa + ns - 1);
    int ub  = (PADX + clo) >> 1;
    int nd  = (12336 + 16*(ns-1))/2 + 2;
    for (int d = tid; d < nd; d += 256){
      unsigned int u0 = xbu[ub + d], u1 = xbu[ub + d + 1];
      xs0[d] = u0;
      xs1[d] = (u0 >> 16) | (u1 << 16);
    }
    int amin = 65535 - 16*(sa + ns - 1) - 4064;
    int irlo = ((amin - 7) & ~7) + 7;
    int irspan = (65535 - 16*sa + 15) - irlo + 1;
    for (int r = tid; r < irspan; r += 256){
      sir[pqb(r)] = irg[IRPAD + irlo + r];
    }
    __syncthreads();
    int db0 = ((n0_w - clo) >> 1) - 8*sa + hl;
    int Dh0 = 65535 - 16*sa - irlo;
    for (int ss = 0; ss < ns; ss++){
      int rB = (Dh0 - 16*ss) - offB;
      int pb = pqb(rB);
      short8v bf0 = *(const short8v*)(sir + pb);
      short8v bf1 = *(const short8v*)(sir + pb - 1280);
      short8v bf2 = *(const short8v*)(sir + pb - 2560);
      short8v bf3 = *(const short8v*)(sir + pb - 3840);
      union { unsigned int u[4]; short8v v; } a0;
      int d0 = db0 - 8*ss;
      a0.u[0]=xsel[d0]; a0.u[1]=xsel[d0+1]; a0.u[2]=xsel[d0+2]; a0.u[3]=xsel[d0+3];
      acc0 = __builtin_amdgcn_mfma_f32_32x32x16_bf16(a0.v, bf0, acc0, 0, 0, 0);
      acc1 = __builtin_amdgcn_mfma_f32_32x32x16_bf16(a0.v, bf1, acc1, 0, 0, 0);
      acc2 = __builtin_amdgcn_mfma_f32_32x32x16_bf16(a0.v, bf2, acc2, 0, 0, 0);
      acc3 = __builtin_amdgcn_mfma_f32_32x32x16_bf16(a0.v, bf3, acc3, 0, 0, 0);
    }
  }
  unsigned short* wp = WP + ((size_t)(kp*4+sig))*SEQ;
  #pragma unroll
  for (int reg = 0; reg < 16; reg++){
    int i = (reg & 3) + 8*(reg >> 2) + 4*lg;
    int o = n0_w + i + 32*lj;
    wp[o]        = f2bf(acc0[reg]);
    wp[o + 1024] = f2bf(acc1[reg]);
    wp[o + 2048] = f2bf(acc2[reg]);
    wp[o + 3072] = f2bf(acc3[reg]);
  }
}

// ---------------- reduce partials + mix + add to master ----------------
__global__ __launch_bounds__(256) void k_wetred(const unsigned short* __restrict__ wp, const float* __restrict__ fx,
    const float* __restrict__ m0, const float* __restrict__ fxp, float* __restrict__ m1)
{
  int q = blockIdx.x*256 + threadIdx.x;
  int sig = q / (SEQ/4);
  int n = (q - sig*(SEQ/4))*4;
  float mix = fxp[(sig>>1)*25+24];
  size_t ob = (size_t)sig*SEQ + n;
  float s0=0.f, s1=0.f, s2=0.f, s3=0.f;
  #pragma unroll
  for (int kp=0; kp<8; kp++){
    const unsigned short* p = wp + ((size_t)(kp*4+sig))*SEQ + n;
    s0 += bf2f(p[0]); s1 += bf2f(p[1]); s2 += bf2f(p[2]); s3 += bf2f(p[3]);
  }
  float4 w0 = *(const float4*)(m0+ob);
  float4 x0 = *(const float4*)(fx+ob);
  float om = 1.f - mix;
  float4 o;
  o.x = w0.x + om*x0.x + mix*s0;
  o.y = w0.y + om*x0.y + mix*s1;
  o.z = w0.z + om*x0.z + mix*s2;
  o.w = w0.w + om*x0.w + mix*s3;
  *(float4*)(m1+ob) = o;
}

// ---------------- launch ----------------
extern "C" void kernel_launch(void* const* d_in, const int* in_sizes, int n_in,
                              void* d_out, int out_size, void* d_ws, size_t ws_size,
                              hipStream_t stream)
{
  const float* tracks = (const float*)d_in[0];
  const float* tp     = (const float*)d_in[1];
  const float* fxp    = (const float*)d_in[2];
  const float* mp     = (const float*)d_in[3];
  const float* noise  = (const float*)d_in[4];
  const float* fbp    = (const float*)d_in[5];
  float* out = (float*)d_out;
  char* w = (char*)d_ws;

  float*  X   = (float*)(w + OFF_X);
  float*  Y   = (float*)(w + OFF_Y);
  float*  FXb = (float*)(w + OFF_FX);
  float*  M0  = (float*)(w + OFF_M0);
  float*  E12 = (float*)(w + OFF_E12);
  float*  I12 = (float*)(w + OFF_I12);
  float*  E1  = (float*)(w + OFF_E1);
  float*  I1  = (float*)(w + OFF_I1);
  float*  GLt = (float*)(w + OFF_GL);
  float*  GLm = GLt + 32;
  SigP*   Pt  = (SigP*)(w + OFF_PT);
  SigP*   Pm  = (SigP*)(w + OFF_PM);
  double* aLt = (double*)(w + OFF_ALT);
  double* aLm = (double*)(w + OFF_ALM);
  float*  AT  = (float*)(w + OFF_AT);
  float*  AM  = (float*)(w + OFF_AM);
  float*  FILT= (float*)(w + OFF_FILT);
  float*  IR  = (float*)(w + OFF_IR);
  float*  XM  = (float*)(w + OFF_XM);
  float*  M1  = (float*)(w + OFF_M1);
  unsigned short* WPu = (unsigned short*)(w + OFF_WP);
  unsigned short* XB  = (unsigned short*)(w + OFF_XB);
  unsigned short* IRV = (unsigned short*)(w + OFF_IR2);
  unsigned short* XBN = (unsigned short*)(w + OFF_XBN);
  unsigned short* FBV = (unsigned short*)(w + OFF_FBV);

  k_params<<<1,64,0,stream>>>(tp, mp, Pt, Pm, AT, AM, aLt, aLm);
  k_power<<<32,64,0,stream>>>(AT, 7);   // T^128
  k_power<<<4,64,0,stream>>>(AM, 6);    // T^64

  // ---- track chain ----
  const int GT = NS_T*C_T/256;
  k_eqA12<<<GT,256,0,stream>>>(tracks, Pt, E12, C_T, L_T);
  k_scan12<<<NS_T,64,0,stream>>>(E12, I12, AT, C_T, C_T/64, 5);
  k_eqC12<<<GT,256,0,stream>>>(tracks, Y, Pt, I12, E1, C_T, L_T);
  k_scan1p<<<NS_T,64,0,stream>>>(E1, I1, aLt, C_T, C_T/64, 5);
  k_smoothcomp<<<GT,256,0,stream>>>(Y, Pt, I1, GLt, X, C_T, L_T, LA_T/L_T);
  k_comptail<<<NS_T*(LA_T/4)/256,256,0,stream>>>(Y, GLt, Pt, X, LA_T);
  k_pan<<<2*(SEQ/4)/256,256,0,stream>>>(X, Pt, out, M0, FXb);

  // ---- reverb ----
  k_prepn<<<(48*XNL+255)/256,256,0,stream>>>(noise, XBN);
  k_prepfb<<<(12*FBL+255)/256,256,0,stream>>>(fbp, FBV);
  k_firm<<<384,256,0,stream>>>(XBN, FBV, FILT);
  k_ir<<<4*(REV_N/4)/256,256,0,stream>>>(FILT, fxp, IR);
  k_prepx<<<(4*XBL)/256,256,0,stream>>>(FXb, XB);
  k_prepir<<<(4*IRL)/256,256,0,stream>>>(IR, IRV);
  k_wetm<<<512,256,0,stream>>>(XB, IRV, WPu);
  k_wetred<<<4*(SEQ/4)/256,256,0,stream>>>(WPu, FXb, M0, fxp, M1);

  // ---- master chain ----
  const int GM = NS_M*C_M/256;
  k_eqA12<<<GM,256,0,stream>>>(M1, Pm, E12, C_M, L_M);
  k_scan12<<<NS_M,64,0,stream>>>(E12, I12, AM, C_M, C_M/64, 6);
  k_eqC12<<<GM,256,0,stream>>>(M1, XM, Pm, I12, E1, C_M, L_M);
  k_scan1p<<<NS_M,64,0,stream>>>(E1, I1, aLm, C_M, C_M/64, 6);
  k_smoothcomp<<<GM,256,0,stream>>>(XM, Pm, I1, GLm, out + OUT_MASTER_OFF, C_M, L_M, LA_M/L_M);
  k_comptail<<<NS_M*(LA_M/4)/256,256,0,stream>>>(XM, GLm, Pm, out + OUT_MASTER_OFF, LA_M);
}

// Round 14
// 492.990 us; speedup vs baseline: 11.2645x; 1.0340x over previous
//
#include <hip/hip_runtime.h>

#define DEVFN __device__ __forceinline__

constexpr int SEQ = 262144;
constexpr int REV_N = 65536;
constexpr int TAPS = 1023;
constexpr int NOISE_LEN = REV_N + TAPS - 1;   // 66558

constexpr int NS_T = 32, L_T = 128, C_T = 2048;
constexpr int NS_M = 4,  L_M = 64,  C_M = 4096;
constexpr int LA_T = 2048, LA_M = 1024;

constexpr int OUT_MASTER_OFF = 16777216;

// bf16 wet-conv buffers
constexpr int PADX = 65552;
constexpr int XBL  = 327744;
constexpr int IRPAD = 4096;
constexpr int IRL  = 73728;
// bf16 fir buffers
constexpr int PADN = 2016;
constexpr int XNL  = 68640;
constexpr int FPAD = 2048;
constexpr int FBL  = 4160;

#define C_DB  0.16609640474436813f
#define C_LOG 6.0205999132796239f
#define PI_D  3.14159265358979323846

typedef __attribute__((ext_vector_type(8)))  short short8v;
typedef __attribute__((ext_vector_type(16))) float f32x16;

struct SigP {
  float g_in;
  float cb0[6], cb1[6], cb2[6], ca1[6], ca2[6];
  float alpha, oma;
  float th, invr, knee, makeup;
  float g_out;
  float gl, gr, send;
};

// ---------------- workspace layout (bytes) ----------------
constexpr size_t OFF_X   = 0;
constexpr size_t OFF_Y   = 33554432;
constexpr size_t OFF_FX  = 67108864;
constexpr size_t OFF_M0  = 71303168;
constexpr size_t OFF_FILT = OFF_X;
constexpr size_t OFF_IR   = OFF_X + 12582912;
constexpr size_t OFF_XM   = OFF_X + 16777216;
constexpr size_t OFF_M1   = OFF_Y;
constexpr size_t OFF_WP   = OFF_Y + 4194304;
constexpr size_t OFF_XB   = OFF_WP + 16777216;
constexpr size_t OFF_IR2  = OFF_XB + (size_t)4*XBL*2;
constexpr size_t OFF_XBN  = 58720256;
constexpr size_t OFF_FBV  = 65536000;
constexpr size_t OFF_E12 = OFF_FX;
constexpr size_t OFF_I12 = OFF_FX + 3145728;
constexpr size_t OFF_E1  = OFF_FX + 6291456;
constexpr size_t OFF_I1  = OFF_FX + 6553600;
constexpr size_t OFF_GL  = 75497472;
constexpr size_t OFF_PT  = OFF_GL + 1024;
constexpr size_t OFF_PM  = OFF_PT + 32*sizeof(SigP);
constexpr size_t OFF_ALT = (OFF_PM + 4*sizeof(SigP) + 7) & ~(size_t)7;
constexpr size_t OFF_ALM = OFF_ALT + 32*8;
constexpr size_t OFF_AT  = (OFF_ALM + 4*8 + 15) & ~(size_t)15;
constexpr size_t OFF_AM  = OFF_AT + 18432;

DEVFN int pq(int i){ return i + ((i >> 5) << 2); }
// B-side pad: +8 elems per 32 -> strided b128 (64B lane stride) conflict-free
DEVFN int pqb(int i){ return i + ((i >> 5) << 3); }

DEVFN unsigned short f2bf(float f){
  unsigned int u = __float_as_uint(f);
  unsigned int r = (u + 0x7fffu + ((u >> 16) & 1u)) >> 16;
  return (unsigned short)r;
}
DEVFN float bf2f(unsigned short h){ return __uint_as_float(((unsigned int)h) << 16); }

// ---------------- params kernel ----------------
DEVFN double dn(float p, double lo, double hi){ return (double)p*(hi-lo)+lo; }

__device__ void mk_sig(const float* p, int L, bool is_master,
                       SigP* sp, float* Tf, double* aL)
{
  const double flo[6] = {20.,80.,2000.,8000.,12000.,6000.};
  const double fhi[6] = {2000.,2000.,8000.,12000.,21050.,21050.};
  double gdb = dn(p[0], -48., 48.);
  sp->g_in = (float)exp2(gdb * 0.16609640474436813);
  double db0[6],db1[6],db2[6],da1[6],da2[6];
  for (int k=0;k<6;k++){
    double g  = dn(p[1+3*k], -12., 12.);
    double fc = dn(p[2+3*k], flo[k], fhi[k]);
    double q  = dn(p[3+3*k], 0.1, 5.0);
    double A  = pow(10.0, g/40.0);
    double w0 = 2.0*PI_D*(fc/44100.0);
    double al = sin(w0)/(2.0*q), co = cos(w0), sA = sqrt(A);
    double b0,b1,b2,a0,a1,a2;
    if (k==0){
      b0 = A*((A+1.0) - (A-1.0)*co + 2.0*sA*al);
      b1 = 2.0*A*((A-1.0) - (A+1.0)*co);
      b2 = A*((A+1.0) - (A-1.0)*co - 2.0*sA*al);
      a0 = (A+1.0) + (A-1.0)*co + 2.0*sA*al;
      a1 = -2.0*((A-1.0) + (A+1.0)*co);
      a2 = (A+1.0) + (A-1.0)*co - 2.0*sA*al;
    } else if (k==5){
      b0 = A*((A+1.0) + (A-1.0)*co + 2.0*sA*al);
      b1 = -2.0*A*((A-1.0) + (A+1.0)*co);
      b2 = A*((A+1.0) + (A-1.0)*co - 2.0*sA*al);
      a0 = (A+1.0) - (A-1.0)*co + 2.0*sA*al;
      a1 = 2.0*((A-1.0) - (A+1.0)*co);
      a2 = (A+1.0) - (A-1.0)*co - 2.0*sA*al;
    } else {
      b0 = 1.0 + al*A; b1 = -2.0*co; b2 = 1.0 - al*A;
      a0 = 1.0 + al/A; a1 = -2.0*co; a2 = 1.0 - al/A;
    }
    double ia0 = 1.0/a0;
    db0[k]=b0*ia0; db1[k]=b1*ia0; db2[k]=b2*ia0; da1[k]=a1*ia0; da2[k]=a2*ia0;
    sp->cb0[k]=(float)db0[k]; sp->cb1[k]=(float)db1[k]; sp->cb2[k]=(float)db2[k];
    sp->ca1[k]=(float)da1[k]; sp->ca2[k]=(float)da2[k];
  }
  for (int i=0;i<12;i++){
    double st[12]; for (int r=0;r<12;r++) st[r]=0.0; st[i]=1.0;
    double ns[12];
    double yprev=0.0, pm1=0.0, pm2=0.0;
    for (int k=0;k<6;k++){
      double yk = db0[k]*yprev + db1[k]*pm1 + db2[k]*pm2 - da1[k]*st[2*k] - da2[k]*st[2*k+1];
      ns[2*k]=yk; ns[2*k+1]=st[2*k];
      pm1=st[2*k]; pm2=st[2*k+1];
      yprev=yk;
    }
    for (int r=0;r<12;r++) Tf[r*12+i]=(float)ns[r];
  }
  double th    = dn(p[19], -60., 0.);
  double ratio = dn(p[20], 1., 10.);
  double at    = dn(p[21], 5., 250.);
  double knee  = dn(p[23], 3., 12.);
  double mkup  = dn(p[24], 0., 6.);
  double alpha = exp(-log(9.0)/(44100.0*at*0.001));
  sp->alpha=(float)alpha; sp->oma=(float)(1.0-alpha);
  sp->th=(float)th; sp->invr=(float)(1.0/ratio); sp->knee=(float)knee; sp->makeup=(float)mkup;
  *aL = pow(alpha, (double)L);
  if (is_master){
    sp->g_out = (float)exp2(dn(p[25],-48.,48.)*0.16609640474436813);
    sp->gl=0.f; sp->gr=0.f; sp->send=0.f;
  } else {
    sp->g_out = 1.f;
    sp->send = (float)exp2(dn(p[25],-80.,12.)*0.16609640474436813);
    double th2 = dn(p[26],0.,1.)*(PI_D/2.0);
    sp->gl = (float)sqrt((PI_D/2.0-th2)*(2.0/PI_D)*cos(th2));
    sp->gr = (float)sqrt(th2*(2.0/PI_D)*sin(th2));
  }
}

__global__ __launch_bounds__(64) void k_params(const float* __restrict__ tp, const float* __restrict__ mp,
    SigP* Pt, SigP* Pm, float* AT, float* AM, double* aLt, double* aLm)
{
  int i = threadIdx.x;
  if (i < 32)       mk_sig(tp + i*27, L_T, false, &Pt[i], AT + i*144, &aLt[i]);
  else if (i < 36){ int j=i-32; mk_sig(mp + (j>>1)*26, L_M, true, &Pm[j], AM + j*144, &aLm[j]); }
}

// ---------------- A <- A^(2^lg) for track (lg=7) and master (lg=6), one launch ----------------
__global__ __launch_bounds__(64) void k_power2(float* __restrict__ AT, float* __restrict__ AM)
{
  __shared__ float Ma[144], Mb[144];
  int b = blockIdx.x, t = threadIdx.x;
  float* A; int lg;
  if (b < 32){ A = AT + (size_t)b*144; lg = 7; }
  else       { A = AM + (size_t)(b-32)*144; lg = 6; }
  for (int idx=t; idx<144; idx+=64) Ma[idx]=A[idx];
  __syncthreads();
  int cur=0;
  for (int j=0;j<lg;j++){
    const float* src = cur? Mb:Ma;
    float* dst = cur? Ma:Mb;
    for (int idx=t; idx<144; idx+=64){
      int r=idx/12, cc=idx-r*12;
      float v=0.f;
      #pragma unroll
      for (int m=0;m<12;m++) v = fmaf(src[r*12+m], src[m*12+cc], v);
      dst[idx]=v;
    }
    __syncthreads();
    cur^=1;
  }
  const float* fin = cur? Mb:Ma;
  for (int idx=t; idx<144; idx+=64) A[idx]=fin[idx];
}

DEVFN float comp_gc(float y, float th, float invr, float kn){
  float av  = fmaxf(fabsf(y), 1e-8f);
  float xdb = C_LOG * __builtin_log2f(av);
  float d   = xdb - th;
  float w = (2.f*d < -kn) ? 0.f
          : ((2.f*fabsf(d) <= kn) ? (d+0.5f*kn)*(d+0.5f*kn)/(2.f*kn) : d);
  return (invr-1.f)*w;
}

// ---------------- A-pass ----------------
__global__ __launch_bounds__(256) void k_eqA12(const float* __restrict__ in, const SigP* __restrict__ P,
    float* __restrict__ E12, int C, int L)
{
  int tid = blockIdx.x*256 + threadIdx.x;
  int sig = tid / C, c = tid - sig*C;
  const SigP* sp = P + sig;
  float B0[6],B1[6],B2[6],A1[6],A2[6];
  float g = sp->g_in;
  #pragma unroll
  for (int k=0;k<6;k++){
    float gg = (k==0)? g : 1.f;
    B0[k]=sp->cb0[k]*gg; B1[k]=sp->cb1[k]*gg; B2[k]=sp->cb2[k]*gg;
    A1[k]=sp->ca1[k];    A2[k]=sp->ca2[k];
  }
  const float* xp = in + (size_t)sig*SEQ + (size_t)c*L;
  float xm1=0.f, xm2=0.f;
  if (c){ xm1=xp[-1]; xm2=xp[-2]; }
  float s[12];
  #pragma unroll
  for (int r=0;r<12;r++) s[r]=0.f;
  for (int i=0;i<L;i+=4){
    float4 v = *(const float4*)(xp+i);
    #pragma unroll
    for (int u4=0;u4<4;u4++){
      float u = (u4==0)?v.x:(u4==1)?v.y:(u4==2)?v.z:v.w;
      float yprev=u, pm1=xm1, pm2=xm2;
      float ny[6];
      #pragma unroll
      for (int k=0;k<6;k++){
        float t0 = fmaf(B0[k],yprev, fmaf(B1[k],pm1, fmaf(B2[k],pm2, -A2[k]*s[2*k+1])));
        float yk = fmaf(-A1[k], s[2*k], t0);
        ny[k]=yk;
        pm1=s[2*k]; pm2=s[2*k+1];
        yprev=yk;
      }
      #pragma unroll
      for (int k=0;k<6;k++){ s[2*k+1]=s[2*k]; s[2*k]=ny[k]; }
      xm2=xm1; xm1=u;
    }
  }
  float* ep = E12 + (size_t)tid*12;
  #pragma unroll
  for (int r=0;r<12;r++) ep[r]=s[r];
}

// ---------------- 12-state affine scan ----------------
__global__ __launch_bounds__(64) void k_scan12(const float* __restrict__ E, float* __restrict__ I,
    const float* __restrict__ Ab, int C, int Q, int lgQ)
{
  __shared__ float As[144], Pa[144], Pb[144];
  __shared__ float seg[64][12], ini[64][12];
  __shared__ float scur[12], stmp[12];
  int sig = blockIdx.x, t = threadIdx.x;
  const float* Asig = Ab + (size_t)sig*144;
  for (int idx=t; idx<144; idx+=64) As[idx]=Asig[idx];
  __syncthreads();
  const float* dp = E + ((size_t)sig*C + (size_t)t*Q)*12;
  float s[12];
  #pragma unroll
  for (int r=0;r<12;r++) s[r]=0.f;
  for (int j=0;j<Q;j++){
    const float* d = dp + j*12;
    float ns[12];
    #pragma unroll
    for (int r=0;r<12;r++){
      float v = d[r];
      #pragma unroll
      for (int cc=0;cc<12;cc++) v = fmaf(As[r*12+cc], s[cc], v);
      ns[r]=v;
    }
    #pragma unroll
    for (int r=0;r<12;r++) s[r]=ns[r];
  }
  #pragma unroll
  for (int r=0;r<12;r++) seg[t][r]=s[r];
  for (int idx=t; idx<144; idx+=64) Pa[idx]=As[idx];
  __syncthreads();
  int cur=0;
  for (int j=0;j<lgQ;j++){
    const float* src = cur? Pb:Pa;
    float* dst = cur? Pa:Pb;
    for (int idx=t; idx<144; idx+=64){
      int r=idx/12, cc=idx-r*12;
      float v=0.f;
      #pragma unroll
      for (int m=0;m<12;m++) v = fmaf(src[r*12+m], src[m*12+cc], v);
      dst[idx]=v;
    }
    __syncthreads();
    cur^=1;
  }
  const float* AQ = cur? Pb:Pa;
  if (t<12) scur[t]=0.f;
  __syncthreads();
  for (int u=0;u<64;u++){
    if (t<12){
      ini[u][t]=scur[t];
      float v = seg[u][t];
      #pragma unroll
      for (int cc=0;cc<12;cc++) v = fmaf(AQ[t*12+cc], scur[cc], v);
      stmp[t]=v;
    }
    __syncthreads();
    if (t<12) scur[t]=stmp[t];
    __syncthreads();
  }
  #pragma unroll
  for (int r=0;r<12;r++) s[r]=ini[t][r];
  float* op = I + ((size_t)sig*C + (size_t)t*Q)*12;
  for (int j=0;j<Q;j++){
    float* o = op + j*12;
    #pragma unroll
    for (int r=0;r<12;r++) o[r]=s[r];
    const float* d = dp + j*12;
    float ns[12];
    #pragma unroll
    for (int r=0;r<12;r++){
      float v = d[r];
      #pragma unroll
      for (int cc=0;cc<12;cc++) v = fmaf(As[r*12+cc], s[cc], v);
      ns[r]=v;
    }
    #pragma unroll
    for (int r=0;r<12;r++) s[r]=ns[r];
  }
}

// ---------------- 1-state scan ----------------
__global__ __launch_bounds__(64) void k_scan1p(const float* __restrict__ endst, float* __restrict__ inits,
    const double* __restrict__ aL, int C, int Q, int lgQ)
{
  __shared__ double ag[64], ins[64];
  int sig = blockIdx.x; int t = threadIdx.x;
  double a = aL[sig];
  const float* dp = endst + (size_t)sig*C + (size_t)t*Q;
  double e=0.0;
  for (int j=0;j<Q;j++) e = a*e + (double)dp[j];
  ag[t]=e;
  __syncthreads();
  if (t == 0){
    double p=a;
    for (int j=0;j<lgQ;j++) p = p*p;
    double s=0.0;
    for (int u=0;u<64;u++){
      ins[u]=s;
      s = p*s + ag[u];
    }
  }
  __syncthreads();
  double s = ins[t];
  float* op = inits + (size_t)sig*C + (size_t)t*Q;
  for (int j=0;j<Q;j++){ op[j]=(float)s; s = a*s + (double)dp[j]; }
}

// ---------------- C-pass ----------------
__global__ __launch_bounds__(256) void k_eqC12(const float* __restrict__ in, float* __restrict__ yout,
    const SigP* __restrict__ P, const float* __restrict__ I12, float* __restrict__ E1, int C, int L)
{
  int tid = blockIdx.x*256 + threadIdx.x;
  int sig = tid / C, c = tid - sig*C;
  const SigP* sp = P + sig;
  float B0[6],B1[6],B2[6],A1[6],A2[6];
  float g = sp->g_in;
  #pragma unroll
  for (int k=0;k<6;k++){
    float gg = (k==0)? g : 1.f;
    B0[k]=sp->cb0[k]*gg; B1[k]=sp->cb1[k]*gg; B2[k]=sp->cb2[k]*gg;
    A1[k]=sp->ca1[k];    A2[k]=sp->ca2[k];
  }
  float al=sp->alpha, oma=sp->oma, th=sp->th, invr=sp->invr, kn=sp->knee;
  size_t base = (size_t)sig*SEQ + (size_t)c*L;
  const float* xp = in + base;
  float* op = yout + base;
  float xm1=0.f, xm2=0.f;
  if (c){ xm1=xp[-1]; xm2=xp[-2]; }
  const float* ip = I12 + (size_t)tid*12;
  float s[12];
  #pragma unroll
  for (int r=0;r<12;r++) s[r]=ip[r];
  float gacc=0.f;
  for (int i=0;i<L;i+=4){
    float4 v = *(const float4*)(xp+i);
    float4 o;
    #pragma unroll
    for (int u4=0;u4<4;u4++){
      float u = (u4==0)?v.x:(u4==1)?v.y:(u4==2)?v.z:v.w;
      float yprev=u, pm1=xm1, pm2=xm2;
      float ny[6];
      #pragma unroll
      for (int k=0;k<6;k++){
        float t0 = fmaf(B0[k],yprev, fmaf(B1[k],pm1, fmaf(B2[k],pm2, -A2[k]*s[2*k+1])));
        float yk = fmaf(-A1[k], s[2*k], t0);
        ny[k]=yk;
        pm1=s[2*k]; pm2=s[2*k+1];
        yprev=yk;
      }
      #pragma unroll
      for (int k=0;k<6;k++){ s[2*k+1]=s[2*k]; s[2*k]=ny[k]; }
      xm2=xm1; xm1=u;
      float y5 = ny[5];
      if (u4==0) o.x=y5; else if (u4==1) o.y=y5; else if (u4==2) o.z=y5; else o.w=y5;
      gacc = fmaf(al, gacc, oma*comp_gc(y5,th,invr,kn));
    }
    *(float4*)(op+i) = o;
  }
  E1[tid]=gacc;
}

// ---------------- fused smoother + compressor apply ----------------
__global__ __launch_bounds__(256) void k_smoothcomp(const float* __restrict__ yin,
    const SigP* __restrict__ P, const float* __restrict__ inits1, float* __restrict__ gslast,
    float* __restrict__ outp, int C, int L, int lac)
{
  int tid = blockIdx.x*256 + threadIdx.x;
  int sig = tid / C, c = tid - sig*C;
  const SigP* sp = P + sig;
  float al=sp->alpha, oma=sp->oma, th=sp->th, invr=sp->invr, kn=sp->knee;
  float mk=sp->makeup, go=sp->g_out;
  size_t base = (size_t)sig*SEQ + (size_t)c*L;
  const float* xp = yin + base;
  bool wr = (c >= lac);
  size_t ob = wr ? (base - (size_t)lac*L) : 0;
  const float* yp = yin + ob;
  float* op = outp + ob;
  float gsv = inits1[tid];
  for (int i=0;i<L;i+=4){
    float4 v = *(const float4*)(xp+i);
    float4 gf;
    gsv = fmaf(al, gsv, oma*comp_gc(v.x,th,invr,kn)); gf.x=gsv;
    gsv = fmaf(al, gsv, oma*comp_gc(v.y,th,invr,kn)); gf.y=gsv;
    gsv = fmaf(al, gsv, oma*comp_gc(v.z,th,invr,kn)); gf.z=gsv;
    gsv = fmaf(al, gsv, oma*comp_gc(v.w,th,invr,kn)); gf.w=gsv;
    if (wr){
      float4 y2 = *(const float4*)(yp+i);
      float4 o;
      o.x = y2.x * __builtin_exp2f((gf.x+mk)*C_DB) * go;
      o.y = y2.y * __builtin_exp2f((gf.y+mk)*C_DB) * go;
      o.z = y2.z * __builtin_exp2f((gf.z+mk)*C_DB) * go;
      o.w = y2.w * __builtin_exp2f((gf.w+mk)*C_DB) * go;
      *(float4*)(op+i) = o;
    }
  }
  if (c == C-1) gslast[sig] = gsv;
}

__global__ __launch_bounds__(256) void k_comptail(const float* __restrict__ yin, const float* __restrict__ gslast,
    const SigP* __restrict__ P, float* __restrict__ outp, int la)
{
  int q = blockIdx.x*256 + threadIdx.x;
  int per = la/4;
  int sig = q / per;
  int r = (q - sig*per)*4;
  int n = SEQ - la + r;
  const SigP* sp = P + sig;
  float f = __builtin_exp2f((gslast[sig]+sp->makeup)*C_DB) * sp->g_out;
  size_t base = (size_t)sig*SEQ + n;
  float4 v = *(const float4*)(yin+base);
  float4 o = { v.x*f, v.y*f, v.z*f, v.w*f };
  *(float4*)(outp+base) = o;
}

// ---------------- pan + master/fx sums ----------------
__global__ __launch_bounds__(256) void k_pan(const float* __restrict__ y, const SigP* __restrict__ P,
    float* __restrict__ panned, float* __restrict__ m0, float* __restrict__ fx)
{
  int q = blockIdx.x*256 + threadIdx.x;
  int b = q / (SEQ/4);
  int n = (q - b*(SEQ/4))*4;
  float4 aL={0,0,0,0}, aR={0,0,0,0}, fL={0,0,0,0}, fR={0,0,0,0};
  for (int t=0;t<16;t++){
    const SigP* sp = P + b*16 + t;
    float gl=sp->gl, gr=sp->gr, sd=sp->send;
    float4 v = *(const float4*)(y + (size_t)(b*16+t)*SEQ + n);
    float4 pl = { v.x*gl, v.y*gl, v.z*gl, v.w*gl };
    float4 pr = { v.x*gr, v.y*gr, v.z*gr, v.w*gr };
    *(float4*)(panned + (size_t)(b*32+t)*SEQ + n)    = pl;
    *(float4*)(panned + (size_t)(b*32+16+t)*SEQ + n) = pr;
    aL.x+=pl.x; aL.y+=pl.y; aL.z+=pl.z; aL.w+=pl.w;
    aR.x+=pr.x; aR.y+=pr.y; aR.z+=pr.z; aR.w+=pr.w;
    fL.x=fmaf(pl.x,sd,fL.x); fL.y=fmaf(pl.y,sd,fL.y); fL.z=fmaf(pl.z,sd,fL.z); fL.w=fmaf(pl.w,sd,fL.w);
    fR.x=fmaf(pr.x,sd,fR.x); fR.y=fmaf(pr.y,sd,fR.y); fR.z=fmaf(pr.z,sd,fR.z); fR.w=fmaf(pr.w,sd,fR.w);
  }
  *(float4*)(m0 + (size_t)(b*2+0)*SEQ + n) = aL;
  *(float4*)(m0 + (size_t)(b*2+1)*SEQ + n) = aR;
  *(float4*)(fx + (size_t)(b*2+0)*SEQ + n) = fL;
  *(float4*)(fx + (size_t)(b*2+1)*SEQ + n) = fR;
}

// ---------------- ir + fused reversed/padded bf16 IRV ----------------
__global__ __launch_bounds__(256) void k_ir2(const float* __restrict__ filt, const float* __restrict__ fxp,
    float* __restrict__ ir, unsigned short* __restrict__ IRV)
{
  int q = blockIdx.x*256 + threadIdx.x;
  int sig = q / (REV_N/4);
  int idx = q - sig*(REV_N/4);
  int i   = idx*4;
  int b = sig >> 1;
  float4 acc={0,0,0,0};
  const float ts = 1.0f/65535.0f;
  for (int band=0; band<12; band++){
    float gn  = fxp[b*25 + band];
    float dec = fxp[b*25 + 12 + band]*10.f + 1.f;
    float4 f = *(const float4*)(filt + ((size_t)(sig*12+band))*REV_N + i);
    float s = -dec*ts;
    float e0=expf(s*(float)i), e1=expf(s*(float)(i+1)), e2=expf(s*(float)(i+2)), e3=expf(s*(float)(i+3));
    acc.x = fmaf(gn*e0, f.x, acc.x);
    acc.y = fmaf(gn*e1, f.y, acc.y);
    acc.z = fmaf(gn*e2, f.z, acc.z);
    acc.w = fmaf(gn*e3, f.w, acc.w);
  }
  const float inv12 = 1.f/12.f;
  acc.x*=inv12; acc.y*=inv12; acc.z*=inv12; acc.w*=inv12;
  *(float4*)(ir + (size_t)sig*REV_N + i) = acc;
  // reversed + padded bf16 copy: IRV[IRPAD + (REV_N-1 - a)] = ir[a]
  unsigned short* iv = IRV + (size_t)sig*IRL;
  int base = IRPAD + REV_N-1 - i;
  iv[base]   = f2bf(acc.x);
  iv[base-1] = f2bf(acc.y);
  iv[base-2] = f2bf(acc.z);
  iv[base-3] = f2bf(acc.w);
  // zero pads: front [0,IRPAD), tail [IRPAD+REV_N, IRL)
  if (idx < 1024){
    *(ushort4*)(iv + idx*4) = make_ushort4(0,0,0,0);
  } else if (idx < 2048){
    *(ushort4*)(iv + IRPAD + REV_N + (idx-1024)*4) = make_ushort4(0,0,0,0);
  }
}

// ---------------- combined bf16 prep: XB (fx), XBN (noise), FBV (fb) ----------------
constexpr int P3_XB  = 4*XBL;             // 1,310,976
constexpr int P3_XBN = 48*XNL;            // 3,294,720
constexpr int P3_TOT = P3_XB + P3_XBN + 12*FBL;
__global__ __launch_bounds__(256) void k_prep3(const float* __restrict__ fx, const float* __restrict__ noise,
    const float* __restrict__ fb, unsigned short* __restrict__ XB, unsigned short* __restrict__ XBN,
    unsigned short* __restrict__ FBV)
{
  int q = blockIdx.x*256 + threadIdx.x;
  if (q < P3_XB){
    int sig = q / XBL;
    int m   = q - sig*XBL;
    int a = m - PADX;
    float v = (a >= 0 && a < SEQ) ? fx[(size_t)sig*SEQ + a] : 0.f;
    XB[(size_t)sig*XBL + m] = f2bf(v);
  } else if (q < P3_XB + P3_XBN){
    int q2 = q - P3_XB;
    int sig = q2 / XNL;
    int m   = q2 - sig*XNL;
    int a = m - PADN + 1022;
    float v = (a >= 0 && a < NOISE_LEN) ? noise[(size_t)sig*NOISE_LEN + a] : 0.f;
    XBN[(size_t)sig*XNL + m] = f2bf(v);
  } else if (q < P3_TOT){
    int q3 = q - P3_XB - P3_XBN;
    int band = q3 / FBL;
    int m = q3 - band*FBL;
    int a = m - FPAD;
    float v = (a >= 0 && a < TAPS) ? fb[band*TAPS + (TAPS-1 - a)] : 0.f;
    FBV[(size_t)band*FBL + m] = f2bf(v);
  }
}

// ---------------- band FIR via MFMA ----------------
__global__ __launch_bounds__(256,3) void k_firm(const unsigned short* __restrict__ XBN,
    const unsigned short* __restrict__ FBV, float* __restrict__ filt)
{
  __shared__ alignas(16) unsigned int xs0[4640];
  __shared__ alignas(16) unsigned int xs1[4640];
  __shared__ alignas(16) unsigned short sir[3840];
  int b = blockIdx.x;                 // 384 = 8 ngrp * 48 sig
  int ng  = b & 7;
  int sig = b >> 3;
  int band = sig % 12;
  int nblk = ng << 13;
  const int sbeg = -62;
  const int send = 126;

  int tid = threadIdx.x;
  int l  = tid & 63, wv = tid >> 6;
  int lj = l & 31, lg = l >> 5, ph = l & 1;
  int hl = (lj + 8*lg - ph) >> 1;
  int offB = 32*lj - 8*lg;
  const unsigned int* xbu = (const unsigned int*)(XBN + (size_t)sig*XNL);
  const unsigned short* irg = FBV + (size_t)band*FBL;
  const unsigned int* xsel = ph ? (const unsigned int*)xs1 : (const unsigned int*)xs0;

  f32x16 acc0 = {};
  f32x16 acc1 = {};
  int n0_0 = nblk + (wv*2+0)*1024;
  int n0_1 = nblk + (wv*2+1)*1024;

  for (int sa = sbeg; sa < send; sa += 128){
    int ns = send - sa; if (ns > 128) ns = 128;
    __syncthreads();
    int clo = nblk - 16*(sa + ns - 1);
    int ub  = (PADN + clo) >> 1;
    int nd  = ((nblk + 7168 + 46 - 16*sa) - clo)/2 + 2;
    for (int d = tid; d < nd; d += 256){
      unsigned int u0 = xbu[ub + d], u1 = xbu[ub + d + 1];
      xs0[d] = u0;
      xs1[d] = (u0 >> 16) | (u1 << 16);
    }
    int amin = 1022 - 16*(sa + ns - 1) - 992;
    int irlo = ((amin - 6) & ~7) + 6;
    int irspan = (1022 - 16*sa + 15) - irlo + 1;
    for (int r = tid; r < irspan; r += 256){
      sir[pqb(r)] = irg[FPAD + irlo + r];
    }
    __syncthreads();
    int db0 = ((n0_0 - clo) >> 1) - 8*sa + hl;
    int db1 = ((n0_1 - clo) >> 1) - 8*sa + hl;
    int Dh0 = 1022 - 16*sa - irlo;
    for (int ss = 0; ss < ns; ss++){
      int rB = (Dh0 - 16*ss) - offB;
      short8v bfrag = *(const short8v*)(sir + pqb(rB));
      union { unsigned int u[4]; short8v v; } a0, a1;
      int d0 = db0 - 8*ss, d1 = db1 - 8*ss;
      a0.u[0]=xsel[d0];   a0.u[1]=xsel[d0+1]; a0.u[2]=xsel[d0+2]; a0.u[3]=xsel[d0+3];
      a1.u[0]=xsel[d1];   a1.u[1]=xsel[d1+1]; a1.u[2]=xsel[d1+2]; a1.u[3]=xsel[d1+3];
      acc0 = __builtin_amdgcn_mfma_f32_32x32x16_bf16(a0.v, bfrag, acc0, 0, 0, 0);
      acc1 = __builtin_amdgcn_mfma_f32_32x32x16_bf16(a1.v, bfrag, acc1, 0, 0, 0);
    }
  }
  float* fp = filt + (size_t)sig*REV_N;
  #pragma unroll
  for (int reg = 0; reg < 16; reg++){
    int i = (reg & 3) + 8*(reg >> 2) + 4*lg;
    fp[n0_0 + i + 32*lj] = acc0[reg];
    fp[n0_1 + i + 32*lj] = acc1[reg];
  }
}

// ---------------- wet conv via MFMA: 1 A-frag x 4 B-frags, ns=128 batches ----------------
__global__ __launch_bounds__(256,2) void k_wetm(const unsigned short* __restrict__ XB,
    const unsigned short* __restrict__ IRV, unsigned short* __restrict__ WP)
{
  __shared__ alignas(16) unsigned int xs0[7200];
  __shared__ alignas(16) unsigned int xs1[7200];
  __shared__ alignas(16) unsigned short sir[7680];
  int b = blockIdx.x;                 // 512 = 16 ngrp * 4 sig * 8 kp
  int ng  = b & 15;
  int sig = (b >> 4) & 3;
  int kp  = b >> 6;
  int nblk = ng << 14;
  int sbeg = -254 + 544*kp;
  int send = sbeg + 544; if (send > 4097) send = 4097;

  int tid = threadIdx.x;
  int l  = tid & 63, wv = tid >> 6;
  int lj = l & 31, lg = l >> 5, ph = l & 1;
  int hl = (lj + 8*lg - ph) >> 1;
  int offB = 32*lj - 8*lg;
  const unsigned int* xbu = (const unsigned int*)(XB + (size_t)sig*XBL);
  const unsigned short* irg = IRV + (size_t)sig*IRL;
  const unsigned int* xsel = ph ? (const unsigned int*)xs1 : (const unsigned int*)xs0;

  f32x16 acc0 = {}, acc1 = {}, acc2 = {}, acc3 = {};
  int n0_w = nblk + wv*4096;

  for (int sa = sbeg; sa < send; sa += 128){
    int ns = send - sa; if (ns > 128) ns = 128;
    __syncthreads();
    int clo = nblk - 16*(sa + ns - 1);
    int ub  = (PADX + clo) >> 1;
    int nd  = (12336 + 16*(ns-1))/2 + 2;
    for (int d = tid; d < nd; d += 256){
      unsigned int u0 = xbu[ub + d], u1 = xbu[ub + d + 1];
      xs0[d] = u0;
      xs1[d] = (u0 >> 16) | (u1 << 16);
    }
    int amin = 65535 - 16*(sa + ns - 1) - 4064;
    int irlo = ((amin - 7) & ~7) + 7;
    int irspan = (65535 - 16*sa + 15) - irlo + 1;
    for (int r = tid; r < irspan; r += 256){
      sir[pqb(r)] = irg[IRPAD + irlo + r];
    }
    __syncthreads();
    int db0 = ((n0_w - clo) >> 1) - 8*sa + hl;
    int Dh0 = 65535 - 16*sa - irlo;
    for (int ss = 0; ss < ns; ss++){
      int rB = (Dh0 - 16*ss) - offB;
      int pb = pqb(rB);
      short8v bf0 = *(const short8v*)(sir + pb);
      short8v bf1 = *(const short8v*)(sir + pb - 1280);
      short8v bf2 = *(const short8v*)(sir + pb - 2560);
      short8v bf3 = *(const short8v*)(sir + pb - 3840);
      union { unsigned int u[4]; short8v v; } a0;
      int d0 = db0 - 8*ss;
      a0.u[0]=xsel[d0]; a0.u[1]=xsel[d0+1]; a0.u[2]=xsel[d0+2]; a0.u[3]=xsel[d0+3];
      acc0 = __builtin_amdgcn_mfma_f32_32x32x16_bf16(a0.v, bf0, acc0, 0, 0, 0);
      acc1 = __builtin_amdgcn_mfma_f32_32x32x16_bf16(a0.v, bf1, acc1, 0, 0, 0);
      acc2 = __builtin_amdgcn_mfma_f32_32x32x16_bf16(a0.v, bf2, acc2, 0, 0, 0);
      acc3 = __builtin_amdgcn_mfma_f32_32x32x16_bf16(a0.v, bf3, acc3, 0, 0, 0);
    }
  }
  unsigned short* wp = WP + ((size_t)(kp*4+sig))*SEQ;
  #pragma unroll
  for (int reg = 0; reg < 16; reg++){
    int i = (reg & 3) + 8*(reg >> 2) + 4*lg;
    int o = n0_w + i + 32*lj;
    wp[o]        = f2bf(acc0[reg]);
    wp[o + 1024] = f2bf(acc1[reg]);
    wp[o + 2048] = f2bf(acc2[reg]);
    wp[o + 3072] = f2bf(acc3[reg]);
  }
}

// ---------------- reduce partials + mix + add to master ----------------
__global__ __launch_bounds__(256) void k_wetred(const unsigned short* __restrict__ wp, const float* __restrict__ fx,
    const float* __restrict__ m0, const float* __restrict__ fxp, float* __restrict__ m1)
{
  int q = blockIdx.x*256 + threadIdx.x;
  int sig = q / (SEQ/4);
  int n = (q - sig*(SEQ/4))*4;
  float mix = fxp[(sig>>1)*25+24];
  size_t ob = (size_t)sig*SEQ + n;
  float s0=0.f, s1=0.f, s2=0.f, s3=0.f;
  #pragma unroll
  for (int kp=0; kp<8; kp++){
    const unsigned short* p = wp + ((size_t)(kp*4+sig))*SEQ + n;
    s0 += bf2f(p[0]); s1 += bf2f(p[1]); s2 += bf2f(p[2]); s3 += bf2f(p[3]);
  }
  float4 w0 = *(const float4*)(m0+ob);
  float4 x0 = *(const float4*)(fx+ob);
  float om = 1.f - mix;
  float4 o;
  o.x = w0.x + om*x0.x + mix*s0;
  o.y = w0.y + om*x0.y + mix*s1;
  o.z = w0.z + om*x0.z + mix*s2;
  o.w = w0.w + om*x0.w + mix*s3;
  *(float4*)(m1+ob) = o;
}

// ---------------- launch ----------------
extern "C" void kernel_launch(void* const* d_in, const int* in_sizes, int n_in,
                              void* d_out, int out_size, void* d_ws, size_t ws_size,
                              hipStream_t stream)
{
  const float* tracks = (const float*)d_in[0];
  const float* tp     = (const float*)d_in[1];
  const float* fxp    = (const float*)d_in[2];
  const float* mp     = (const float*)d_in[3];
  const float* noise  = (const float*)d_in[4];
  const float* fbp    = (const float*)d_in[5];
  float* out = (float*)d_out;
  char* w = (char*)d_ws;

  float*  X   = (float*)(w + OFF_X);
  float*  Y   = (float*)(w + OFF_Y);
  float*  FXb = (float*)(w + OFF_FX);
  float*  M0  = (float*)(w + OFF_M0);
  float*  E12 = (float*)(w + OFF_E12);
  float*  I12 = (float*)(w + OFF_I12);
  float*  E1  = (float*)(w + OFF_E1);
  float*  I1  = (float*)(w + OFF_I1);
  float*  GLt = (float*)(w + OFF_GL);
  float*  GLm = GLt + 32;
  SigP*   Pt  = (SigP*)(w + OFF_PT);
  SigP*   Pm  = (SigP*)(w + OFF_PM);
  double* aLt = (double*)(w + OFF_ALT);
  double* aLm = (double*)(w + OFF_ALM);
  float*  AT  = (float*)(w + OFF_AT);
  float*  AM  = (float*)(w + OFF_AM);
  float*  FILT= (float*)(w + OFF_FILT);
  float*  IR  = (float*)(w + OFF_IR);
  float*  XM  = (float*)(w + OFF_XM);
  float*  M1  = (float*)(w + OFF_M1);
  unsigned short* WPu = (unsigned short*)(w + OFF_WP);
  unsigned short* XB  = (unsigned short*)(w + OFF_XB);
  unsigned short* IRV = (unsigned short*)(w + OFF_IR2);
  unsigned short* XBN = (unsigned short*)(w + OFF_XBN);
  unsigned short* FBV = (unsigned short*)(w + OFF_FBV);

  k_params<<<1,64,0,stream>>>(tp, mp, Pt, Pm, AT, AM, aLt, aLm);
  k_power2<<<36,64,0,stream>>>(AT, AM);

  // ---- track chain ----
  const int GT = NS_T*C_T/256;
  k_eqA12<<<GT,256,0,stream>>>(tracks, Pt, E12, C_T, L_T);
  k_scan12<<<NS_T,64,0,stream>>>(E12, I12, AT, C_T, C_T/64, 5);
  k_eqC12<<<GT,256,0,stream>>>(tracks, Y, Pt, I12, E1, C_T, L_T);
  k_scan1p<<<NS_T,64,0,stream>>>(E1, I1, aLt, C_T, C_T/64, 5);
  k_smoothcomp<<<GT,256,0,stream>>>(Y, Pt, I1, GLt, X, C_T, L_T, LA_T/L_T);
  k_comptail<<<NS_T*(LA_T/4)/256,256,0,stream>>>(Y, GLt, Pt, X, LA_T);
  k_pan<<<2*(SEQ/4)/256,256,0,stream>>>(X, Pt, out, M0, FXb);

  // ---- reverb ----
  k_prep3<<<(P3_TOT+255)/256,256,0,stream>>>(FXb, noise, fbp, XB, XBN, FBV);
  k_firm<<<384,256,0,stream>>>(XBN, FBV, FILT);
  k_ir2<<<4*(REV_N/4)/256,256,0,stream>>>(FILT, fxp, IR, IRV);
  k_wetm<<<512,256,0,stream>>>(XB, IRV, WPu);
  k_wetred<<<4*(SEQ/4)/256,256,0,stream>>>(WPu, FXb, M0, fxp, M1);

  // ---- master chain ----
  const int GM = NS_M*C_M/256;
  k_eqA12<<<GM,256,0,stream>>>(M1, Pm, E12, C_M, L_M);
  k_scan12<<<NS_M,64,0,stream>>>(E12, I12, AM, C_M, C_M/64, 6);
  k_eqC12<<<GM,256,0,stream>>>(M1, XM, Pm, I12, E1, C_M, L_M);
  k_scan1p<<<NS_M,64,0,stream>>>(E1, I1, aLm, C_M, C_M/64, 6);
  k_smoothcomp<<<GM,256,0,stream>>>(XM, Pm, I1, GLm, out + OUT_MASTER_OFF, C_M, L_M, LA_M/L_M);
  k_comptail<<<NS_M*(LA_M/4)/256,256,0,stream>>>(XM, GLm, Pm, out + OUT_MASTER_OFF, LA_M);
}

// Round 15
// 456.100 us; speedup vs baseline: 12.1756x; 1.0809x over previous
//
#include <hip/hip_runtime.h>

#define DEVFN __device__ __forceinline__

constexpr int SEQ = 262144;
constexpr int REV_N = 65536;
constexpr int TAPS = 1023;
constexpr int NOISE_LEN = REV_N + TAPS - 1;   // 66558

constexpr int NS_T = 32, L_T = 128, C_T = 2048;
constexpr int NS_M = 4,  L_M = 64,  C_M = 4096;
constexpr int LA_T = 2048, LA_M = 1024;

constexpr int OUT_MASTER_OFF = 16777216;

// bf16 wet-conv buffers
constexpr int PADX = 65552;
constexpr int XBL  = 327744;
constexpr int IRPAD = 4096;
constexpr int IRL  = 73728;
// bf16 fir buffers
constexpr int PADN = 2016;
constexpr int XNL  = 68640;
constexpr int FPAD = 2048;
constexpr int FBL  = 4160;

#define C_DB  0.16609640474436813f
#define C_LOG 6.0205999132796239f
#define PI_D  3.14159265358979323846

typedef __attribute__((ext_vector_type(8)))  short short8v;
typedef __attribute__((ext_vector_type(16))) float f32x16;

struct SigP {
  float g_in;
  float cb0[6], cb1[6], cb2[6], ca1[6], ca2[6];
  float alpha, oma;
  float th, invr, knee, makeup;
  float g_out;
  float gl, gr, send;
};

// ---------------- workspace layout (bytes) ----------------
constexpr size_t OFF_X   = 0;
constexpr size_t OFF_Y   = 33554432;
constexpr size_t OFF_FX  = 67108864;
constexpr size_t OFF_M0  = 71303168;
constexpr size_t OFF_FILT = OFF_X;
constexpr size_t OFF_IR   = OFF_X + 12582912;
constexpr size_t OFF_XM   = OFF_X + 16777216;
constexpr size_t OFF_M1   = OFF_Y;
constexpr size_t OFF_WP   = OFF_Y + 4194304;
constexpr size_t OFF_XB   = OFF_WP + 16777216;
constexpr size_t OFF_IR2  = OFF_XB + (size_t)4*XBL*2;
constexpr size_t OFF_XBN  = 58720256;
constexpr size_t OFF_FBV  = 65536000;
constexpr size_t OFF_E12 = OFF_FX;
constexpr size_t OFF_I12 = OFF_FX + 3145728;
constexpr size_t OFF_E1  = OFF_FX + 6291456;
constexpr size_t OFF_I1  = OFF_FX + 6553600;
constexpr size_t OFF_GL  = 75497472;
constexpr size_t OFF_PT  = OFF_GL + 1024;
constexpr size_t OFF_PM  = OFF_PT + 32*sizeof(SigP);
constexpr size_t OFF_ALT = (OFF_PM + 4*sizeof(SigP) + 7) & ~(size_t)7;
constexpr size_t OFF_ALM = OFF_ALT + 32*8;
constexpr size_t OFF_AT  = (OFF_ALM + 4*8 + 15) & ~(size_t)15;
constexpr size_t OFF_AM  = OFF_AT + 18432;

DEVFN int pq(int i){ return i + ((i >> 5) << 2); }
// B-side pad: +8 elems per 32 -> strided b128 (64B lane stride) conflict-free
DEVFN int pqb(int i){ return i + ((i >> 5) << 3); }

DEVFN unsigned short f2bf(float f){
  unsigned int u = __float_as_uint(f);
  unsigned int r = (u + 0x7fffu + ((u >> 16) & 1u)) >> 16;
  return (unsigned short)r;
}
DEVFN float bf2f(unsigned short h){ return __uint_as_float(((unsigned int)h) << 16); }

// ---------------- params ----------------
DEVFN double dn(float p, double lo, double hi){ return (double)p*(hi-lo)+lo; }

__device__ void mk_sig(const float* p, int L, bool is_master,
                       SigP* sp, float* Tf, double* aL)
{
  const double flo[6] = {20.,80.,2000.,8000.,12000.,6000.};
  const double fhi[6] = {2000.,2000.,8000.,12000.,21050.,21050.};
  double gdb = dn(p[0], -48., 48.);
  sp->g_in = (float)exp2(gdb * 0.16609640474436813);
  double db0[6],db1[6],db2[6],da1[6],da2[6];
  for (int k=0;k<6;k++){
    double g  = dn(p[1+3*k], -12., 12.);
    double fc = dn(p[2+3*k], flo[k], fhi[k]);
    double q  = dn(p[3+3*k], 0.1, 5.0);
    double A  = pow(10.0, g/40.0);
    double w0 = 2.0*PI_D*(fc/44100.0);
    double al = sin(w0)/(2.0*q), co = cos(w0), sA = sqrt(A);
    double b0,b1,b2,a0,a1,a2;
    if (k==0){
      b0 = A*((A+1.0) - (A-1.0)*co + 2.0*sA*al);
      b1 = 2.0*A*((A-1.0) - (A+1.0)*co);
      b2 = A*((A+1.0) - (A-1.0)*co - 2.0*sA*al);
      a0 = (A+1.0) + (A-1.0)*co + 2.0*sA*al;
      a1 = -2.0*((A-1.0) + (A+1.0)*co);
      a2 = (A+1.0) + (A-1.0)*co - 2.0*sA*al;
    } else if (k==5){
      b0 = A*((A+1.0) + (A-1.0)*co + 2.0*sA*al);
      b1 = -2.0*A*((A-1.0) + (A+1.0)*co);
      b2 = A*((A+1.0) + (A-1.0)*co - 2.0*sA*al);
      a0 = (A+1.0) - (A-1.0)*co + 2.0*sA*al;
      a1 = 2.0*((A-1.0) - (A+1.0)*co);
      a2 = (A+1.0) - (A-1.0)*co - 2.0*sA*al;
    } else {
      b0 = 1.0 + al*A; b1 = -2.0*co; b2 = 1.0 - al*A;
      a0 = 1.0 + al/A; a1 = -2.0*co; a2 = 1.0 - al/A;
    }
    double ia0 = 1.0/a0;
    db0[k]=b0*ia0; db1[k]=b1*ia0; db2[k]=b2*ia0; da1[k]=a1*ia0; da2[k]=a2*ia0;
    sp->cb0[k]=(float)db0[k]; sp->cb1[k]=(float)db1[k]; sp->cb2[k]=(float)db2[k];
    sp->ca1[k]=(float)da1[k]; sp->ca2[k]=(float)da2[k];
  }
  for (int i=0;i<12;i++){
    double st[12]; for (int r=0;r<12;r++) st[r]=0.0; st[i]=1.0;
    double ns[12];
    double yprev=0.0, pm1=0.0, pm2=0.0;
    for (int k=0;k<6;k++){
      double yk = db0[k]*yprev + db1[k]*pm1 + db2[k]*pm2 - da1[k]*st[2*k] - da2[k]*st[2*k+1];
      ns[2*k]=yk; ns[2*k+1]=st[2*k];
      pm1=st[2*k]; pm2=st[2*k+1];
      yprev=yk;
    }
    for (int r=0;r<12;r++) Tf[r*12+i]=(float)ns[r];
  }
  double th    = dn(p[19], -60., 0.);
  double ratio = dn(p[20], 1., 10.);
  double at    = dn(p[21], 5., 250.);
  double knee  = dn(p[23], 3., 12.);
  double mkup  = dn(p[24], 0., 6.);
  double alpha = exp(-log(9.0)/(44100.0*at*0.001));
  sp->alpha=(float)alpha; sp->oma=(float)(1.0-alpha);
  sp->th=(float)th; sp->invr=(float)(1.0/ratio); sp->knee=(float)knee; sp->makeup=(float)mkup;
  *aL = pow(alpha, (double)L);
  if (is_master){
    sp->g_out = (float)exp2(dn(p[25],-48.,48.)*0.16609640474436813);
    sp->gl=0.f; sp->gr=0.f; sp->send=0.f;
  } else {
    sp->g_out = 1.f;
    sp->send = (float)exp2(dn(p[25],-80.,12.)*0.16609640474436813);
    double th2 = dn(p[26],0.,1.)*(PI_D/2.0);
    sp->gl = (float)sqrt((PI_D/2.0-th2)*(2.0/PI_D)*cos(th2));
    sp->gr = (float)sqrt(th2*(2.0/PI_D)*sin(th2));
  }
}

// fused params + matrix power: block b handles one signal
__global__ __launch_bounds__(64) void k_params2(const float* __restrict__ tp, const float* __restrict__ mp,
    SigP* Pt, SigP* Pm, float* AT, float* AM, double* aLt, double* aLm)
{
  __shared__ float Ma[144], Mb[144];
  int b = blockIdx.x, t = threadIdx.x;
  float* Aout; int lg;
  if (t == 0){
    if (b < 32) mk_sig(tp + b*27, L_T, false, &Pt[b], Ma, &aLt[b]);
    else        mk_sig(mp + (b-32 >> 1)*26, L_M, true, &Pm[b-32], Ma, &aLm[b-32]);
  }
  if (b < 32){ Aout = AT + (size_t)b*144; lg = 7; }
  else       { Aout = AM + (size_t)(b-32)*144; lg = 6; }
  __syncthreads();
  int cur=0;
  for (int j=0;j<lg;j++){
    const float* src = cur? Mb:Ma;
    float* dst = cur? Ma:Mb;
    for (int idx=t; idx<144; idx+=64){
      int r=idx/12, cc=idx-r*12;
      float v=0.f;
      #pragma unroll
      for (int m=0;m<12;m++) v = fmaf(src[r*12+m], src[m*12+cc], v);
      dst[idx]=v;
    }
    __syncthreads();
    cur^=1;
  }
  const float* fin = cur? Mb:Ma;
  for (int idx=t; idx<144; idx+=64) Aout[idx]=fin[idx];
}

DEVFN float comp_gc(float y, float th, float invr, float kn){
  float av  = fmaxf(fabsf(y), 1e-8f);
  float xdb = C_LOG * __builtin_log2f(av);
  float d   = xdb - th;
  float w = (2.f*d < -kn) ? 0.f
          : ((2.f*fabsf(d) <= kn) ? (d+0.5f*kn)*(d+0.5f*kn)/(2.f*kn) : d);
  return (invr-1.f)*w;
}

// ---------------- A-pass ----------------
__global__ __launch_bounds__(256) void k_eqA12(const float* __restrict__ in, const SigP* __restrict__ P,
    float* __restrict__ E12, int C, int L)
{
  int tid = blockIdx.x*256 + threadIdx.x;
  int sig = tid / C, c = tid - sig*C;
  const SigP* sp = P + sig;
  float B0[6],B1[6],B2[6],A1[6],A2[6];
  float g = sp->g_in;
  #pragma unroll
  for (int k=0;k<6;k++){
    float gg = (k==0)? g : 1.f;
    B0[k]=sp->cb0[k]*gg; B1[k]=sp->cb1[k]*gg; B2[k]=sp->cb2[k]*gg;
    A1[k]=sp->ca1[k];    A2[k]=sp->ca2[k];
  }
  const float* xp = in + (size_t)sig*SEQ + (size_t)c*L;
  float xm1=0.f, xm2=0.f;
  if (c){ xm1=xp[-1]; xm2=xp[-2]; }
  float s[12];
  #pragma unroll
  for (int r=0;r<12;r++) s[r]=0.f;
  for (int i=0;i<L;i+=4){
    float4 v = *(const float4*)(xp+i);
    #pragma unroll
    for (int u4=0;u4<4;u4++){
      float u = (u4==0)?v.x:(u4==1)?v.y:(u4==2)?v.z:v.w;
      float yprev=u, pm1=xm1, pm2=xm2;
      float ny[6];
      #pragma unroll
      for (int k=0;k<6;k++){
        float t0 = fmaf(B0[k],yprev, fmaf(B1[k],pm1, fmaf(B2[k],pm2, -A2[k]*s[2*k+1])));
        float yk = fmaf(-A1[k], s[2*k], t0);
        ny[k]=yk;
        pm1=s[2*k]; pm2=s[2*k+1];
        yprev=yk;
      }
      #pragma unroll
      for (int k=0;k<6;k++){ s[2*k+1]=s[2*k]; s[2*k]=ny[k]; }
      xm2=xm1; xm1=u;
    }
  }
  float* ep = E12 + (size_t)tid*12;
  #pragma unroll
  for (int r=0;r<12;r++) ep[r]=s[r];
}

// ---------------- 12-state affine scan ----------------
__global__ __launch_bounds__(64) void k_scan12(const float* __restrict__ E, float* __restrict__ I,
    const float* __restrict__ Ab, int C, int Q, int lgQ)
{
  __shared__ float As[144], Pa[144], Pb[144];
  __shared__ float seg[64][12], ini[64][12];
  __shared__ float scur[12], stmp[12];
  int sig = blockIdx.x, t = threadIdx.x;
  const float* Asig = Ab + (size_t)sig*144;
  for (int idx=t; idx<144; idx+=64) As[idx]=Asig[idx];
  __syncthreads();
  const float* dp = E + ((size_t)sig*C + (size_t)t*Q)*12;
  float s[12];
  #pragma unroll
  for (int r=0;r<12;r++) s[r]=0.f;
  for (int j=0;j<Q;j++){
    const float* d = dp + j*12;
    float ns[12];
    #pragma unroll
    for (int r=0;r<12;r++){
      float v = d[r];
      #pragma unroll
      for (int cc=0;cc<12;cc++) v = fmaf(As[r*12+cc], s[cc], v);
      ns[r]=v;
    }
    #pragma unroll
    for (int r=0;r<12;r++) s[r]=ns[r];
  }
  #pragma unroll
  for (int r=0;r<12;r++) seg[t][r]=s[r];
  for (int idx=t; idx<144; idx+=64) Pa[idx]=As[idx];
  __syncthreads();
  int cur=0;
  for (int j=0;j<lgQ;j++){
    const float* src = cur? Pb:Pa;
    float* dst = cur? Pa:Pb;
    for (int idx=t; idx<144; idx+=64){
      int r=idx/12, cc=idx-r*12;
      float v=0.f;
      #pragma unroll
      for (int m=0;m<12;m++) v = fmaf(src[r*12+m], src[m*12+cc], v);
      dst[idx]=v;
    }
    __syncthreads();
    cur^=1;
  }
  const float* AQ = cur? Pb:Pa;
  if (t<12) scur[t]=0.f;
  __syncthreads();
  for (int u=0;u<64;u++){
    if (t<12){
      ini[u][t]=scur[t];
      float v = seg[u][t];
      #pragma unroll
      for (int cc=0;cc<12;cc++) v = fmaf(AQ[t*12+cc], scur[cc], v);
      stmp[t]=v;
    }
    __syncthreads();
    if (t<12) scur[t]=stmp[t];
    __syncthreads();
  }
  #pragma unroll
  for (int r=0;r<12;r++) s[r]=ini[t][r];
  float* op = I + ((size_t)sig*C + (size_t)t*Q)*12;
  for (int j=0;j<Q;j++){
    float* o = op + j*12;
    #pragma unroll
    for (int r=0;r<12;r++) o[r]=s[r];
    const float* d = dp + j*12;
    float ns[12];
    #pragma unroll
    for (int r=0;r<12;r++){
      float v = d[r];
      #pragma unroll
      for (int cc=0;cc<12;cc++) v = fmaf(As[r*12+cc], s[cc], v);
      ns[r]=v;
    }
    #pragma unroll
    for (int r=0;r<12;r++) s[r]=ns[r];
  }
}

// ---------------- 1-state scan ----------------
__global__ __launch_bounds__(64) void k_scan1p(const float* __restrict__ endst, float* __restrict__ inits,
    const double* __restrict__ aL, int C, int Q, int lgQ)
{
  __shared__ double ag[64], ins[64];
  int sig = blockIdx.x; int t = threadIdx.x;
  double a = aL[sig];
  const float* dp = endst + (size_t)sig*C + (size_t)t*Q;
  double e=0.0;
  for (int j=0;j<Q;j++) e = a*e + (double)dp[j];
  ag[t]=e;
  __syncthreads();
  if (t == 0){
    double p=a;
    for (int j=0;j<lgQ;j++) p = p*p;
    double s=0.0;
    for (int u=0;u<64;u++){
      ins[u]=s;
      s = p*s + ag[u];
    }
  }
  __syncthreads();
  double s = ins[t];
  float* op = inits + (size_t)sig*C + (size_t)t*Q;
  for (int j=0;j<Q;j++){ op[j]=(float)s; s = a*s + (double)dp[j]; }
}

// ---------------- C-pass ----------------
__global__ __launch_bounds__(256) void k_eqC12(const float* __restrict__ in, float* __restrict__ yout,
    const SigP* __restrict__ P, const float* __restrict__ I12, float* __restrict__ E1, int C, int L)
{
  int tid = blockIdx.x*256 + threadIdx.x;
  int sig = tid / C, c = tid - sig*C;
  const SigP* sp = P + sig;
  float B0[6],B1[6],B2[6],A1[6],A2[6];
  float g = sp->g_in;
  #pragma unroll
  for (int k=0;k<6;k++){
    float gg = (k==0)? g : 1.f;
    B0[k]=sp->cb0[k]*gg; B1[k]=sp->cb1[k]*gg; B2[k]=sp->cb2[k]*gg;
    A1[k]=sp->ca1[k];    A2[k]=sp->ca2[k];
  }
  float al=sp->alpha, oma=sp->oma, th=sp->th, invr=sp->invr, kn=sp->knee;
  size_t base = (size_t)sig*SEQ + (size_t)c*L;
  const float* xp = in + base;
  float* op = yout + base;
  float xm1=0.f, xm2=0.f;
  if (c){ xm1=xp[-1]; xm2=xp[-2]; }
  const float* ip = I12 + (size_t)tid*12;
  float s[12];
  #pragma unroll
  for (int r=0;r<12;r++) s[r]=ip[r];
  float gacc=0.f;
  for (int i=0;i<L;i+=4){
    float4 v = *(const float4*)(xp+i);
    float4 o;
    #pragma unroll
    for (int u4=0;u4<4;u4++){
      float u = (u4==0)?v.x:(u4==1)?v.y:(u4==2)?v.z:v.w;
      float yprev=u, pm1=xm1, pm2=xm2;
      float ny[6];
      #pragma unroll
      for (int k=0;k<6;k++){
        float t0 = fmaf(B0[k],yprev, fmaf(B1[k],pm1, fmaf(B2[k],pm2, -A2[k]*s[2*k+1])));
        float yk = fmaf(-A1[k], s[2*k], t0);
        ny[k]=yk;
        pm1=s[2*k]; pm2=s[2*k+1];
        yprev=yk;
      }
      #pragma unroll
      for (int k=0;k<6;k++){ s[2*k+1]=s[2*k]; s[2*k]=ny[k]; }
      xm2=xm1; xm1=u;
      float y5 = ny[5];
      if (u4==0) o.x=y5; else if (u4==1) o.y=y5; else if (u4==2) o.z=y5; else o.w=y5;
      gacc = fmaf(al, gacc, oma*comp_gc(y5,th,invr,kn));
    }
    *(float4*)(op+i) = o;
  }
  E1[tid]=gacc;
}

// ---------------- fused smoother + compressor apply ----------------
__global__ __launch_bounds__(256) void k_smoothcomp(const float* __restrict__ yin,
    const SigP* __restrict__ P, const float* __restrict__ inits1, float* __restrict__ gslast,
    float* __restrict__ outp, int C, int L, int lac)
{
  int tid = blockIdx.x*256 + threadIdx.x;
  int sig = tid / C, c = tid - sig*C;
  const SigP* sp = P + sig;
  float al=sp->alpha, oma=sp->oma, th=sp->th, invr=sp->invr, kn=sp->knee;
  float mk=sp->makeup, go=sp->g_out;
  size_t base = (size_t)sig*SEQ + (size_t)c*L;
  const float* xp = yin + base;
  bool wr = (c >= lac);
  size_t ob = wr ? (base - (size_t)lac*L) : 0;
  const float* yp = yin + ob;
  float* op = outp + ob;
  float gsv = inits1[tid];
  for (int i=0;i<L;i+=4){
    float4 v = *(const float4*)(xp+i);
    float4 gf;
    gsv = fmaf(al, gsv, oma*comp_gc(v.x,th,invr,kn)); gf.x=gsv;
    gsv = fmaf(al, gsv, oma*comp_gc(v.y,th,invr,kn)); gf.y=gsv;
    gsv = fmaf(al, gsv, oma*comp_gc(v.z,th,invr,kn)); gf.z=gsv;
    gsv = fmaf(al, gsv, oma*comp_gc(v.w,th,invr,kn)); gf.w=gsv;
    if (wr){
      float4 y2 = *(const float4*)(yp+i);
      float4 o;
      o.x = y2.x * __builtin_exp2f((gf.x+mk)*C_DB) * go;
      o.y = y2.y * __builtin_exp2f((gf.y+mk)*C_DB) * go;
      o.z = y2.z * __builtin_exp2f((gf.z+mk)*C_DB) * go;
      o.w = y2.w * __builtin_exp2f((gf.w+mk)*C_DB) * go;
      *(float4*)(op+i) = o;
    }
  }
  if (c == C-1) gslast[sig] = gsv;
}

__global__ __launch_bounds__(256) void k_comptail(const float* __restrict__ yin, const float* __restrict__ gslast,
    const SigP* __restrict__ P, float* __restrict__ outp, int la)
{
  int q = blockIdx.x*256 + threadIdx.x;
  int per = la/4;
  int sig = q / per;
  int r = (q - sig*per)*4;
  int n = SEQ - la + r;
  const SigP* sp = P + sig;
  float f = __builtin_exp2f((gslast[sig]+sp->makeup)*C_DB) * sp->g_out;
  size_t base = (size_t)sig*SEQ + n;
  float4 v = *(const float4*)(yin+base);
  float4 o = { v.x*f, v.y*f, v.z*f, v.w*f };
  *(float4*)(outp+base) = o;
}

// ---------------- pan + master/fx sums ----------------
__global__ __launch_bounds__(256) void k_pan(const float* __restrict__ y, const SigP* __restrict__ P,
    float* __restrict__ panned, float* __restrict__ m0, float* __restrict__ fx)
{
  int q = blockIdx.x*256 + threadIdx.x;
  int b = q / (SEQ/4);
  int n = (q - b*(SEQ/4))*4;
  float4 aL={0,0,0,0}, aR={0,0,0,0}, fL={0,0,0,0}, fR={0,0,0,0};
  for (int t=0;t<16;t++){
    const SigP* sp = P + b*16 + t;
    float gl=sp->gl, gr=sp->gr, sd=sp->send;
    float4 v = *(const float4*)(y + (size_t)(b*16+t)*SEQ + n);
    float4 pl = { v.x*gl, v.y*gl, v.z*gl, v.w*gl };
    float4 pr = { v.x*gr, v.y*gr, v.z*gr, v.w*gr };
    *(float4*)(panned + (size_t)(b*32+t)*SEQ + n)    = pl;
    *(float4*)(panned + (size_t)(b*32+16+t)*SEQ + n) = pr;
    aL.x+=pl.x; aL.y+=pl.y; aL.z+=pl.z; aL.w+=pl.w;
    aR.x+=pr.x; aR.y+=pr.y; aR.z+=pr.z; aR.w+=pr.w;
    fL.x=fmaf(pl.x,sd,fL.x); fL.y=fmaf(pl.y,sd,fL.y); fL.z=fmaf(pl.z,sd,fL.z); fL.w=fmaf(pl.w,sd,fL.w);
    fR.x=fmaf(pr.x,sd,fR.x); fR.y=fmaf(pr.y,sd,fR.y); fR.z=fmaf(pr.z,sd,fR.z); fR.w=fmaf(pr.w,sd,fR.w);
  }
  *(float4*)(m0 + (size_t)(b*2+0)*SEQ + n) = aL;
  *(float4*)(m0 + (size_t)(b*2+1)*SEQ + n) = aR;
  *(float4*)(fx + (size_t)(b*2+0)*SEQ + n) = fL;
  *(float4*)(fx + (size_t)(b*2+1)*SEQ + n) = fR;
}

// ---------------- ir + fused reversed/padded bf16 IRV ----------------
__global__ __launch_bounds__(256) void k_ir2(const float* __restrict__ filt, const float* __restrict__ fxp,
    float* __restrict__ ir, unsigned short* __restrict__ IRV)
{
  int q = blockIdx.x*256 + threadIdx.x;
  int sig = q / (REV_N/4);
  int idx = q - sig*(REV_N/4);
  int i   = idx*4;
  int b = sig >> 1;
  float4 acc={0,0,0,0};
  const float ts = 1.0f/65535.0f;
  for (int band=0; band<12; band++){
    float gn  = fxp[b*25 + band];
    float dec = fxp[b*25 + 12 + band]*10.f + 1.f;
    float4 f = *(const float4*)(filt + ((size_t)(sig*12+band))*REV_N + i);
    float s = -dec*ts;
    float e0=expf(s*(float)i), e1=expf(s*(float)(i+1)), e2=expf(s*(float)(i+2)), e3=expf(s*(float)(i+3));
    acc.x = fmaf(gn*e0, f.x, acc.x);
    acc.y = fmaf(gn*e1, f.y, acc.y);
    acc.z = fmaf(gn*e2, f.z, acc.z);
    acc.w = fmaf(gn*e3, f.w, acc.w);
  }
  const float inv12 = 1.f/12.f;
  acc.x*=inv12; acc.y*=inv12; acc.z*=inv12; acc.w*=inv12;
  *(float4*)(ir + (size_t)sig*REV_N + i) = acc;
  unsigned short* iv = IRV + (size_t)sig*IRL;
  int base = IRPAD + REV_N-1 - i;
  iv[base]   = f2bf(acc.x);
  iv[base-1] = f2bf(acc.y);
  iv[base-2] = f2bf(acc.z);
  iv[base-3] = f2bf(acc.w);
  if (idx < 1024){
    *(ushort4*)(iv + idx*4) = make_ushort4(0,0,0,0);
  } else if (idx < 2048){
    *(ushort4*)(iv + IRPAD + REV_N + (idx-1024)*4) = make_ushort4(0,0,0,0);
  }
}

// ---------------- combined bf16 prep: XB (fx), XBN (noise), FBV (fb) ----------------
constexpr int P3_XB  = 4*XBL;
constexpr int P3_XBN = 48*XNL;
constexpr int P3_TOT = P3_XB + P3_XBN + 12*FBL;
__global__ __launch_bounds__(256) void k_prep3(const float* __restrict__ fx, const float* __restrict__ noise,
    const float* __restrict__ fb, unsigned short* __restrict__ XB, unsigned short* __restrict__ XBN,
    unsigned short* __restrict__ FBV)
{
  int q = blockIdx.x*256 + threadIdx.x;
  if (q < P3_XB){
    int sig = q / XBL;
    int m   = q - sig*XBL;
    int a = m - PADX;
    float v = (a >= 0 && a < SEQ) ? fx[(size_t)sig*SEQ + a] : 0.f;
    XB[(size_t)sig*XBL + m] = f2bf(v);
  } else if (q < P3_XB + P3_XBN){
    int q2 = q - P3_XB;
    int sig = q2 / XNL;
    int m   = q2 - sig*XNL;
    int a = m - PADN + 1022;
    float v = (a >= 0 && a < NOISE_LEN) ? noise[(size_t)sig*NOISE_LEN + a] : 0.f;
    XBN[(size_t)sig*XNL + m] = f2bf(v);
  } else if (q < P3_TOT){
    int q3 = q - P3_XB - P3_XBN;
    int band = q3 / FBL;
    int m = q3 - band*FBL;
    int a = m - FPAD;
    float v = (a >= 0 && a < TAPS) ? fb[band*TAPS + (TAPS-1 - a)] : 0.f;
    FBV[(size_t)band*FBL + m] = f2bf(v);
  }
}

// ---------------- band FIR via MFMA, swapped operands: A=fb(4xb32), B=x(aligned b128) ----------------
// out[n] = sum_m fb[m] x[n-m].  C[i][j] = out[n0w + 1024b + i + 32j].
// A[i][k] = fb[16s + i - k] = R[1022-16s-i+k]  (R = reversed fb, zero-padded in FBV)
// B_b[k][j] = x[n0w + 1024b + 32j + k - 16s]   (16B-aligned: offset === 0 mod 8)
// s in [-2, 65); window staging done ONCE (fb window 1112 elems, x window 17440 elems).
__global__ __launch_bounds__(256,3) void k_firm2(const unsigned short* __restrict__ XBN,
    const unsigned short* __restrict__ FBV, float* __restrict__ filt)
{
  __shared__ alignas(16) unsigned short sx[21800];   // pqb(17440)
  __shared__ alignas(16) unsigned int rf0[560];
  __shared__ alignas(16) unsigned int rf1[560];
  int b = blockIdx.x;                 // 192 = 4 ngrp * 48 sig
  int ng  = b & 3;
  int sig = b >> 2;
  int band = sig % 12;
  int nblk = ng << 14;                // 16384 outputs per block
  int tid = threadIdx.x;
  int l  = tid & 63, wv = tid >> 6;
  int lj = l & 31, lg = l >> 5;
  int ph = lj & 1;

  // ---- stage x: elements [xlo, xlo+17440), xlo = nblk - 1024 ----
  const unsigned short* xg = XBN + (size_t)sig*XNL + (PADN + nblk - 1024);
  for (int i = 4*tid; i < 17440; i += 1024){
    ushort4 v = *(const ushort4*)(xg + i);
    *(ushort4*)(sx + pqb(i)) = v;
  }
  // ---- stage fb window: R[qlo + 2d + phase], qlo = -40; FBV dword base (FPAD+qlo)/2 = 1004 ----
  const unsigned int* fbu = (const unsigned int*)(FBV + (size_t)band*FBL);
  for (int d = tid; d < 560; d += 256){
    unsigned int u0 = fbu[1004 + d], u1 = fbu[1004 + d + 1];
    rf0[d] = u0;
    rf1[d] = (u0 >> 16) | (u1 << 16);
  }
  __syncthreads();

  const unsigned int* rsel = ph ? rf1 : rf0;
  f32x16 acc0 = {}, acc1 = {}, acc2 = {}, acc3 = {};
  int n0_w = wv*4096;                 // relative to nblk; x window already offset by xlo

  for (int ss = 0; ss < 67; ss++){    // s = ss - 2
    // A (fb): element q0rel = 1094 - 16*ss - lj + 8*lg (window-relative, qlo=-40)
    int d0 = (1094 - 16*ss - lj + 8*lg - ph) >> 1;
    union { unsigned int u[4]; short8v v; } a0;
    a0.u[0]=rsel[d0]; a0.u[1]=rsel[d0+1]; a0.u[2]=rsel[d0+2]; a0.u[3]=rsel[d0+3];
    // B (x): element e0 = n0_w + 1056 + 32*lj + 8*lg - 16*ss  (>=0, === 0 mod 8)
    int e0 = n0_w + 1056 + 32*lj + 8*lg - 16*ss;
    int pb = pqb(e0);
    short8v bf0 = *(const short8v*)(sx + pb);
    short8v bf1 = *(const short8v*)(sx + pb + 1280);
    short8v bf2 = *(const short8v*)(sx + pb + 2560);
    short8v bf3 = *(const short8v*)(sx + pb + 3840);
    acc0 = __builtin_amdgcn_mfma_f32_32x32x16_bf16(a0.v, bf0, acc0, 0, 0, 0);
    acc1 = __builtin_amdgcn_mfma_f32_32x32x16_bf16(a0.v, bf1, acc1, 0, 0, 0);
    acc2 = __builtin_amdgcn_mfma_f32_32x32x16_bf16(a0.v, bf2, acc2, 0, 0, 0);
    acc3 = __builtin_amdgcn_mfma_f32_32x32x16_bf16(a0.v, bf3, acc3, 0, 0, 0);
  }
  float* fp = filt + (size_t)sig*REV_N + nblk;
  #pragma unroll
  for (int reg = 0; reg < 16; reg++){
    int i = (reg & 3) + 8*(reg >> 2) + 4*lg;
    int o = wv*4096 + i + 32*lj;
    fp[o]        = acc0[reg];
    fp[o + 1024] = acc1[reg];
    fp[o + 2048] = acc2[reg];
    fp[o + 3072] = acc3[reg];
  }
}

// ---------------- wet conv via MFMA: 1 A-frag x 4 B-frags, ns=128 batches ----------------
__global__ __launch_bounds__(256,2) void k_wetm(const unsigned short* __restrict__ XB,
    const unsigned short* __restrict__ IRV, unsigned short* __restrict__ WP)
{
  __shared__ alignas(16) unsigned int xs0[7200];
  __shared__ alignas(16) unsigned int xs1[7200];
  __shared__ alignas(16) unsigned short sir[7680];
  int b = blockIdx.x;                 // 512 = 16 ngrp * 4 sig * 8 kp
  int ng  = b & 15;
  int sig = (b >> 4) & 3;
  int kp  = b >> 6;
  int nblk = ng << 14;
  int sbeg = -254 + 544*kp;
  int send = sbeg + 544; if (send > 4097) send = 4097;

  int tid = threadIdx.x;
  int l  = tid & 63, wv = tid >> 6;
  int lj = l & 31, lg = l >> 5, ph = l & 1;
  int hl = (lj + 8*lg - ph) >> 1;
  int offB = 32*lj - 8*lg;
  const unsigned int* xbu = (const unsigned int*)(XB + (size_t)sig*XBL);
  const unsigned short* irg = IRV + (size_t)sig*IRL;
  const unsigned int* xsel = ph ? (const unsigned int*)xs1 : (const unsigned int*)xs0;

  f32x16 acc0 = {}, acc1 = {}, acc2 = {}, acc3 = {};
  int n0_w = nblk + wv*4096;

  for (int sa = sbeg; sa < send; sa += 128){
    int ns = send - sa; if (ns > 128) ns = 128;
    __syncthreads();
    int clo = nblk - 16*(sa + ns - 1);
    int ub  = (PADX + clo) >> 1;
    int nd  = (12336 + 16*(ns-1))/2 + 2;
    for (int d = tid; d < nd; d += 256){
      unsigned int u0 = xbu[ub + d], u1 = xbu[ub + d + 1];
      xs0[d] = u0;
      xs1[d] = (u0 >> 16) | (u1 << 16);
    }
    int amin = 65535 - 16*(sa + ns - 1) - 4064;
    int irlo = ((amin - 7) & ~7) + 7;
    int irspan = (65535 - 16*sa + 15) - irlo + 1;
    for (int r = tid; r < irspan; r += 256){
      sir[pqb(r)] = irg[IRPAD + irlo + r];
    }
    __syncthreads();
    int db0 = ((n0_w - clo) >> 1) - 8*sa + hl;
    int Dh0 = 65535 - 16*sa - irlo;
    for (int ss = 0; ss < ns; ss++){
      int rB = (Dh0 - 16*ss) - offB;
      int pb = pqb(rB);
      short8v bf0 = *(const short8v*)(sir + pb);
      short8v bf1 = *(const short8v*)(sir + pb - 1280);
      short8v bf2 = *(const short8v*)(sir + pb - 2560);
      short8v bf3 = *(const short8v*)(sir + pb - 3840);
      union { unsigned int u[4]; short8v v; } a0;
      int d0 = db0 - 8*ss;
      a0.u[0]=xsel[d0]; a0.u[1]=xsel[d0+1]; a0.u[2]=xsel[d0+2]; a0.u[3]=xsel[d0+3];
      acc0 = __builtin_amdgcn_mfma_f32_32x32x16_bf16(a0.v, bf0, acc0, 0, 0, 0);
      acc1 = __builtin_amdgcn_mfma_f32_32x32x16_bf16(a0.v, bf1, acc1, 0, 0, 0);
      acc2 = __builtin_amdgcn_mfma_f32_32x32x16_bf16(a0.v, bf2, acc2, 0, 0, 0);
      acc3 = __builtin_amdgcn_mfma_f32_32x32x16_bf16(a0.v, bf3, acc3, 0, 0, 0);
    }
  }
  unsigned short* wp = WP + ((size_t)(kp*4+sig))*SEQ;
  #pragma unroll
  for (int reg = 0; reg < 16; reg++){
    int i = (reg & 3) + 8*(reg >> 2) + 4*lg;
    int o = n0_w + i + 32*lj;
    wp[o]        = f2bf(acc0[reg]);
    wp[o + 1024] = f2bf(acc1[reg]);
    wp[o + 2048] = f2bf(acc2[reg]);
    wp[o + 3072] = f2bf(acc3[reg]);
  }
}

// ---------------- reduce partials + mix + add to master ----------------
__global__ __launch_bounds__(256) void k_wetred(const unsigned short* __restrict__ wp, const float* __restrict__ fx,
    const float* __restrict__ m0, const float* __restrict__ fxp, float* __restrict__ m1)
{
  int q = blockIdx.x*256 + threadIdx.x;
  int sig = q / (SEQ/4);
  int n = (q - sig*(SEQ/4))*4;
  float mix = fxp[(sig>>1)*25+24];
  size_t ob = (size_t)sig*SEQ + n;
  float s0=0.f, s1=0.f, s2=0.f, s3=0.f;
  #pragma unroll
  for (int kp=0; kp<8; kp++){
    const unsigned short* p = wp + ((size_t)(kp*4+sig))*SEQ + n;
    s0 += bf2f(p[0]); s1 += bf2f(p[1]); s2 += bf2f(p[2]); s3 += bf2f(p[3]);
  }
  float4 w0 = *(const float4*)(m0+ob);
  float4 x0 = *(const float4*)(fx+ob);
  float om = 1.f - mix;
  float4 o;
  o.x = w0.x + om*x0.x + mix*s0;
  o.y = w0.y + om*x0.y + mix*s1;
  o.z = w0.z + om*x0.z + mix*s2;
  o.w = w0.w + om*x0.w + mix*s3;
  *(float4*)(m1+ob) = o;
}

// ---------------- launch ----------------
extern "C" void kernel_launch(void* const* d_in, const int* in_sizes, int n_in,
                              void* d_out, int out_size, void* d_ws, size_t ws_size,
                              hipStream_t stream)
{
  const float* tracks = (const float*)d_in[0];
  const float* tp     = (const float*)d_in[1];
  const float* fxp    = (const float*)d_in[2];
  const float* mp     = (const float*)d_in[3];
  const float* noise  = (const float*)d_in[4];
  const float* fbp    = (const float*)d_in[5];
  float* out = (float*)d_out;
  char* w = (char*)d_ws;

  float*  X   = (float*)(w + OFF_X);
  float*  Y   = (float*)(w + OFF_Y);
  float*  FXb = (float*)(w + OFF_FX);
  float*  M0  = (float*)(w + OFF_M0);
  float*  E12 = (float*)(w + OFF_E12);
  float*  I12 = (float*)(w + OFF_I12);
  float*  E1  = (float*)(w + OFF_E1);
  float*  I1  = (float*)(w + OFF_I1);
  float*  GLt = (float*)(w + OFF_GL);
  float*  GLm = GLt + 32;
  SigP*   Pt  = (SigP*)(w + OFF_PT);
  SigP*   Pm  = (SigP*)(w + OFF_PM);
  double* aLt = (double*)(w + OFF_ALT);
  double* aLm = (double*)(w + OFF_ALM);
  float*  AT  = (float*)(w + OFF_AT);
  float*  AM  = (float*)(w + OFF_AM);
  float*  FILT= (float*)(w + OFF_FILT);
  float*  IR  = (float*)(w + OFF_IR);
  float*  XM  = (float*)(w + OFF_XM);
  float*  M1  = (float*)(w + OFF_M1);
  unsigned short* WPu = (unsigned short*)(w + OFF_WP);
  unsigned short* XB  = (unsigned short*)(w + OFF_XB);
  unsigned short* IRV = (unsigned short*)(w + OFF_IR2);
  unsigned short* XBN = (unsigned short*)(w + OFF_XBN);
  unsigned short* FBV = (unsigned short*)(w + OFF_FBV);

  k_params2<<<36,64,0,stream>>>(tp, mp, Pt, Pm, AT, AM, aLt, aLm);

  // ---- track chain ----
  const int GT = NS_T*C_T/256;
  k_eqA12<<<GT,256,0,stream>>>(tracks, Pt, E12, C_T, L_T);
  k_scan12<<<NS_T,64,0,stream>>>(E12, I12, AT, C_T, C_T/64, 5);
  k_eqC12<<<GT,256,0,stream>>>(tracks, Y, Pt, I12, E1, C_T, L_T);
  k_scan1p<<<NS_T,64,0,stream>>>(E1, I1, aLt, C_T, C_T/64, 5);
  k_smoothcomp<<<GT,256,0,stream>>>(Y, Pt, I1, GLt, X, C_T, L_T, LA_T/L_T);
  k_comptail<<<NS_T*(LA_T/4)/256,256,0,stream>>>(Y, GLt, Pt, X, LA_T);
  k_pan<<<2*(SEQ/4)/256,256,0,stream>>>(X, Pt, out, M0, FXb);

  // ---- reverb ----
  k_prep3<<<(P3_TOT+255)/256,256,0,stream>>>(FXb, noise, fbp, XB, XBN, FBV);
  k_firm2<<<192,256,0,stream>>>(XBN, FBV, FILT);
  k_ir2<<<4*(REV_N/4)/256,256,0,stream>>>(FILT, fxp, IR, IRV);
  k_wetm<<<512,256,0,stream>>>(XB, IRV, WPu);
  k_wetred<<<4*(SEQ/4)/256,256,0,stream>>>(WPu, FXb, M0, fxp, M1);

  // ---- master chain ----
  const int GM = NS_M*C_M/256;
  k_eqA12<<<GM,256,0,stream>>>(M1, Pm, E12, C_M, L_M);
  k_scan12<<<NS_M,64,0,stream>>>(E12, I12, AM, C_M, C_M/64, 6);
  k_eqC12<<<GM,256,0,stream>>>(M1, XM, Pm, I12, E1, C_M, L_M);
  k_scan1p<<<NS_M,64,0,stream>>>(E1, I1, aLm, C_M, C_M/64, 6);
  k_smoothcomp<<<GM,256,0,stream>>>(XM, Pm, I1, GLm, out + OUT_MASTER_OFF, C_M, L_M, LA_M/L_M);
  k_comptail<<<NS_M*(LA_M/4)/256,256,0,stream>>>(XM, GLm, Pm, out + OUT_MASTER_OFF, LA_M);
}